// Round 1
// baseline (2962.424 us; speedup 1.0000x reference)
//
#include <hip/hip_runtime.h>
#include <cstdint>
#include <math.h>

#define T_TOKENS 4096
#define SEQ 2048
#define DM 2048
#define NH 16
#define NKV 8
#define HD 128
#define QDIM 2048   // NH*HD
#define KVDIM 1024  // NKV*HD
#define QKVN 4096   // QDIM + 2*KVDIM
#define INTER 8192
#define GUN 16384   // 2*INTER

typedef int v4i __attribute__((ext_vector_type(4)));

__device__ inline float wave_sum(float v) {
#pragma unroll
  for (int off = 32; off > 0; off >>= 1) v += __shfl_down(v, off);
  return v;
}
__device__ inline float wave_max(float v) {
#pragma unroll
  for (int off = 32; off > 0; off >>= 1) v = fmaxf(v, __shfl_down(v, off));
  return v;
}
__device__ inline float dot4(float4 a, float4 b) {
  return a.x * b.x + a.y * b.y + a.z * b.z + a.w * b.w;
}
__device__ inline int8_t quant1(float v, float s) {
  float q = rintf(v / s);
  q = fminf(fmaxf(q, -127.f), 127.f);
  return (int8_t)(int)q;
}

// ---------------- RoPE tables ----------------
__global__ void rope_table_kernel(float* __restrict__ cosT, float* __restrict__ sinT) {
  int s = blockIdx.x, d = threadIdx.x;  // 64 threads
  float inv = 1.0f / powf(10000.0f, (float)d * (1.0f / 64.0f));
  float f = (float)s * inv;
  cosT[s * 64 + d] = cosf(f);
  sinT[s * 64 + d] = sinf(f);
}

// ---------------- per-row weight quant (2-pass) ----------------
__global__ __launch_bounds__(256) void quant_w_kernel(const float* __restrict__ w,
                                                      int8_t* __restrict__ qw,
                                                      float* __restrict__ sw, int K) {
  __shared__ float red[4];
  int row = blockIdx.x, tid = threadIdx.x;
  const float* wr = w + (size_t)row * K;
  float mx = 0.f;
  for (int i = tid * 4; i < K; i += 1024) {
    float4 v = *(const float4*)(wr + i);
    mx = fmaxf(mx, fmaxf(fmaxf(fabsf(v.x), fabsf(v.y)), fmaxf(fabsf(v.z), fabsf(v.w))));
  }
  mx = wave_max(mx);
  if ((tid & 63) == 0) red[tid >> 6] = mx;
  __syncthreads();
  float m = fmaxf(fmaxf(red[0], red[1]), fmaxf(red[2], red[3]));
  float s = m * (1.0f / 127.0f);
  if (tid == 0) sw[row] = s;
  float sd = (s > 0.f) ? s : 1.f;
  int8_t* qr = qw + (size_t)row * K;
  for (int i = tid * 4; i < K; i += 1024) {
    float4 v = *(const float4*)(wr + i);
    char4 o;
    o.x = quant1(v.x, sd);
    o.y = quant1(v.y, sd);
    o.z = quant1(v.z, sd);
    o.w = quant1(v.w, sd);
    *(char4*)(qr + i) = o;
  }
}

// ---------------- RMSNorm + per-token quant ----------------
__global__ __launch_bounds__(256) void rmsnorm_quant_kernel(const float* __restrict__ x,
                                                            const float* __restrict__ w,
                                                            int8_t* __restrict__ q,
                                                            float* __restrict__ s) {
  __shared__ float red[8];
  int t = blockIdx.x, tid = threadIdx.x;
  const float* xr = x + (size_t)t * DM;
  float4 a = *(const float4*)(xr + tid * 8);
  float4 b = *(const float4*)(xr + tid * 8 + 4);
  float ss = dot4(a, a) + dot4(b, b);
  ss = wave_sum(ss);
  if ((tid & 63) == 0) red[tid >> 6] = ss;
  __syncthreads();
  float tot = red[0] + red[1] + red[2] + red[3];
  float rms = rsqrtf(tot * (1.0f / DM) + 1e-6f);
  float4 wa = *(const float4*)(w + tid * 8);
  float4 wb = *(const float4*)(w + tid * 8 + 4);
  float y[8] = {a.x * rms * wa.x, a.y * rms * wa.y, a.z * rms * wa.z, a.w * rms * wa.w,
                b.x * rms * wb.x, b.y * rms * wb.y, b.z * rms * wb.z, b.w * rms * wb.w};
  float mx = 0.f;
#pragma unroll
  for (int i = 0; i < 8; i++) mx = fmaxf(mx, fabsf(y[i]));
  mx = wave_max(mx);
  if ((tid & 63) == 0) red[4 + (tid >> 6)] = mx;
  __syncthreads();
  float m = fmaxf(fmaxf(red[4], red[5]), fmaxf(red[6], red[7]));
  float sc = fmaxf(m * (1.0f / 127.0f), 1e-8f);
  if (tid == 0) s[t] = sc;
  int8_t* qr = q + (size_t)t * DM + tid * 8;
  char4 o0, o1;
  o0.x = quant1(y[0], sc); o0.y = quant1(y[1], sc); o0.z = quant1(y[2], sc); o0.w = quant1(y[3], sc);
  o1.x = quant1(y[4], sc); o1.y = quant1(y[5], sc); o1.z = quant1(y[6], sc); o1.w = quant1(y[7], sc);
  *(char4*)(qr) = o0;
  *(char4*)(qr + 4) = o1;
}

// ---------------- plain per-token quant of a [*,2048] f32 matrix ----------------
__global__ __launch_bounds__(256) void quant_rows_2048_kernel(const float* __restrict__ x,
                                                              int8_t* __restrict__ q,
                                                              float* __restrict__ s) {
  __shared__ float red[4];
  int t = blockIdx.x, tid = threadIdx.x;
  const float* xr = x + (size_t)t * DM;
  float4 a = *(const float4*)(xr + tid * 8);
  float4 b = *(const float4*)(xr + tid * 8 + 4);
  float y[8] = {a.x, a.y, a.z, a.w, b.x, b.y, b.z, b.w};
  float mx = 0.f;
#pragma unroll
  for (int i = 0; i < 8; i++) mx = fmaxf(mx, fabsf(y[i]));
  mx = wave_max(mx);
  if ((tid & 63) == 0) red[tid >> 6] = mx;
  __syncthreads();
  float m = fmaxf(fmaxf(red[0], red[1]), fmaxf(red[2], red[3]));
  float sc = fmaxf(m * (1.0f / 127.0f), 1e-8f);
  if (tid == 0) s[t] = sc;
  int8_t* qr = q + (size_t)t * DM + tid * 8;
  char4 o0, o1;
  o0.x = quant1(y[0], sc); o0.y = quant1(y[1], sc); o0.z = quant1(y[2], sc); o0.w = quant1(y[3], sc);
  o1.x = quant1(y[4], sc); o1.y = quant1(y[5], sc); o1.z = quant1(y[6], sc); o1.w = quant1(y[7], sc);
  *(char4*)(qr) = o0;
  *(char4*)(qr + 4) = o1;
}

// ---------------- gelu(gate)*up + per-token quant (INTER=8192) ----------------
__global__ __launch_bounds__(256) void gelu_mul_quant_kernel(const float* __restrict__ gu,
                                                             int8_t* __restrict__ q,
                                                             float* __restrict__ s) {
  __shared__ float red[4];
  int t = blockIdx.x, tid = threadIdx.x;
  const float* g = gu + (size_t)t * GUN;
  const float* u = g + INTER;
  float act[32];
  float mx = 0.f;
#pragma unroll
  for (int i4 = 0; i4 < 32; i4 += 4) {
    float4 gv = *(const float4*)(g + tid * 32 + i4);
    float4 uv = *(const float4*)(u + tid * 32 + i4);
    float gg[4] = {gv.x, gv.y, gv.z, gv.w};
    float uu[4] = {uv.x, uv.y, uv.z, uv.w};
#pragma unroll
    for (int j = 0; j < 4; j++) {
      float xx = gg[j];
      float inner = 0.7978845608028654f * (xx + 0.044715f * xx * xx * xx);
      float gl = 0.5f * xx * (1.0f + tanhf(inner));
      float av = gl * uu[j];
      act[i4 + j] = av;
      mx = fmaxf(mx, fabsf(av));
    }
  }
  mx = wave_max(mx);
  if ((tid & 63) == 0) red[tid >> 6] = mx;
  __syncthreads();
  float m = fmaxf(fmaxf(red[0], red[1]), fmaxf(red[2], red[3]));
  float sc = fmaxf(m * (1.0f / 127.0f), 1e-8f);
  if (tid == 0) s[t] = sc;
  int8_t* qr = q + (size_t)t * INTER + tid * 32;
#pragma unroll
  for (int i4 = 0; i4 < 32; i4 += 4) {
    char4 o;
    o.x = quant1(act[i4], sc);
    o.y = quant1(act[i4 + 1], sc);
    o.z = quant1(act[i4 + 2], sc);
    o.w = quant1(act[i4 + 3], sc);
    *(char4*)(qr + i4) = o;
  }
}

// ---------------- RoPE apply (in-place on q,k cols of qkv) ----------------
__global__ __launch_bounds__(256) void rope_apply_kernel(float* __restrict__ qkv,
                                                         const float* __restrict__ cosT,
                                                         const float* __restrict__ sinT) {
  int t = blockIdx.x, tid = threadIdx.x;
  int sp = t & (SEQ - 1);
  float* base = qkv + (size_t)t * QKVN;
#pragma unroll
  for (int it = 0; it < 6; ++it) {
    int p = tid + it * 256;  // 1536 pairs: 24 heads x 64
    int hh = p >> 6, d = p & 63;
    float* ptr = base + (hh < NH ? hh * HD : QDIM + (hh - NH) * HD);
    float c = cosT[sp * 64 + d], sn = sinT[sp * 64 + d];
    float x0 = ptr[d], x1 = ptr[d + 64];
    ptr[d] = x0 * c - x1 * sn;
    ptr[d + 64] = x1 * c + x0 * sn;
  }
}

// ---------------- int8 GEMM: C[M,N] = (qA[M,K] @ qB[N,K]^T) * sA * sB (+res) ----------------
__global__ __launch_bounds__(256) void gemm_i8_kernel(const int8_t* __restrict__ A,
                                                      const float* __restrict__ sA,
                                                      const int8_t* __restrict__ B,
                                                      const float* __restrict__ sB,
                                                      const float* __restrict__ res,
                                                      float* __restrict__ C, int N, int K) {
  __shared__ __align__(16) int8_t lA[128][80];
  __shared__ __align__(16) int8_t lB[128][80];
  int tid = threadIdx.x;
  int row0 = blockIdx.y * 128;
  int col0 = blockIdx.x * 128;
  int lane = tid & 63, wid = tid >> 6;
  int wm = (wid >> 1) * 64, wn = (wid & 1) * 64;
  int fr = lane & 15, fk = (lane >> 4) * 16;
  int srow = tid >> 2, soff = (tid & 3) * 16;

  v4i acc[4][4];
#pragma unroll
  for (int m = 0; m < 4; m++)
#pragma unroll
    for (int n = 0; n < 4; n++) acc[m][n] = (v4i){0, 0, 0, 0};

  const int8_t* A0 = A + (size_t)(row0 + srow) * K + soff;
  const int8_t* A1 = A + (size_t)(row0 + srow + 64) * K + soff;
  const int8_t* B0 = B + (size_t)(col0 + srow) * K + soff;
  const int8_t* B1 = B + (size_t)(col0 + srow + 64) * K + soff;

  for (int k0 = 0; k0 < K; k0 += 64) {
    *(v4i*)&lA[srow][soff] = *(const v4i*)(A0 + k0);
    *(v4i*)&lA[srow + 64][soff] = *(const v4i*)(A1 + k0);
    *(v4i*)&lB[srow][soff] = *(const v4i*)(B0 + k0);
    *(v4i*)&lB[srow + 64][soff] = *(const v4i*)(B1 + k0);
    __syncthreads();
    v4i a[4], b[4];
#pragma unroll
    for (int m = 0; m < 4; m++) a[m] = *(const v4i*)&lA[wm + m * 16 + fr][fk];
#pragma unroll
    for (int n = 0; n < 4; n++) b[n] = *(const v4i*)&lB[wn + n * 16 + fr][fk];
#pragma unroll
    for (int m = 0; m < 4; m++)
#pragma unroll
      for (int n = 0; n < 4; n++)
        acc[m][n] = __builtin_amdgcn_mfma_i32_16x16x64_i8(a[m], b[n], acc[m][n], 0, 0, 0);
    __syncthreads();
  }
  int rj = (lane >> 4) * 4;
  int cn = lane & 15;
#pragma unroll
  for (int m = 0; m < 4; m++) {
#pragma unroll
    for (int j = 0; j < 4; j++) {
      int rl = row0 + wm + m * 16 + rj + j;
      float sa = sA[rl];
      size_t rowoff = (size_t)rl * N;
#pragma unroll
      for (int n = 0; n < 4; n++) {
        int cg = col0 + wn + n * 16 + cn;
        float v = (float)acc[m][n][j] * sa * sB[cg];
        if (res) v += res[rowoff + cg];
        C[rowoff + cg] = v;
      }
    }
  }
}

// ---------------- flash attention, f32, 32x32 tiles, tanh softcap, causal ----------------
__global__ __launch_bounds__(256) void attn_kernel(const float* __restrict__ qkv,
                                                   float* __restrict__ out) {
  __shared__ __align__(16) float qs[32][132];
  __shared__ __align__(16) float ks[32][132];
  __shared__ __align__(16) float vs[32][132];
  __shared__ float ps[32][33];
  int qt = blockIdx.x;
  int bh = blockIdx.y;
  int b = bh >> 4, h = bh & 15, g = h >> 1;
  int tid = threadIdx.x;
  for (int cc = tid; cc < 1024; cc += 256) {
    int rr = cc >> 5, d4 = (cc & 31) * 4;
    *(float4*)&qs[rr][d4] =
        *(const float4*)(qkv + (size_t)(b * SEQ + qt * 32 + rr) * QKVN + h * HD + d4);
  }
  float mrun = -INFINITY, l = 0.f;
  float o[16];
#pragma unroll
  for (int i = 0; i < 16; i++) o[i] = 0.f;
  int sr = tid & 15;
  int sj = (tid >> 4) * 2;
  int r = tid >> 3, c0 = (tid & 7) * 16;
  int ktiles = qt + 1;
  for (int kt = 0; kt < ktiles; ++kt) {
    __syncthreads();
    for (int cc = tid; cc < 1024; cc += 256) {
      int rr = cc >> 5, d4 = (cc & 31) * 4;
      size_t tb = (size_t)(b * SEQ + kt * 32 + rr) * QKVN;
      *(float4*)&ks[rr][d4] = *(const float4*)(qkv + tb + QDIM + g * HD + d4);
      *(float4*)&vs[rr][d4] = *(const float4*)(qkv + tb + QDIM + KVDIM + g * HD + d4);
    }
    __syncthreads();
    float sc00 = 0, sc01 = 0, sc10 = 0, sc11 = 0;
#pragma unroll 8
    for (int d4 = 0; d4 < 128; d4 += 4) {
      float4 q0 = *(const float4*)&qs[sr][d4];
      float4 q1 = *(const float4*)&qs[sr + 16][d4];
      float4 k0 = *(const float4*)&ks[sj][d4];
      float4 k1 = *(const float4*)&ks[sj + 1][d4];
      sc00 += dot4(q0, k0);
      sc01 += dot4(q0, k1);
      sc10 += dot4(q1, k0);
      sc11 += dot4(q1, k1);
    }
    {
      // combined scale: (1/sqrt(128)) / 50 inside tanh, *50 outside
      const float kin = 0.08838834764831845f * 0.02f;
      int qg0 = qt * 32 + sr, qg1 = qg0 + 16;
      int kg0 = kt * 32 + sj, kg1 = kg0 + 1;
      float v00 = 50.f * tanhf(sc00 * kin);
      float v01 = 50.f * tanhf(sc01 * kin);
      float v10 = 50.f * tanhf(sc10 * kin);
      float v11 = 50.f * tanhf(sc11 * kin);
      ps[sr][sj] = (kg0 <= qg0) ? v00 : -1e30f;
      ps[sr][sj + 1] = (kg1 <= qg0) ? v01 : -1e30f;
      ps[sr + 16][sj] = (kg0 <= qg1) ? v10 : -1e30f;
      ps[sr + 16][sj + 1] = (kg1 <= qg1) ? v11 : -1e30f;
    }
    __syncthreads();
    float mt = -1e30f;
#pragma unroll
    for (int j = 0; j < 32; j++) mt = fmaxf(mt, ps[r][j]);
    float mnew = fmaxf(mrun, mt);
    float alpha = expf(mrun - mnew);
    l *= alpha;
#pragma unroll
    for (int i = 0; i < 16; i++) o[i] *= alpha;
#pragma unroll 4
    for (int j = 0; j < 32; j++) {
      float e = expf(ps[r][j] - mnew);
      l += e;
      const float* vr = &vs[j][c0];
#pragma unroll
      for (int i4 = 0; i4 < 16; i4 += 4) {
        float4 vv = *(const float4*)(vr + i4);
        o[i4] += e * vv.x;
        o[i4 + 1] += e * vv.y;
        o[i4 + 2] += e * vv.z;
        o[i4 + 3] += e * vv.w;
      }
    }
    mrun = mnew;
  }
  float invl = 1.f / l;
  int qg = qt * 32 + r;
  float* op = out + (size_t)(b * SEQ + qg) * QDIM + h * HD + c0;
#pragma unroll
  for (int i = 0; i < 16; i++) op[i] = o[i] * invl;
}

extern "C" void kernel_launch(void* const* d_in, const int* in_sizes, int n_in, void* d_out,
                              int out_size, void* d_ws, size_t ws_size, hipStream_t stream) {
  (void)in_sizes; (void)n_in; (void)out_size; (void)ws_size;
  const float* hidden = (const float*)d_in[0];
  const float* w_in_norm = (const float*)d_in[1];
  const float* w_post_norm = (const float*)d_in[2];
  const float* wqkv = (const float*)d_in[3];
  const float* wo = (const float*)d_in[4];
  const float* w_gate_up = (const float*)d_in[5];
  const float* w_down = (const float*)d_in[6];
  float* out = (float*)d_out;

  char* p = (char*)d_ws;
  size_t off = 0;
  auto take = [&](size_t bytes) -> char* {
    char* r = p + off;
    off += (bytes + 255) & ~(size_t)255;
    return r;
  };
  int8_t* qx = (int8_t*)take((size_t)T_TOKENS * DM);
  float* sx = (float*)take((size_t)T_TOKENS * 4);
  int8_t* qw_qkv = (int8_t*)take((size_t)QKVN * DM);
  float* sw_qkv = (float*)take((size_t)QKVN * 4);
  int8_t* qw_wo = (int8_t*)take((size_t)DM * QDIM);
  float* sw_wo = (float*)take((size_t)DM * 4);
  int8_t* qw_gu = (int8_t*)take((size_t)GUN * DM);
  float* sw_gu = (float*)take((size_t)GUN * 4);
  int8_t* qw_dn = (int8_t*)take((size_t)DM * INTER);
  float* sw_dn = (float*)take((size_t)DM * 4);
  float* cosT = (float*)take((size_t)SEQ * 64 * 4);
  float* sinT = (float*)take((size_t)SEQ * 64 * 4);
  float* x1 = (float*)take((size_t)T_TOKENS * DM * 4);
  float* s_act = (float*)take(1024 * 4);
  // region B: phase1 = qkv[T,4096]f32 + attn_out[T,2048]f32 ; phase2 = gu[1024,16384]f32 + act[1024,8192]i8
  char* regB = take((size_t)T_TOKENS * QKVN * 4 + (size_t)T_TOKENS * QDIM * 4);
  float* qkv = (float*)regB;
  float* attn_out = (float*)(regB + (size_t)T_TOKENS * QKVN * 4);
  float* gu = (float*)regB;
  int8_t* act_q8 = (int8_t*)(regB + (size_t)1024 * GUN * 4);

  rope_table_kernel<<<SEQ, 64, 0, stream>>>(cosT, sinT);
  quant_w_kernel<<<QKVN, 256, 0, stream>>>(wqkv, qw_qkv, sw_qkv, DM);
  quant_w_kernel<<<DM, 256, 0, stream>>>(wo, qw_wo, sw_wo, QDIM);
  quant_w_kernel<<<GUN, 256, 0, stream>>>(w_gate_up, qw_gu, sw_gu, DM);
  quant_w_kernel<<<DM, 256, 0, stream>>>(w_down, qw_dn, sw_dn, INTER);

  // attention block
  rmsnorm_quant_kernel<<<T_TOKENS, 256, 0, stream>>>(hidden, w_in_norm, qx, sx);
  gemm_i8_kernel<<<dim3(QKVN / 128, T_TOKENS / 128), 256, 0, stream>>>(qx, sx, qw_qkv, sw_qkv,
                                                                       nullptr, qkv, QKVN, DM);
  rope_apply_kernel<<<T_TOKENS, 256, 0, stream>>>(qkv, cosT, sinT);
  attn_kernel<<<dim3(SEQ / 32, 32), 256, 0, stream>>>(qkv, attn_out);
  quant_rows_2048_kernel<<<T_TOKENS, 256, 0, stream>>>(attn_out, qx, sx);
  gemm_i8_kernel<<<dim3(DM / 128, T_TOKENS / 128), 256, 0, stream>>>(qx, sx, qw_wo, sw_wo, hidden,
                                                                     x1, DM, QDIM);

  // MLP block (chunked over tokens: 4 x 1024 rows)
  rmsnorm_quant_kernel<<<T_TOKENS, 256, 0, stream>>>(x1, w_post_norm, qx, sx);
  for (int ch = 0; ch < 4; ++ch) {
    const int8_t* qxc = qx + (size_t)ch * 1024 * DM;
    const float* sxc = sx + (size_t)ch * 1024;
    gemm_i8_kernel<<<dim3(GUN / 128, 1024 / 128), 256, 0, stream>>>(qxc, sxc, qw_gu, sw_gu,
                                                                    nullptr, gu, GUN, DM);
    gelu_mul_quant_kernel<<<1024, 256, 0, stream>>>(gu, act_q8, s_act);
    gemm_i8_kernel<<<dim3(DM / 128, 1024 / 128), 256, 0, stream>>>(
        act_q8, s_act, qw_dn, sw_dn, x1 + (size_t)ch * 1024 * DM, out + (size_t)ch * 1024 * DM, DM,
        INTER);
  }
}

// Round 2
// 1626.715 us; speedup vs baseline: 1.8211x; 1.8211x over previous
//
#include <hip/hip_runtime.h>
#include <cstdint>
#include <math.h>

#define T_TOKENS 4096
#define SEQ 2048
#define DM 2048
#define NH 16
#define NKV 8
#define HD 128
#define QDIM 2048   // NH*HD
#define KVDIM 1024  // NKV*HD
#define QKVN 4096   // QDIM + 2*KVDIM
#define INTER 8192
#define GUN 16384   // 2*INTER

typedef int v4i __attribute__((ext_vector_type(4)));
typedef float v4f __attribute__((ext_vector_type(4)));
typedef short s8v __attribute__((ext_vector_type(8)));
typedef short s4v __attribute__((ext_vector_type(4)));

__device__ inline float wave_sum(float v) {
#pragma unroll
  for (int off = 32; off > 0; off >>= 1) v += __shfl_down(v, off);
  return v;
}
__device__ inline float wave_max(float v) {
#pragma unroll
  for (int off = 32; off > 0; off >>= 1) v = fmaxf(v, __shfl_down(v, off));
  return v;
}
__device__ inline float dot4(float4 a, float4 b) {
  return a.x * b.x + a.y * b.y + a.z * b.z + a.w * b.w;
}
__device__ inline int8_t quant1(float v, float s) {
  float q = rintf(v / s);
  q = fminf(fmaxf(q, -127.f), 127.f);
  return (int8_t)(int)q;
}
__device__ inline unsigned short f2bf_rne(float x) {
  unsigned u = __float_as_uint(x);
  return (unsigned short)((u + 0x7FFFu + ((u >> 16) & 1u)) >> 16);
}
__device__ inline float bf2f(unsigned short h) { return __uint_as_float(((unsigned)h) << 16); }

// ---------------- RoPE tables ----------------
__global__ void rope_table_kernel(float* __restrict__ cosT, float* __restrict__ sinT) {
  int s = blockIdx.x, d = threadIdx.x;  // 64 threads
  float inv = 1.0f / powf(10000.0f, (float)d * (1.0f / 64.0f));
  float f = (float)s * inv;
  cosT[s * 64 + d] = cosf(f);
  sinT[s * 64 + d] = sinf(f);
}

// ---------------- per-row weight quant (2-pass) ----------------
__global__ __launch_bounds__(256) void quant_w_kernel(const float* __restrict__ w,
                                                      int8_t* __restrict__ qw,
                                                      float* __restrict__ sw, int K) {
  __shared__ float red[4];
  int row = blockIdx.x, tid = threadIdx.x;
  const float* wr = w + (size_t)row * K;
  float mx = 0.f;
  for (int i = tid * 4; i < K; i += 1024) {
    float4 v = *(const float4*)(wr + i);
    mx = fmaxf(mx, fmaxf(fmaxf(fabsf(v.x), fabsf(v.y)), fmaxf(fabsf(v.z), fabsf(v.w))));
  }
  mx = wave_max(mx);
  if ((tid & 63) == 0) red[tid >> 6] = mx;
  __syncthreads();
  float m = fmaxf(fmaxf(red[0], red[1]), fmaxf(red[2], red[3]));
  float s = m * (1.0f / 127.0f);
  if (tid == 0) sw[row] = s;
  float sd = (s > 0.f) ? s : 1.f;
  int8_t* qr = qw + (size_t)row * K;
  for (int i = tid * 4; i < K; i += 1024) {
    float4 v = *(const float4*)(wr + i);
    char4 o;
    o.x = quant1(v.x, sd);
    o.y = quant1(v.y, sd);
    o.z = quant1(v.z, sd);
    o.w = quant1(v.w, sd);
    *(char4*)(qr + i) = o;
  }
}

// ---------------- RMSNorm + per-token quant ----------------
__global__ __launch_bounds__(256) void rmsnorm_quant_kernel(const float* __restrict__ x,
                                                            const float* __restrict__ w,
                                                            int8_t* __restrict__ q,
                                                            float* __restrict__ s) {
  __shared__ float red[8];
  int t = blockIdx.x, tid = threadIdx.x;
  const float* xr = x + (size_t)t * DM;
  float4 a = *(const float4*)(xr + tid * 8);
  float4 b = *(const float4*)(xr + tid * 8 + 4);
  float ss = dot4(a, a) + dot4(b, b);
  ss = wave_sum(ss);
  if ((tid & 63) == 0) red[tid >> 6] = ss;
  __syncthreads();
  float tot = red[0] + red[1] + red[2] + red[3];
  float rms = rsqrtf(tot * (1.0f / DM) + 1e-6f);
  float4 wa = *(const float4*)(w + tid * 8);
  float4 wb = *(const float4*)(w + tid * 8 + 4);
  float y[8] = {a.x * rms * wa.x, a.y * rms * wa.y, a.z * rms * wa.z, a.w * rms * wa.w,
                b.x * rms * wb.x, b.y * rms * wb.y, b.z * rms * wb.z, b.w * rms * wb.w};
  float mx = 0.f;
#pragma unroll
  for (int i = 0; i < 8; i++) mx = fmaxf(mx, fabsf(y[i]));
  mx = wave_max(mx);
  if ((tid & 63) == 0) red[4 + (tid >> 6)] = mx;
  __syncthreads();
  float m = fmaxf(fmaxf(red[4], red[5]), fmaxf(red[6], red[7]));
  float sc = fmaxf(m * (1.0f / 127.0f), 1e-8f);
  if (tid == 0) s[t] = sc;
  int8_t* qr = q + (size_t)t * DM + tid * 8;
  char4 o0, o1;
  o0.x = quant1(y[0], sc); o0.y = quant1(y[1], sc); o0.z = quant1(y[2], sc); o0.w = quant1(y[3], sc);
  o1.x = quant1(y[4], sc); o1.y = quant1(y[5], sc); o1.z = quant1(y[6], sc); o1.w = quant1(y[7], sc);
  *(char4*)(qr) = o0;
  *(char4*)(qr + 4) = o1;
}

// ---------------- plain per-token quant of a [*,2048] f32 matrix ----------------
__global__ __launch_bounds__(256) void quant_rows_2048_kernel(const float* __restrict__ x,
                                                              int8_t* __restrict__ q,
                                                              float* __restrict__ s) {
  __shared__ float red[4];
  int t = blockIdx.x, tid = threadIdx.x;
  const float* xr = x + (size_t)t * DM;
  float4 a = *(const float4*)(xr + tid * 8);
  float4 b = *(const float4*)(xr + tid * 8 + 4);
  float y[8] = {a.x, a.y, a.z, a.w, b.x, b.y, b.z, b.w};
  float mx = 0.f;
#pragma unroll
  for (int i = 0; i < 8; i++) mx = fmaxf(mx, fabsf(y[i]));
  mx = wave_max(mx);
  if ((tid & 63) == 0) red[tid >> 6] = mx;
  __syncthreads();
  float m = fmaxf(fmaxf(red[0], red[1]), fmaxf(red[2], red[3]));
  float sc = fmaxf(m * (1.0f / 127.0f), 1e-8f);
  if (tid == 0) s[t] = sc;
  int8_t* qr = q + (size_t)t * DM + tid * 8;
  char4 o0, o1;
  o0.x = quant1(y[0], sc); o0.y = quant1(y[1], sc); o0.z = quant1(y[2], sc); o0.w = quant1(y[3], sc);
  o1.x = quant1(y[4], sc); o1.y = quant1(y[5], sc); o1.z = quant1(y[6], sc); o1.w = quant1(y[7], sc);
  *(char4*)(qr) = o0;
  *(char4*)(qr + 4) = o1;
}

// ---------------- gelu(gate)*up + per-token quant (INTER=8192) ----------------
__global__ __launch_bounds__(256) void gelu_mul_quant_kernel(const float* __restrict__ gu,
                                                             int8_t* __restrict__ q,
                                                             float* __restrict__ s) {
  __shared__ float red[4];
  int t = blockIdx.x, tid = threadIdx.x;
  const float* g = gu + (size_t)t * GUN;
  const float* u = g + INTER;
  float act[32];
  float mx = 0.f;
#pragma unroll
  for (int i4 = 0; i4 < 32; i4 += 4) {
    float4 gv = *(const float4*)(g + tid * 32 + i4);
    float4 uv = *(const float4*)(u + tid * 32 + i4);
    float gg[4] = {gv.x, gv.y, gv.z, gv.w};
    float uu[4] = {uv.x, uv.y, uv.z, uv.w};
#pragma unroll
    for (int j = 0; j < 4; j++) {
      float xx = gg[j];
      float inner = 0.7978845608028654f * (xx + 0.044715f * xx * xx * xx);
      float gl = 0.5f * xx * (1.0f + tanhf(inner));
      float av = gl * uu[j];
      act[i4 + j] = av;
      mx = fmaxf(mx, fabsf(av));
    }
  }
  mx = wave_max(mx);
  if ((tid & 63) == 0) red[tid >> 6] = mx;
  __syncthreads();
  float m = fmaxf(fmaxf(red[0], red[1]), fmaxf(red[2], red[3]));
  float sc = fmaxf(m * (1.0f / 127.0f), 1e-8f);
  if (tid == 0) s[t] = sc;
  int8_t* qr = q + (size_t)t * INTER + tid * 32;
#pragma unroll
  for (int i4 = 0; i4 < 32; i4 += 4) {
    char4 o;
    o.x = quant1(act[i4], sc);
    o.y = quant1(act[i4 + 1], sc);
    o.z = quant1(act[i4 + 2], sc);
    o.w = quant1(act[i4 + 3], sc);
    *(char4*)(qr + i4) = o;
  }
}

// ---------------- RoPE apply (in-place on q,k cols of qkv) ----------------
__global__ __launch_bounds__(256) void rope_apply_kernel(float* __restrict__ qkv,
                                                         const float* __restrict__ cosT,
                                                         const float* __restrict__ sinT) {
  int t = blockIdx.x, tid = threadIdx.x;
  int sp = t & (SEQ - 1);
  float* base = qkv + (size_t)t * QKVN;
#pragma unroll
  for (int it = 0; it < 6; ++it) {
    int p = tid + it * 256;  // 1536 pairs: 24 heads x 64
    int hh = p >> 6, d = p & 63;
    float* ptr = base + (hh < NH ? hh * HD : QDIM + (hh - NH) * HD);
    float c = cosT[sp * 64 + d], sn = sinT[sp * 64 + d];
    float x0 = ptr[d], x1 = ptr[d + 64];
    ptr[d] = x0 * c - x1 * sn;
    ptr[d + 64] = x1 * c + x0 * sn;
  }
}

// ---------------- int8 GEMM: C[M,N] = (qA[M,K] @ qB[N,K]^T) * sA * sB (+res) ----------------
__global__ __launch_bounds__(256) void gemm_i8_kernel(const int8_t* __restrict__ A,
                                                      const float* __restrict__ sA,
                                                      const int8_t* __restrict__ B,
                                                      const float* __restrict__ sB,
                                                      const float* __restrict__ res,
                                                      float* __restrict__ C, int N, int K) {
  __shared__ __align__(16) int8_t lA[128][80];
  __shared__ __align__(16) int8_t lB[128][80];
  int tid = threadIdx.x;
  int row0 = blockIdx.y * 128;
  int col0 = blockIdx.x * 128;
  int lane = tid & 63, wid = tid >> 6;
  int wm = (wid >> 1) * 64, wn = (wid & 1) * 64;
  int fr = lane & 15, fk = (lane >> 4) * 16;
  int srow = tid >> 2, soff = (tid & 3) * 16;

  v4i acc[4][4];
#pragma unroll
  for (int m = 0; m < 4; m++)
#pragma unroll
    for (int n = 0; n < 4; n++) acc[m][n] = (v4i){0, 0, 0, 0};

  const int8_t* A0 = A + (size_t)(row0 + srow) * K + soff;
  const int8_t* A1 = A + (size_t)(row0 + srow + 64) * K + soff;
  const int8_t* B0 = B + (size_t)(col0 + srow) * K + soff;
  const int8_t* B1 = B + (size_t)(col0 + srow + 64) * K + soff;

  for (int k0 = 0; k0 < K; k0 += 64) {
    *(v4i*)&lA[srow][soff] = *(const v4i*)(A0 + k0);
    *(v4i*)&lA[srow + 64][soff] = *(const v4i*)(A1 + k0);
    *(v4i*)&lB[srow][soff] = *(const v4i*)(B0 + k0);
    *(v4i*)&lB[srow + 64][soff] = *(const v4i*)(B1 + k0);
    __syncthreads();
    v4i a[4], b[4];
#pragma unroll
    for (int m = 0; m < 4; m++) a[m] = *(const v4i*)&lA[wm + m * 16 + fr][fk];
#pragma unroll
    for (int n = 0; n < 4; n++) b[n] = *(const v4i*)&lB[wn + n * 16 + fr][fk];
#pragma unroll
    for (int m = 0; m < 4; m++)
#pragma unroll
      for (int n = 0; n < 4; n++)
        acc[m][n] = __builtin_amdgcn_mfma_i32_16x16x64_i8(a[m], b[n], acc[m][n], 0, 0, 0);
    __syncthreads();
  }
  int rj = (lane >> 4) * 4;
  int cn = lane & 15;
#pragma unroll
  for (int m = 0; m < 4; m++) {
#pragma unroll
    for (int j = 0; j < 4; j++) {
      int rl = row0 + wm + m * 16 + rj + j;
      float sa = sA[rl];
      size_t rowoff = (size_t)rl * N;
#pragma unroll
      for (int n = 0; n < 4; n++) {
        int cg = col0 + wn + n * 16 + cn;
        float v = (float)acc[m][n][j] * sa * sB[cg];
        if (res) v += res[rowoff + cg];
        C[rowoff + cg] = v;
      }
    }
  }
}

// ---------------- flash attention via bf16 MFMA with hi/lo split (f32-accurate) ----------------
// 4 waves/block, 64 q rows/block (16 per wave), 32-wide KV tiles.
// Fragment convention (16x16x32): operand "row" = lane&15, k-elem = (lane>>4)*8+e.
// C/D: col = lane&15, row = (lane>>4)*4 + j.
#define KPAD 136
#define VPAD 40
#define PPAD 40

__global__ __launch_bounds__(256, 3) void attn_mfma_kernel(const float* __restrict__ qkv,
                                                           float* __restrict__ out) {
  __shared__ unsigned short khi[32][KPAD], klo[32][KPAD];
  __shared__ unsigned short vhi[128][VPAD], vlo[128][VPAD];
  __shared__ unsigned short phi[4][16][PPAD], plo[4][16][PPAD];

  int qt = (int)gridDim.x - 1 - (int)blockIdx.x;  // big tiles launch first
  int bh = blockIdx.y;
  int b = bh >> 4, h = bh & 15, g = h >> 1;
  int tid = threadIdx.x;
  int lane = tid & 63, w = tid >> 6;
  int lr = lane & 15, lq = lane >> 4;
  int qbase = qt * 64 + w * 16;

  // Q fragments (hi/lo), kept in registers for all KV tiles
  s8v qh[4], ql[4];
  {
    const float* qrow = qkv + (size_t)(b * SEQ + qbase + lr) * QKVN + h * HD;
#pragma unroll
    for (int c = 0; c < 4; ++c) {
      const float* src = qrow + c * 32 + lq * 8;
      float4 f0 = *(const float4*)(src);
      float4 f1 = *(const float4*)(src + 4);
      float ff[8] = {f0.x, f0.y, f0.z, f0.w, f1.x, f1.y, f1.z, f1.w};
      s8v hi, lo;
#pragma unroll
      for (int e = 0; e < 8; ++e) {
        unsigned short hb = f2bf_rne(ff[e]);
        hi[e] = (short)hb;
        lo[e] = (short)f2bf_rne(ff[e] - bf2f(hb));
      }
      qh[c] = hi;
      ql[c] = lo;
    }
  }

  v4f oacc[8];
#pragma unroll
  for (int i = 0; i < 8; ++i) oacc[i] = (v4f){0.f, 0.f, 0.f, 0.f};
  float mrun[4] = {-1e30f, -1e30f, -1e30f, -1e30f};
  float lsum[4] = {0.f, 0.f, 0.f, 0.f};

  const float kin = 0.0017677669529663687f;  // 1/(sqrt(128)*50)
  int ktmax = 2 * qt + 1;

  for (int kt = 0; kt <= ktmax; ++kt) {
    int kbase = kt * 32;
    __syncthreads();
    {
      // stage K row-major as bf16 hi/lo
      const float* kg = qkv + (size_t)(b * SEQ + kbase) * QKVN + QDIM + g * HD;
#pragma unroll
      for (int i = 0; i < 4; ++i) {
        int pos = tid + i * 256;
        int r = pos >> 5, c4 = (pos & 31) * 4;
        float4 f = *(const float4*)(kg + (size_t)r * QKVN + c4);
        float ff[4] = {f.x, f.y, f.z, f.w};
        s4v hi, lo;
#pragma unroll
        for (int e = 0; e < 4; ++e) {
          unsigned short hb = f2bf_rne(ff[e]);
          hi[e] = (short)hb;
          lo[e] = (short)f2bf_rne(ff[e] - bf2f(hb));
        }
        *(s4v*)&khi[r][c4] = hi;
        *(s4v*)&klo[r][c4] = lo;
      }
      // stage V transposed (column-segment mapping: coalesced global, b64 LDS writes)
      const float* vg = qkv + (size_t)(b * SEQ + kbase) * QKVN + QDIM + KVDIM + g * HD;
      int d = tid & 127;
      int kq = (tid >> 7) * 4;
#pragma unroll
      for (int i = 0; i < 4; ++i) {
        int k0 = kq + i * 8;
        s4v hi, lo;
#pragma unroll
        for (int j = 0; j < 4; ++j) {
          float x = vg[(size_t)(k0 + j) * QKVN + d];
          unsigned short hb = f2bf_rne(x);
          hi[j] = (short)hb;
          lo[j] = (short)f2bf_rne(x - bf2f(hb));
        }
        *(s4v*)&vhi[d][k0] = hi;
        *(s4v*)&vlo[d][k0] = lo;
      }
    }
    __syncthreads();
    if (kbase > qbase + 15) continue;  // fully masked for this wave

    // QK^T: two 16x16 score tiles, 3-term hi/lo split
    v4f sacc[2];
#pragma unroll
    for (int t2 = 0; t2 < 2; ++t2) {
      v4f s = (v4f){0.f, 0.f, 0.f, 0.f};
#pragma unroll
      for (int c = 0; c < 4; ++c) {
        s8v kh = *(const s8v*)&khi[t2 * 16 + lr][c * 32 + lq * 8];
        s8v kl = *(const s8v*)&klo[t2 * 16 + lr][c * 32 + lq * 8];
        s = __builtin_amdgcn_mfma_f32_16x16x32_bf16(qh[c], kh, s, 0, 0, 0);
        s = __builtin_amdgcn_mfma_f32_16x16x32_bf16(qh[c], kl, s, 0, 0, 0);
        s = __builtin_amdgcn_mfma_f32_16x16x32_bf16(ql[c], kh, s, 0, 0, 0);
      }
      sacc[t2] = s;
    }

    // softcap + causal mask + online softmax
    float c0[4], c1[4], mt[4];
#pragma unroll
    for (int j = 0; j < 4; ++j) {
      int qg = qbase + lq * 4 + j;
      int k0g = kbase + lr, k1g = kbase + 16 + lr;
      float z0 = __expf(2.f * (sacc[0][j] * kin));
      float z1 = __expf(2.f * (sacc[1][j] * kin));
      float t0 = 50.f - 100.f * __builtin_amdgcn_rcpf(z0 + 1.f);
      float t1 = 50.f - 100.f * __builtin_amdgcn_rcpf(z1 + 1.f);
      c0[j] = (k0g <= qg) ? t0 : -1e30f;
      c1[j] = (k1g <= qg) ? t1 : -1e30f;
      mt[j] = fmaxf(c0[j], c1[j]);
    }
#pragma unroll
    for (int st = 1; st <= 8; st <<= 1)
#pragma unroll
      for (int j = 0; j < 4; ++j) mt[j] = fmaxf(mt[j], __shfl_xor(mt[j], st));

    float al[4], rs[4];
#pragma unroll
    for (int j = 0; j < 4; ++j) {
      float mnew = fmaxf(mrun[j], mt[j]);
      al[j] = __expf(mrun[j] - mnew);
      mrun[j] = mnew;
      float e0 = __expf(c0[j] - mnew);
      float e1 = __expf(c1[j] - mnew);
      rs[j] = e0 + e1;
      int q = lq * 4 + j;
      unsigned short h0 = f2bf_rne(e0);
      unsigned short h1 = f2bf_rne(e1);
      phi[w][q][lr] = h0;
      phi[w][q][16 + lr] = h1;
      plo[w][q][lr] = f2bf_rne(e0 - bf2f(h0));
      plo[w][q][16 + lr] = f2bf_rne(e1 - bf2f(h1));
    }
#pragma unroll
    for (int st = 1; st <= 8; st <<= 1)
#pragma unroll
      for (int j = 0; j < 4; ++j) rs[j] += __shfl_xor(rs[j], st);
#pragma unroll
    for (int j = 0; j < 4; ++j) lsum[j] = lsum[j] * al[j] + rs[j];
#pragma unroll
    for (int dt = 0; dt < 8; ++dt)
#pragma unroll
      for (int j = 0; j < 4; ++j) oacc[dt][j] *= al[j];

    // P fragments back from wave-private LDS (same-wave DS ordering)
    s8v pah = *(const s8v*)&phi[w][lr][lq * 8];
    s8v pal = *(const s8v*)&plo[w][lr][lq * 8];
    // PV: out[q][d] += P * V ; V B-frag: row = d (lane&15), k-elems contiguous
#pragma unroll
    for (int dt = 0; dt < 8; ++dt) {
      s8v vh = *(const s8v*)&vhi[dt * 16 + lr][lq * 8];
      s8v vl = *(const s8v*)&vlo[dt * 16 + lr][lq * 8];
      v4f o = oacc[dt];
      o = __builtin_amdgcn_mfma_f32_16x16x32_bf16(pah, vh, o, 0, 0, 0);
      o = __builtin_amdgcn_mfma_f32_16x16x32_bf16(pah, vl, o, 0, 0, 0);
      o = __builtin_amdgcn_mfma_f32_16x16x32_bf16(pal, vh, o, 0, 0, 0);
      oacc[dt] = o;
    }
  }

  float inv[4];
#pragma unroll
  for (int j = 0; j < 4; ++j) inv[j] = 1.f / lsum[j];
  float* ob = out + (size_t)(b * SEQ + qbase) * QDIM + h * HD;
#pragma unroll
  for (int dt = 0; dt < 8; ++dt)
#pragma unroll
    for (int j = 0; j < 4; ++j)
      ob[(size_t)(lq * 4 + j) * QDIM + dt * 16 + lr] = oacc[dt][j] * inv[j];
}

extern "C" void kernel_launch(void* const* d_in, const int* in_sizes, int n_in, void* d_out,
                              int out_size, void* d_ws, size_t ws_size, hipStream_t stream) {
  (void)in_sizes; (void)n_in; (void)out_size; (void)ws_size;
  const float* hidden = (const float*)d_in[0];
  const float* w_in_norm = (const float*)d_in[1];
  const float* w_post_norm = (const float*)d_in[2];
  const float* wqkv = (const float*)d_in[3];
  const float* wo = (const float*)d_in[4];
  const float* w_gate_up = (const float*)d_in[5];
  const float* w_down = (const float*)d_in[6];
  float* out = (float*)d_out;

  char* p = (char*)d_ws;
  size_t off = 0;
  auto take = [&](size_t bytes) -> char* {
    char* r = p + off;
    off += (bytes + 255) & ~(size_t)255;
    return r;
  };
  int8_t* qx = (int8_t*)take((size_t)T_TOKENS * DM);
  float* sx = (float*)take((size_t)T_TOKENS * 4);
  int8_t* qw_qkv = (int8_t*)take((size_t)QKVN * DM);
  float* sw_qkv = (float*)take((size_t)QKVN * 4);
  int8_t* qw_wo = (int8_t*)take((size_t)DM * QDIM);
  float* sw_wo = (float*)take((size_t)DM * 4);
  int8_t* qw_gu = (int8_t*)take((size_t)GUN * DM);
  float* sw_gu = (float*)take((size_t)GUN * 4);
  int8_t* qw_dn = (int8_t*)take((size_t)DM * INTER);
  float* sw_dn = (float*)take((size_t)DM * 4);
  float* cosT = (float*)take((size_t)SEQ * 64 * 4);
  float* sinT = (float*)take((size_t)SEQ * 64 * 4);
  float* x1 = (float*)take((size_t)T_TOKENS * DM * 4);
  float* s_act = (float*)take(1024 * 4);
  // region B: phase1 = qkv[T,4096]f32 + attn_out[T,2048]f32 ; phase2 = gu[1024,16384]f32 + act[1024,8192]i8
  char* regB = take((size_t)T_TOKENS * QKVN * 4 + (size_t)T_TOKENS * QDIM * 4);
  float* qkv = (float*)regB;
  float* attn_out = (float*)(regB + (size_t)T_TOKENS * QKVN * 4);
  float* gu = (float*)regB;
  int8_t* act_q8 = (int8_t*)(regB + (size_t)1024 * GUN * 4);

  rope_table_kernel<<<SEQ, 64, 0, stream>>>(cosT, sinT);
  quant_w_kernel<<<QKVN, 256, 0, stream>>>(wqkv, qw_qkv, sw_qkv, DM);
  quant_w_kernel<<<DM, 256, 0, stream>>>(wo, qw_wo, sw_wo, QDIM);
  quant_w_kernel<<<GUN, 256, 0, stream>>>(w_gate_up, qw_gu, sw_gu, DM);
  quant_w_kernel<<<DM, 256, 0, stream>>>(w_down, qw_dn, sw_dn, INTER);

  // attention block
  rmsnorm_quant_kernel<<<T_TOKENS, 256, 0, stream>>>(hidden, w_in_norm, qx, sx);
  gemm_i8_kernel<<<dim3(QKVN / 128, T_TOKENS / 128), 256, 0, stream>>>(qx, sx, qw_qkv, sw_qkv,
                                                                       nullptr, qkv, QKVN, DM);
  rope_apply_kernel<<<T_TOKENS, 256, 0, stream>>>(qkv, cosT, sinT);
  attn_mfma_kernel<<<dim3(SEQ / 64, 32), 256, 0, stream>>>(qkv, attn_out);
  quant_rows_2048_kernel<<<T_TOKENS, 256, 0, stream>>>(attn_out, qx, sx);
  gemm_i8_kernel<<<dim3(DM / 128, T_TOKENS / 128), 256, 0, stream>>>(qx, sx, qw_wo, sw_wo, hidden,
                                                                     x1, DM, QDIM);

  // MLP block (chunked over tokens: 4 x 1024 rows)
  rmsnorm_quant_kernel<<<T_TOKENS, 256, 0, stream>>>(x1, w_post_norm, qx, sx);
  for (int ch = 0; ch < 4; ++ch) {
    const int8_t* qxc = qx + (size_t)ch * 1024 * DM;
    const float* sxc = sx + (size_t)ch * 1024;
    gemm_i8_kernel<<<dim3(GUN / 128, 1024 / 128), 256, 0, stream>>>(qxc, sxc, qw_gu, sw_gu,
                                                                    nullptr, gu, GUN, DM);
    gelu_mul_quant_kernel<<<1024, 256, 0, stream>>>(gu, act_q8, s_act);
    gemm_i8_kernel<<<dim3(DM / 128, 1024 / 128), 256, 0, stream>>>(
        act_q8, s_act, qw_dn, sw_dn, x1 + (size_t)ch * 1024 * DM, out + (size_t)ch * 1024 * DM, DM,
        INTER);
  }
}

// Round 3
// 1477.198 us; speedup vs baseline: 2.0054x; 1.1012x over previous
//
#include <hip/hip_runtime.h>
#include <cstdint>
#include <math.h>

#define T_TOKENS 4096
#define SEQ 2048
#define DM 2048
#define NH 16
#define NKV 8
#define HD 128
#define QDIM 2048   // NH*HD
#define KVDIM 1024  // NKV*HD
#define QKVN 4096   // QDIM + 2*KVDIM
#define INTER 8192
#define GUN 16384   // 2*INTER

typedef int v4i __attribute__((ext_vector_type(4)));
typedef float v4f __attribute__((ext_vector_type(4)));
typedef short s8v __attribute__((ext_vector_type(8)));
typedef short s4v __attribute__((ext_vector_type(4)));
typedef short s2v __attribute__((ext_vector_type(2)));

#define GL16(g, l)                                                                       \
  __builtin_amdgcn_global_load_lds((__attribute__((address_space(1))) const void*)(g),   \
                                   (__attribute__((address_space(3))) void*)(l), 16, 0, 0)

__device__ inline float wave_sum(float v) {
#pragma unroll
  for (int off = 32; off > 0; off >>= 1) v += __shfl_down(v, off);
  return v;
}
__device__ inline float wave_max(float v) {
#pragma unroll
  for (int off = 32; off > 0; off >>= 1) v = fmaxf(v, __shfl_down(v, off));
  return v;
}
__device__ inline float dot4(float4 a, float4 b) {
  return a.x * b.x + a.y * b.y + a.z * b.z + a.w * b.w;
}
__device__ inline int8_t quant1(float v, float s) {
  float q = rintf(v / s);
  q = fminf(fmaxf(q, -127.f), 127.f);
  return (int8_t)(int)q;
}
__device__ inline unsigned short f2bf_rne(float x) {
  unsigned u = __float_as_uint(x);
  return (unsigned short)((u + 0x7FFFu + ((u >> 16) & 1u)) >> 16);
}
__device__ inline float bf2f(unsigned short h) { return __uint_as_float(((unsigned)h) << 16); }

// ---------------- RoPE tables ----------------
__global__ void rope_table_kernel(float* __restrict__ cosT, float* __restrict__ sinT) {
  int s = blockIdx.x, d = threadIdx.x;  // 64 threads
  float inv = 1.0f / powf(10000.0f, (float)d * (1.0f / 64.0f));
  float f = (float)s * inv;
  cosT[s * 64 + d] = cosf(f);
  sinT[s * 64 + d] = sinf(f);
}

// ---------------- per-row weight quant (single-read, register cached) ----------------
__global__ __launch_bounds__(256) void quant_w_kernel(const float* __restrict__ w,
                                                      int8_t* __restrict__ qw,
                                                      float* __restrict__ sw, int K) {
  __shared__ float red[4];
  int row = blockIdx.x, tid = threadIdx.x;
  const float* wr = w + (size_t)row * K;
  int nv = K >> 10;  // float4s per thread (K / (256*4)): 2 for K=2048, 8 for K=8192
  float4 v[8];
  float mx = 0.f;
#pragma unroll
  for (int i = 0; i < 8; i++) {
    if (i < nv) {
      v[i] = *(const float4*)(wr + (size_t)(tid + i * 256) * 4);
      mx = fmaxf(mx, fmaxf(fmaxf(fabsf(v[i].x), fabsf(v[i].y)),
                           fmaxf(fabsf(v[i].z), fabsf(v[i].w))));
    }
  }
  mx = wave_max(mx);
  if ((tid & 63) == 0) red[tid >> 6] = mx;
  __syncthreads();
  float m = fmaxf(fmaxf(red[0], red[1]), fmaxf(red[2], red[3]));
  float s = m * (1.0f / 127.0f);
  if (tid == 0) sw[row] = s;
  float sd = (s > 0.f) ? s : 1.f;
  int8_t* qr = qw + (size_t)row * K;
#pragma unroll
  for (int i = 0; i < 8; i++) {
    if (i < nv) {
      char4 o;
      o.x = quant1(v[i].x, sd);
      o.y = quant1(v[i].y, sd);
      o.z = quant1(v[i].z, sd);
      o.w = quant1(v[i].w, sd);
      *(char4*)(qr + (size_t)(tid + i * 256) * 4) = o;
    }
  }
}

// ---------------- RMSNorm + per-token quant ----------------
__global__ __launch_bounds__(256) void rmsnorm_quant_kernel(const float* __restrict__ x,
                                                            const float* __restrict__ w,
                                                            int8_t* __restrict__ q,
                                                            float* __restrict__ s) {
  __shared__ float red[8];
  int t = blockIdx.x, tid = threadIdx.x;
  const float* xr = x + (size_t)t * DM;
  float4 a = *(const float4*)(xr + tid * 8);
  float4 b = *(const float4*)(xr + tid * 8 + 4);
  float ss = dot4(a, a) + dot4(b, b);
  ss = wave_sum(ss);
  if ((tid & 63) == 0) red[tid >> 6] = ss;
  __syncthreads();
  float tot = red[0] + red[1] + red[2] + red[3];
  float rms = rsqrtf(tot * (1.0f / DM) + 1e-6f);
  float4 wa = *(const float4*)(w + tid * 8);
  float4 wb = *(const float4*)(w + tid * 8 + 4);
  float y[8] = {a.x * rms * wa.x, a.y * rms * wa.y, a.z * rms * wa.z, a.w * rms * wa.w,
                b.x * rms * wb.x, b.y * rms * wb.y, b.z * rms * wb.z, b.w * rms * wb.w};
  float mx = 0.f;
#pragma unroll
  for (int i = 0; i < 8; i++) mx = fmaxf(mx, fabsf(y[i]));
  mx = wave_max(mx);
  if ((tid & 63) == 0) red[4 + (tid >> 6)] = mx;
  __syncthreads();
  float m = fmaxf(fmaxf(red[4], red[5]), fmaxf(red[6], red[7]));
  float sc = fmaxf(m * (1.0f / 127.0f), 1e-8f);
  if (tid == 0) s[t] = sc;
  int8_t* qr = q + (size_t)t * DM + tid * 8;
  char4 o0, o1;
  o0.x = quant1(y[0], sc); o0.y = quant1(y[1], sc); o0.z = quant1(y[2], sc); o0.w = quant1(y[3], sc);
  o1.x = quant1(y[4], sc); o1.y = quant1(y[5], sc); o1.z = quant1(y[6], sc); o1.w = quant1(y[7], sc);
  *(char4*)(qr) = o0;
  *(char4*)(qr + 4) = o1;
}

// ---------------- plain per-token quant of a [*,2048] f32 matrix ----------------
__global__ __launch_bounds__(256) void quant_rows_2048_kernel(const float* __restrict__ x,
                                                              int8_t* __restrict__ q,
                                                              float* __restrict__ s) {
  __shared__ float red[4];
  int t = blockIdx.x, tid = threadIdx.x;
  const float* xr = x + (size_t)t * DM;
  float4 a = *(const float4*)(xr + tid * 8);
  float4 b = *(const float4*)(xr + tid * 8 + 4);
  float y[8] = {a.x, a.y, a.z, a.w, b.x, b.y, b.z, b.w};
  float mx = 0.f;
#pragma unroll
  for (int i = 0; i < 8; i++) mx = fmaxf(mx, fabsf(y[i]));
  mx = wave_max(mx);
  if ((tid & 63) == 0) red[tid >> 6] = mx;
  __syncthreads();
  float m = fmaxf(fmaxf(red[0], red[1]), fmaxf(red[2], red[3]));
  float sc = fmaxf(m * (1.0f / 127.0f), 1e-8f);
  if (tid == 0) s[t] = sc;
  int8_t* qr = q + (size_t)t * DM + tid * 8;
  char4 o0, o1;
  o0.x = quant1(y[0], sc); o0.y = quant1(y[1], sc); o0.z = quant1(y[2], sc); o0.w = quant1(y[3], sc);
  o1.x = quant1(y[4], sc); o1.y = quant1(y[5], sc); o1.z = quant1(y[6], sc); o1.w = quant1(y[7], sc);
  *(char4*)(qr) = o0;
  *(char4*)(qr + 4) = o1;
}

// ---------------- gelu(gate)*up + per-token quant (INTER=8192) ----------------
__global__ __launch_bounds__(256) void gelu_mul_quant_kernel(const float* __restrict__ gu,
                                                             int8_t* __restrict__ q,
                                                             float* __restrict__ s) {
  __shared__ float red[4];
  int t = blockIdx.x, tid = threadIdx.x;
  const float* g = gu + (size_t)t * GUN;
  const float* u = g + INTER;
  float act[32];
  float mx = 0.f;
#pragma unroll
  for (int i4 = 0; i4 < 32; i4 += 4) {
    float4 gv = *(const float4*)(g + tid * 32 + i4);
    float4 uv = *(const float4*)(u + tid * 32 + i4);
    float gg[4] = {gv.x, gv.y, gv.z, gv.w};
    float uu[4] = {uv.x, uv.y, uv.z, uv.w};
#pragma unroll
    for (int j = 0; j < 4; j++) {
      float xx = gg[j];
      float inner = 0.7978845608028654f * (xx + 0.044715f * xx * xx * xx);
      float gl = 0.5f * xx * (1.0f + tanhf(inner));
      float av = gl * uu[j];
      act[i4 + j] = av;
      mx = fmaxf(mx, fabsf(av));
    }
  }
  mx = wave_max(mx);
  if ((tid & 63) == 0) red[tid >> 6] = mx;
  __syncthreads();
  float m = fmaxf(fmaxf(red[0], red[1]), fmaxf(red[2], red[3]));
  float sc = fmaxf(m * (1.0f / 127.0f), 1e-8f);
  if (tid == 0) s[t] = sc;
  int8_t* qr = q + (size_t)t * INTER + tid * 32;
#pragma unroll
  for (int i4 = 0; i4 < 32; i4 += 4) {
    char4 o;
    o.x = quant1(act[i4], sc);
    o.y = quant1(act[i4 + 1], sc);
    o.z = quant1(act[i4 + 2], sc);
    o.w = quant1(act[i4 + 3], sc);
    *(char4*)(qr + i4) = o;
  }
}

// ---------------- RoPE + f32->bf16 hi/lo conversion: Q ----------------
__global__ __launch_bounds__(256) void cvt_q_kernel(const float* __restrict__ qf,
                                                    const float* __restrict__ cosT,
                                                    const float* __restrict__ sinT,
                                                    unsigned short* __restrict__ Qhi,
                                                    unsigned short* __restrict__ Qlo) {
  int t = blockIdx.x, tid = threadIdx.x;
  int sp = t & (SEQ - 1);
  int h = tid >> 4, pb = (tid & 15) * 4;
  const float* row = qf + (size_t)t * QDIM + h * HD;
  float4 x0 = *(const float4*)(row + pb);
  float4 x1 = *(const float4*)(row + pb + 64);
  float4 c = *(const float4*)(cosT + sp * 64 + pb);
  float4 s = *(const float4*)(sinT + sp * 64 + pb);
  float y0[4] = {x0.x * c.x - x1.x * s.x, x0.y * c.y - x1.y * s.y, x0.z * c.z - x1.z * s.z,
                 x0.w * c.w - x1.w * s.w};
  float y1[4] = {x1.x * c.x + x0.x * s.x, x1.y * c.y + x0.y * s.y, x1.z * c.z + x0.z * s.z,
                 x1.w * c.w + x0.w * s.w};
  s4v h0, l0, h1, l1;
#pragma unroll
  for (int e = 0; e < 4; e++) {
    unsigned short hb = f2bf_rne(y0[e]);
    h0[e] = (short)hb;
    l0[e] = (short)f2bf_rne(y0[e] - bf2f(hb));
    hb = f2bf_rne(y1[e]);
    h1[e] = (short)hb;
    l1[e] = (short)f2bf_rne(y1[e] - bf2f(hb));
  }
  size_t o = (size_t)t * QDIM + h * HD + pb;
  *(s4v*)&Qhi[o] = h0;
  *(s4v*)&Qlo[o] = l0;
  *(s4v*)&Qhi[o + 64] = h1;
  *(s4v*)&Qlo[o + 64] = l1;
}

// ---------------- RoPE + conversion: K (layout [(b,g)][s][d]) ----------------
__global__ __launch_bounds__(256) void cvt_k_kernel(const float* __restrict__ kvf,
                                                    const float* __restrict__ cosT,
                                                    const float* __restrict__ sinT,
                                                    unsigned short* __restrict__ Khi,
                                                    unsigned short* __restrict__ Klo) {
  int t = blockIdx.x, tid = threadIdx.x;
  int sp = t & (SEQ - 1);
  int b = t >> 11;
  int g = tid >> 5, pb = (tid & 31) * 2;
  const float* row = kvf + (size_t)t * DM + g * HD;
  float2 x0 = *(const float2*)(row + pb);
  float2 x1 = *(const float2*)(row + pb + 64);
  float2 c = *(const float2*)(cosT + sp * 64 + pb);
  float2 s = *(const float2*)(sinT + sp * 64 + pb);
  float y0[2] = {x0.x * c.x - x1.x * s.x, x0.y * c.y - x1.y * s.y};
  float y1[2] = {x1.x * c.x + x0.x * s.x, x1.y * c.y + x0.y * s.y};
  s2v h0, l0, h1, l1;
#pragma unroll
  for (int e = 0; e < 2; e++) {
    unsigned short hb = f2bf_rne(y0[e]);
    h0[e] = (short)hb;
    l0[e] = (short)f2bf_rne(y0[e] - bf2f(hb));
    hb = f2bf_rne(y1[e]);
    h1[e] = (short)hb;
    l1[e] = (short)f2bf_rne(y1[e] - bf2f(hb));
  }
  size_t o = ((size_t)(b * NKV + g) * SEQ + sp) * HD + pb;
  *(s2v*)&Khi[o] = h0;
  *(s2v*)&Klo[o] = l0;
  *(s2v*)&Khi[o + 64] = h1;
  *(s2v*)&Klo[o + 64] = l1;
}

// ---------------- V transpose + conversion: Vt layout [(b,g)][d][s] bf16 ----------------
__global__ __launch_bounds__(256) void cvt_v_kernel(const float* __restrict__ kvf,
                                                    unsigned short* __restrict__ Vt) {
  __shared__ float vt[32][132];
  int bg = blockIdx.y;
  int b = bg >> 3, g = bg & 7;
  int s0 = blockIdx.x * 32;
  int tid = threadIdx.x;
#pragma unroll
  for (int i = 0; i < 4; i++) {
    int pos = tid + i * 256;
    int r = pos >> 5, d4 = (pos & 31) * 4;
    *(float4*)&vt[r][d4] =
        *(const float4*)(kvf + (size_t)(b * SEQ + s0 + r) * DM + KVDIM + g * HD + d4);
  }
  __syncthreads();
  int d = tid & 127, half = tid >> 7;
  unsigned short u[16];
#pragma unroll
  for (int i = 0; i < 16; i++) u[i] = f2bf_rne(vt[half * 16 + i][d]);
  unsigned short* dst = Vt + ((size_t)bg * HD + d) * SEQ + s0 + half * 16;
  *(s8v*)dst = *(s8v*)&u[0];
  *(s8v*)(dst + 8) = *(s8v*)&u[8];
}

// ---------------- int8 GEMM (global_load_lds + XOR swizzle, 128x128, BK=64) ----------------
__global__ __launch_bounds__(256) void gemm_i8_kernel(const int8_t* __restrict__ A,
                                                      const float* __restrict__ sA,
                                                      const int8_t* __restrict__ B,
                                                      const float* __restrict__ sB,
                                                      const float* __restrict__ res,
                                                      float* __restrict__ C, int N, int K) {
  __shared__ __align__(16) int8_t lA[8192];
  __shared__ __align__(16) int8_t lB[8192];
  int tid = threadIdx.x;
  int row0 = blockIdx.y * 128;
  int col0 = blockIdx.x * 128;
  int lane = tid & 63, wid = tid >> 6;
  int wm = (wid >> 1) * 64, wn = (wid & 1) * 64;
  int fr = lane & 15, lq = lane >> 4;

  // staging geometry: wave wid covers LDS rows [wid*32, wid*32+32), two 16-row issues
  int rS = wid * 32 + (lane >> 2);                 // j=0 row; j=1 is rS+16 (same &3)
  int cS = ((lane & 3) ^ (rS & 3)) << 4;           // inverse-swizzled source chunk
  const int8_t* gA0 = A + (size_t)(row0 + rS) * K + cS;
  const int8_t* gA1 = A + (size_t)(row0 + rS + 16) * K + cS;
  const int8_t* gB0 = B + (size_t)(col0 + rS) * K + cS;
  const int8_t* gB1 = B + (size_t)(col0 + rS + 16) * K + cS;
  int8_t* lA0 = &lA[wid * 2048];
  int8_t* lA1 = &lA[wid * 2048 + 1024];
  int8_t* lB0 = &lB[wid * 2048];
  int8_t* lB1 = &lB[wid * 2048 + 1024];

  // fragment read offsets (swizzled)
  int aoff[4], boff[4];
#pragma unroll
  for (int m = 0; m < 4; m++) {
    int r = wm + m * 16 + fr;
    aoff[m] = r * 64 + ((lq ^ (r & 3)) << 4);
    r = wn + m * 16 + fr;
    boff[m] = r * 64 + ((lq ^ (r & 3)) << 4);
  }

  v4i acc[4][4];
#pragma unroll
  for (int m = 0; m < 4; m++)
#pragma unroll
    for (int n = 0; n < 4; n++) acc[m][n] = (v4i){0, 0, 0, 0};

  for (int k0 = 0; k0 < K; k0 += 64) {
    GL16(gA0 + k0, lA0);
    GL16(gA1 + k0, lA1);
    GL16(gB0 + k0, lB0);
    GL16(gB1 + k0, lB1);
    __syncthreads();
    v4i a[4], b[4];
#pragma unroll
    for (int m = 0; m < 4; m++) a[m] = *(const v4i*)&lA[aoff[m]];
#pragma unroll
    for (int n = 0; n < 4; n++) b[n] = *(const v4i*)&lB[boff[n]];
#pragma unroll
    for (int m = 0; m < 4; m++)
#pragma unroll
      for (int n = 0; n < 4; n++)
        acc[m][n] = __builtin_amdgcn_mfma_i32_16x16x64_i8(a[m], b[n], acc[m][n], 0, 0, 0);
    __syncthreads();
  }
  int rj = lq * 4;
  int cn = fr;
#pragma unroll
  for (int m = 0; m < 4; m++) {
#pragma unroll
    for (int j = 0; j < 4; j++) {
      int rl = row0 + wm + m * 16 + rj + j;
      float sa = sA[rl];
      size_t rowoff = (size_t)rl * N;
#pragma unroll
      for (int n = 0; n < 4; n++) {
        int cg = col0 + wn + n * 16 + cn;
        float v = (float)acc[m][n][j] * sa * sB[cg];
        if (res) v += res[rowoff + cg];
        C[rowoff + cg] = v;
      }
    }
  }
}

// ---------------- flash attention: bf16 MFMA, fragments direct from global ----------------
// 4 waves/block, 64 q rows/block (16/wave), 32-wide KV tiles, no block barriers.
__global__ __launch_bounds__(256) void attn_mfma_kernel(
    const unsigned short* __restrict__ Qhi, const unsigned short* __restrict__ Qlo,
    const unsigned short* __restrict__ Khi, const unsigned short* __restrict__ Klo,
    const unsigned short* __restrict__ Vt, float* __restrict__ out) {
  __shared__ unsigned short ps[4][16][40];
  int qt = (int)gridDim.x - 1 - (int)blockIdx.x;  // big tiles first
  int bh = blockIdx.y;
  int b = bh >> 4, h = bh & 15, g = h >> 1;
  int bg = b * NKV + g;
  int tid = threadIdx.x;
  int lane = tid & 63, w = tid >> 6;
  int lr = lane & 15, lq = lane >> 4;
  int qbase = qt * 64 + w * 16;

  // Q fragments (hi/lo) in registers
  s8v qh[4], ql[4];
  {
    size_t qo = (size_t)(b * SEQ + qbase + lr) * QDIM + h * HD + lq * 8;
#pragma unroll
    for (int c = 0; c < 4; ++c) {
      qh[c] = *(const s8v*)(Qhi + qo + c * 32);
      ql[c] = *(const s8v*)(Qlo + qo + c * 32);
    }
  }

  v4f oacc[8];
#pragma unroll
  for (int i = 0; i < 8; ++i) oacc[i] = (v4f){0.f, 0.f, 0.f, 0.f};
  float mrun[4] = {-1e30f, -1e30f, -1e30f, -1e30f};
  float lsum[4] = {0.f, 0.f, 0.f, 0.f};
  const float kin = 0.0017677669529663687f;  // 1/(sqrt(128)*50)

  const unsigned short* kbh = Khi + (size_t)bg * SEQ * HD;
  const unsigned short* kbl = Klo + (size_t)bg * SEQ * HD;
  const unsigned short* vb = Vt + (size_t)bg * HD * SEQ;

  for (int kbase = 0; kbase <= qbase + 15; kbase += 32) {
    // QK^T: two 16x16 tiles, 3-term hi/lo
    v4f sacc[2];
#pragma unroll
    for (int t2 = 0; t2 < 2; ++t2) {
      v4f s = (v4f){0.f, 0.f, 0.f, 0.f};
      size_t ko = (size_t)(kbase + t2 * 16 + lr) * HD + lq * 8;
#pragma unroll
      for (int c = 0; c < 4; ++c) {
        s8v kh = *(const s8v*)(kbh + ko + c * 32);
        s8v kl = *(const s8v*)(kbl + ko + c * 32);
        s = __builtin_amdgcn_mfma_f32_16x16x32_bf16(qh[c], kh, s, 0, 0, 0);
        s = __builtin_amdgcn_mfma_f32_16x16x32_bf16(qh[c], kl, s, 0, 0, 0);
        s = __builtin_amdgcn_mfma_f32_16x16x32_bf16(ql[c], kh, s, 0, 0, 0);
      }
      sacc[t2] = s;
    }

    // softcap + causal mask + online softmax
    float c0[4], c1[4], mt[4];
#pragma unroll
    for (int j = 0; j < 4; ++j) {
      int qg = qbase + lq * 4 + j;
      int k0g = kbase + lr, k1g = kbase + 16 + lr;
      float z0 = __expf(2.f * (sacc[0][j] * kin));
      float z1 = __expf(2.f * (sacc[1][j] * kin));
      float t0 = 50.f - 100.f * __builtin_amdgcn_rcpf(z0 + 1.f);
      float t1 = 50.f - 100.f * __builtin_amdgcn_rcpf(z1 + 1.f);
      c0[j] = (k0g <= qg) ? t0 : -1e30f;
      c1[j] = (k1g <= qg) ? t1 : -1e30f;
      mt[j] = fmaxf(c0[j], c1[j]);
    }
#pragma unroll
    for (int st = 1; st <= 8; st <<= 1)
#pragma unroll
      for (int j = 0; j < 4; ++j) mt[j] = fmaxf(mt[j], __shfl_xor(mt[j], st));

    float al[4], rs[4];
#pragma unroll
    for (int j = 0; j < 4; ++j) {
      float mnew = fmaxf(mrun[j], mt[j]);
      al[j] = __expf(mrun[j] - mnew);
      mrun[j] = mnew;
      float e0 = __expf(c0[j] - mnew);
      float e1 = __expf(c1[j] - mnew);
      rs[j] = e0 + e1;
      int q = lq * 4 + j;
      ps[w][q][lr] = f2bf_rne(e0);
      ps[w][q][16 + lr] = f2bf_rne(e1);
    }
#pragma unroll
    for (int st = 1; st <= 8; st <<= 1)
#pragma unroll
      for (int j = 0; j < 4; ++j) rs[j] += __shfl_xor(rs[j], st);
#pragma unroll
    for (int j = 0; j < 4; ++j) lsum[j] = lsum[j] * al[j] + rs[j];
#pragma unroll
    for (int dt = 0; dt < 8; ++dt)
#pragma unroll
      for (int j = 0; j < 4; ++j) oacc[dt][j] *= al[j];

    s8v pa = *(const s8v*)&ps[w][lr][lq * 8];
#pragma unroll
    for (int dt = 0; dt < 8; ++dt) {
      s8v vh = *(const s8v*)(vb + (size_t)(dt * 16 + lr) * SEQ + kbase + lq * 8);
      oacc[dt] = __builtin_amdgcn_mfma_f32_16x16x32_bf16(pa, vh, oacc[dt], 0, 0, 0);
    }
  }

  float inv[4];
#pragma unroll
  for (int j = 0; j < 4; ++j) inv[j] = 1.f / lsum[j];
  float* ob = out + (size_t)(b * SEQ + qbase) * QDIM + h * HD;
#pragma unroll
  for (int dt = 0; dt < 8; ++dt)
#pragma unroll
    for (int j = 0; j < 4; ++j)
      ob[(size_t)(lq * 4 + j) * QDIM + dt * 16 + lr] = oacc[dt][j] * inv[j];
}

extern "C" void kernel_launch(void* const* d_in, const int* in_sizes, int n_in, void* d_out,
                              int out_size, void* d_ws, size_t ws_size, hipStream_t stream) {
  (void)in_sizes; (void)n_in; (void)out_size; (void)ws_size;
  const float* hidden = (const float*)d_in[0];
  const float* w_in_norm = (const float*)d_in[1];
  const float* w_post_norm = (const float*)d_in[2];
  const float* wqkv = (const float*)d_in[3];
  const float* wo = (const float*)d_in[4];
  const float* w_gate_up = (const float*)d_in[5];
  const float* w_down = (const float*)d_in[6];
  float* out = (float*)d_out;

  char* p = (char*)d_ws;
  size_t off = 0;
  auto take = [&](size_t bytes) -> char* {
    char* r = p + off;
    off += (bytes + 255) & ~(size_t)255;
    return r;
  };
  const size_t MB = 1u << 20;
  int8_t* qx = (int8_t*)take((size_t)T_TOKENS * DM);
  float* sx = (float*)take((size_t)T_TOKENS * 4);
  int8_t* qw_qkv = (int8_t*)take((size_t)QKVN * DM);
  float* sw_qkv = (float*)take((size_t)QKVN * 4);
  int8_t* qw_wo = (int8_t*)take((size_t)DM * QDIM);
  float* sw_wo = (float*)take((size_t)DM * 4);
  int8_t* qw_gu = (int8_t*)take((size_t)GUN * DM);
  float* sw_gu = (float*)take((size_t)GUN * 4);
  int8_t* qw_dn = (int8_t*)take((size_t)DM * INTER);
  float* sw_dn = (float*)take((size_t)DM * 4);
  float* cosT = (float*)take((size_t)SEQ * 64 * 4);
  float* sinT = (float*)take((size_t)SEQ * 64 * 4);
  float* x1 = (float*)take((size_t)T_TOKENS * DM * 4);
  float* s_act = (float*)take((size_t)T_TOKENS * 4);
  char* regB = take(96 * MB);
  // phase-1 layout within regB:
  float* qf32 = (float*)regB;                         // [0,32MB): Q f32 -> later KV f32 -> attn_out
  float* kvf32 = (float*)regB;                        //   (reused sequentially)
  float* attn_out = (float*)regB;
  unsigned short* Qhi = (unsigned short*)(regB + 32 * MB);   // 16MB
  unsigned short* Qlo = (unsigned short*)(regB + 48 * MB);   // 16MB
  unsigned short* Khi = (unsigned short*)(regB + 64 * MB);   // 8MB
  unsigned short* Klo = (unsigned short*)(regB + 72 * MB);   // 8MB
  unsigned short* Vt = (unsigned short*)(regB + 80 * MB);    // 8MB
  // phase-2 layout:
  float* gu = (float*)regB;                            // [0,64MB)
  int8_t* act_q8 = (int8_t*)(regB + 64 * MB);          // [64,96MB)

  rope_table_kernel<<<SEQ, 64, 0, stream>>>(cosT, sinT);
  quant_w_kernel<<<QKVN, 256, 0, stream>>>(wqkv, qw_qkv, sw_qkv, DM);
  quant_w_kernel<<<DM, 256, 0, stream>>>(wo, qw_wo, sw_wo, QDIM);
  quant_w_kernel<<<GUN, 256, 0, stream>>>(w_gate_up, qw_gu, sw_gu, DM);
  quant_w_kernel<<<DM, 256, 0, stream>>>(w_down, qw_dn, sw_dn, INTER);

  // attention block
  rmsnorm_quant_kernel<<<T_TOKENS, 256, 0, stream>>>(hidden, w_in_norm, qx, sx);
  // Q projection -> qf32, convert+rope -> bf16 planes
  gemm_i8_kernel<<<dim3(QDIM / 128, T_TOKENS / 128), 256, 0, stream>>>(qx, sx, qw_qkv, sw_qkv,
                                                                       nullptr, qf32, QDIM, DM);
  cvt_q_kernel<<<T_TOKENS, 256, 0, stream>>>(qf32, cosT, sinT, Qhi, Qlo);
  // KV projection -> kvf32 (reuses region A), convert
  gemm_i8_kernel<<<dim3(DM / 128, T_TOKENS / 128), 256, 0, stream>>>(
      qx, sx, qw_qkv + (size_t)QDIM * DM, sw_qkv + QDIM, nullptr, kvf32, DM, DM);
  cvt_k_kernel<<<T_TOKENS, 256, 0, stream>>>(kvf32, cosT, sinT, Khi, Klo);
  cvt_v_kernel<<<dim3(SEQ / 32, 16), 256, 0, stream>>>(kvf32, Vt);
  attn_mfma_kernel<<<dim3(SEQ / 64, 32), 256, 0, stream>>>(Qhi, Qlo, Khi, Klo, Vt, attn_out);
  quant_rows_2048_kernel<<<T_TOKENS, 256, 0, stream>>>(attn_out, qx, sx);
  gemm_i8_kernel<<<dim3(DM / 128, T_TOKENS / 128), 256, 0, stream>>>(qx, sx, qw_wo, sw_wo, hidden,
                                                                     x1, DM, QDIM);

  // MLP block: gate_up chunked (gu 64MB buffer), act_q8 kept full, single down GEMM
  rmsnorm_quant_kernel<<<T_TOKENS, 256, 0, stream>>>(x1, w_post_norm, qx, sx);
  for (int ch = 0; ch < 4; ++ch) {
    const int8_t* qxc = qx + (size_t)ch * 1024 * DM;
    const float* sxc = sx + (size_t)ch * 1024;
    gemm_i8_kernel<<<dim3(GUN / 128, 1024 / 128), 256, 0, stream>>>(qxc, sxc, qw_gu, sw_gu,
                                                                    nullptr, gu, GUN, DM);
    gelu_mul_quant_kernel<<<1024, 256, 0, stream>>>(gu, act_q8 + (size_t)ch * 1024 * INTER,
                                                    s_act + (size_t)ch * 1024);
  }
  gemm_i8_kernel<<<dim3(DM / 128, T_TOKENS / 128), 256, 0, stream>>>(act_q8, s_act, qw_dn, sw_dn,
                                                                     x1, out, DM, INTER);
}

// Round 4
// 1095.770 us; speedup vs baseline: 2.7035x; 1.3481x over previous
//
#include <hip/hip_runtime.h>
#include <cstdint>
#include <math.h>

#define T_TOKENS 4096
#define SEQ 2048
#define DM 2048
#define NH 16
#define NKV 8
#define HD 128
#define QDIM 2048   // NH*HD
#define KVDIM 1024  // NKV*HD
#define QKVN 4096   // QDIM + 2*KVDIM
#define INTER 8192
#define GUN 16384   // 2*INTER

typedef int v4i __attribute__((ext_vector_type(4)));
typedef float v4f __attribute__((ext_vector_type(4)));
typedef short s8v __attribute__((ext_vector_type(8)));
typedef short s4v __attribute__((ext_vector_type(4)));
typedef short s2v __attribute__((ext_vector_type(2)));

#define GL16(g, l)                                                                       \
  __builtin_amdgcn_global_load_lds((__attribute__((address_space(1))) const void*)(g),   \
                                   (__attribute__((address_space(3))) void*)(l), 16, 0, 0)

__device__ inline float wave_sum(float v) {
#pragma unroll
  for (int off = 32; off > 0; off >>= 1) v += __shfl_down(v, off);
  return v;
}
__device__ inline float wave_max(float v) {
#pragma unroll
  for (int off = 32; off > 0; off >>= 1) v = fmaxf(v, __shfl_down(v, off));
  return v;
}
__device__ inline float dot4(float4 a, float4 b) {
  return a.x * b.x + a.y * b.y + a.z * b.z + a.w * b.w;
}
__device__ inline int8_t quant1(float v, float s) {
  float q = rintf(v / s);
  q = fminf(fmaxf(q, -127.f), 127.f);
  return (int8_t)(int)q;
}
__device__ inline unsigned short f2bf_rne(float x) {
  unsigned u = __float_as_uint(x);
  return (unsigned short)((u + 0x7FFFu + ((u >> 16) & 1u)) >> 16);
}
__device__ inline float bf2f(unsigned short h) { return __uint_as_float(((unsigned)h) << 16); }

// ---------------- RoPE tables ----------------
__global__ void rope_table_kernel(float* __restrict__ cosT, float* __restrict__ sinT) {
  int s = blockIdx.x, d = threadIdx.x;  // 64 threads
  float inv = 1.0f / powf(10000.0f, (float)d * (1.0f / 64.0f));
  float f = (float)s * inv;
  cosT[s * 64 + d] = cosf(f);
  sinT[s * 64 + d] = sinf(f);
}

// ---------------- per-row weight quant (single-read, register cached) ----------------
__global__ __launch_bounds__(256) void quant_w_kernel(const float* __restrict__ w,
                                                      int8_t* __restrict__ qw,
                                                      float* __restrict__ sw, int K) {
  __shared__ float red[4];
  int row = blockIdx.x, tid = threadIdx.x;
  const float* wr = w + (size_t)row * K;
  int nv = K >> 10;  // float4s per thread
  float4 v[8];
  float mx = 0.f;
#pragma unroll
  for (int i = 0; i < 8; i++) {
    if (i < nv) {
      v[i] = *(const float4*)(wr + (size_t)(tid + i * 256) * 4);
      mx = fmaxf(mx, fmaxf(fmaxf(fabsf(v[i].x), fabsf(v[i].y)),
                           fmaxf(fabsf(v[i].z), fabsf(v[i].w))));
    }
  }
  mx = wave_max(mx);
  if ((tid & 63) == 0) red[tid >> 6] = mx;
  __syncthreads();
  float m = fmaxf(fmaxf(red[0], red[1]), fmaxf(red[2], red[3]));
  float s = m * (1.0f / 127.0f);
  if (tid == 0) sw[row] = s;
  float sd = (s > 0.f) ? s : 1.f;
  int8_t* qr = qw + (size_t)row * K;
#pragma unroll
  for (int i = 0; i < 8; i++) {
    if (i < nv) {
      char4 o;
      o.x = quant1(v[i].x, sd);
      o.y = quant1(v[i].y, sd);
      o.z = quant1(v[i].z, sd);
      o.w = quant1(v[i].w, sd);
      *(char4*)(qr + (size_t)(tid + i * 256) * 4) = o;
    }
  }
}

// ---------------- RMSNorm + per-token quant ----------------
__global__ __launch_bounds__(256) void rmsnorm_quant_kernel(const float* __restrict__ x,
                                                            const float* __restrict__ w,
                                                            int8_t* __restrict__ q,
                                                            float* __restrict__ s) {
  __shared__ float red[8];
  int t = blockIdx.x, tid = threadIdx.x;
  const float* xr = x + (size_t)t * DM;
  float4 a = *(const float4*)(xr + tid * 8);
  float4 b = *(const float4*)(xr + tid * 8 + 4);
  float ss = dot4(a, a) + dot4(b, b);
  ss = wave_sum(ss);
  if ((tid & 63) == 0) red[tid >> 6] = ss;
  __syncthreads();
  float tot = red[0] + red[1] + red[2] + red[3];
  float rms = rsqrtf(tot * (1.0f / DM) + 1e-6f);
  float4 wa = *(const float4*)(w + tid * 8);
  float4 wb = *(const float4*)(w + tid * 8 + 4);
  float y[8] = {a.x * rms * wa.x, a.y * rms * wa.y, a.z * rms * wa.z, a.w * rms * wa.w,
                b.x * rms * wb.x, b.y * rms * wb.y, b.z * rms * wb.z, b.w * rms * wb.w};
  float mx = 0.f;
#pragma unroll
  for (int i = 0; i < 8; i++) mx = fmaxf(mx, fabsf(y[i]));
  mx = wave_max(mx);
  if ((tid & 63) == 0) red[4 + (tid >> 6)] = mx;
  __syncthreads();
  float m = fmaxf(fmaxf(red[4], red[5]), fmaxf(red[6], red[7]));
  float sc = fmaxf(m * (1.0f / 127.0f), 1e-8f);
  if (tid == 0) s[t] = sc;
  int8_t* qr = q + (size_t)t * DM + tid * 8;
  char4 o0, o1;
  o0.x = quant1(y[0], sc); o0.y = quant1(y[1], sc); o0.z = quant1(y[2], sc); o0.w = quant1(y[3], sc);
  o1.x = quant1(y[4], sc); o1.y = quant1(y[5], sc); o1.z = quant1(y[6], sc); o1.w = quant1(y[7], sc);
  *(char4*)(qr) = o0;
  *(char4*)(qr + 4) = o1;
}

// ---------------- plain per-token quant of a [*,2048] f32 matrix ----------------
__global__ __launch_bounds__(256) void quant_rows_2048_kernel(const float* __restrict__ x,
                                                              int8_t* __restrict__ q,
                                                              float* __restrict__ s) {
  __shared__ float red[4];
  int t = blockIdx.x, tid = threadIdx.x;
  const float* xr = x + (size_t)t * DM;
  float4 a = *(const float4*)(xr + tid * 8);
  float4 b = *(const float4*)(xr + tid * 8 + 4);
  float y[8] = {a.x, a.y, a.z, a.w, b.x, b.y, b.z, b.w};
  float mx = 0.f;
#pragma unroll
  for (int i = 0; i < 8; i++) mx = fmaxf(mx, fabsf(y[i]));
  mx = wave_max(mx);
  if ((tid & 63) == 0) red[tid >> 6] = mx;
  __syncthreads();
  float m = fmaxf(fmaxf(red[0], red[1]), fmaxf(red[2], red[3]));
  float sc = fmaxf(m * (1.0f / 127.0f), 1e-8f);
  if (tid == 0) s[t] = sc;
  int8_t* qr = q + (size_t)t * DM + tid * 8;
  char4 o0, o1;
  o0.x = quant1(y[0], sc); o0.y = quant1(y[1], sc); o0.z = quant1(y[2], sc); o0.w = quant1(y[3], sc);
  o1.x = quant1(y[4], sc); o1.y = quant1(y[5], sc); o1.z = quant1(y[6], sc); o1.w = quant1(y[7], sc);
  *(char4*)(qr) = o0;
  *(char4*)(qr + 4) = o1;
}

// ---------------- gelu(gate)*up + per-token quant (INTER=8192) ----------------
__global__ __launch_bounds__(256) void gelu_mul_quant_kernel(const float* __restrict__ gu,
                                                             int8_t* __restrict__ q,
                                                             float* __restrict__ s) {
  __shared__ float red[4];
  int t = blockIdx.x, tid = threadIdx.x;
  const float* g = gu + (size_t)t * GUN;
  const float* u = g + INTER;
  float act[32];
  float mx = 0.f;
#pragma unroll
  for (int i4 = 0; i4 < 32; i4 += 4) {
    float4 gv = *(const float4*)(g + tid * 32 + i4);
    float4 uv = *(const float4*)(u + tid * 32 + i4);
    float gg[4] = {gv.x, gv.y, gv.z, gv.w};
    float uu[4] = {uv.x, uv.y, uv.z, uv.w};
#pragma unroll
    for (int j = 0; j < 4; j++) {
      float xx = gg[j];
      float inner = 0.7978845608028654f * (xx + 0.044715f * xx * xx * xx);
      float gl = 0.5f * xx * (1.0f + tanhf(inner));
      float av = gl * uu[j];
      act[i4 + j] = av;
      mx = fmaxf(mx, fabsf(av));
    }
  }
  mx = wave_max(mx);
  if ((tid & 63) == 0) red[tid >> 6] = mx;
  __syncthreads();
  float m = fmaxf(fmaxf(red[0], red[1]), fmaxf(red[2], red[3]));
  float sc = fmaxf(m * (1.0f / 127.0f), 1e-8f);
  if (tid == 0) s[t] = sc;
  int8_t* qr = q + (size_t)t * INTER + tid * 32;
#pragma unroll
  for (int i4 = 0; i4 < 32; i4 += 4) {
    char4 o;
    o.x = quant1(act[i4], sc);
    o.y = quant1(act[i4 + 1], sc);
    o.z = quant1(act[i4 + 2], sc);
    o.w = quant1(act[i4 + 3], sc);
    *(char4*)(qr + i4) = o;
  }
}

// ---------------- RoPE + f32->bf16 hi/lo conversion: Q ----------------
__global__ __launch_bounds__(256) void cvt_q_kernel(const float* __restrict__ qf,
                                                    const float* __restrict__ cosT,
                                                    const float* __restrict__ sinT,
                                                    unsigned short* __restrict__ Qhi,
                                                    unsigned short* __restrict__ Qlo) {
  int t = blockIdx.x, tid = threadIdx.x;
  int sp = t & (SEQ - 1);
  int h = tid >> 4, pb = (tid & 15) * 4;
  const float* row = qf + (size_t)t * QDIM + h * HD;
  float4 x0 = *(const float4*)(row + pb);
  float4 x1 = *(const float4*)(row + pb + 64);
  float4 c = *(const float4*)(cosT + sp * 64 + pb);
  float4 s = *(const float4*)(sinT + sp * 64 + pb);
  float y0[4] = {x0.x * c.x - x1.x * s.x, x0.y * c.y - x1.y * s.y, x0.z * c.z - x1.z * s.z,
                 x0.w * c.w - x1.w * s.w};
  float y1[4] = {x1.x * c.x + x0.x * s.x, x1.y * c.y + x0.y * s.y, x1.z * c.z + x0.z * s.z,
                 x1.w * c.w + x0.w * s.w};
  s4v h0, l0, h1, l1;
#pragma unroll
  for (int e = 0; e < 4; e++) {
    unsigned short hb = f2bf_rne(y0[e]);
    h0[e] = (short)hb;
    l0[e] = (short)f2bf_rne(y0[e] - bf2f(hb));
    hb = f2bf_rne(y1[e]);
    h1[e] = (short)hb;
    l1[e] = (short)f2bf_rne(y1[e] - bf2f(hb));
  }
  size_t o = (size_t)t * QDIM + h * HD + pb;
  *(s4v*)&Qhi[o] = h0;
  *(s4v*)&Qlo[o] = l0;
  *(s4v*)&Qhi[o + 64] = h1;
  *(s4v*)&Qlo[o + 64] = l1;
}

// ---------------- RoPE + conversion: K (layout [(b,g)][s][d]) ----------------
__global__ __launch_bounds__(256) void cvt_k_kernel(const float* __restrict__ kvf,
                                                    const float* __restrict__ cosT,
                                                    const float* __restrict__ sinT,
                                                    unsigned short* __restrict__ Khi,
                                                    unsigned short* __restrict__ Klo) {
  int t = blockIdx.x, tid = threadIdx.x;
  int sp = t & (SEQ - 1);
  int b = t >> 11;
  int g = tid >> 5, pb = (tid & 31) * 2;
  const float* row = kvf + (size_t)t * DM + g * HD;
  float2 x0 = *(const float2*)(row + pb);
  float2 x1 = *(const float2*)(row + pb + 64);
  float2 c = *(const float2*)(cosT + sp * 64 + pb);
  float2 s = *(const float2*)(sinT + sp * 64 + pb);
  float y0[2] = {x0.x * c.x - x1.x * s.x, x0.y * c.y - x1.y * s.y};
  float y1[2] = {x1.x * c.x + x0.x * s.x, x1.y * c.y + x0.y * s.y};
  s2v h0, l0, h1, l1;
#pragma unroll
  for (int e = 0; e < 2; e++) {
    unsigned short hb = f2bf_rne(y0[e]);
    h0[e] = (short)hb;
    l0[e] = (short)f2bf_rne(y0[e] - bf2f(hb));
    hb = f2bf_rne(y1[e]);
    h1[e] = (short)hb;
    l1[e] = (short)f2bf_rne(y1[e] - bf2f(hb));
  }
  size_t o = ((size_t)(b * NKV + g) * SEQ + sp) * HD + pb;
  *(s2v*)&Khi[o] = h0;
  *(s2v*)&Klo[o] = l0;
  *(s2v*)&Khi[o + 64] = h1;
  *(s2v*)&Klo[o + 64] = l1;
}

// ---------------- V transpose + conversion: Vt layout [(b,g)][d][s] bf16 ----------------
__global__ __launch_bounds__(256) void cvt_v_kernel(const float* __restrict__ kvf,
                                                    unsigned short* __restrict__ Vt) {
  __shared__ float vt[32][132];
  int bg = blockIdx.y;
  int b = bg >> 3, g = bg & 7;
  int s0 = blockIdx.x * 32;
  int tid = threadIdx.x;
#pragma unroll
  for (int i = 0; i < 4; i++) {
    int pos = tid + i * 256;
    int r = pos >> 5, d4 = (pos & 31) * 4;
    *(float4*)&vt[r][d4] =
        *(const float4*)(kvf + (size_t)(b * SEQ + s0 + r) * DM + KVDIM + g * HD + d4);
  }
  __syncthreads();
  int d = tid & 127, half = tid >> 7;
  unsigned short u[16];
#pragma unroll
  for (int i = 0; i < 16; i++) u[i] = f2bf_rne(vt[half * 16 + i][d]);
  unsigned short* dst = Vt + ((size_t)bg * HD + d) * SEQ + s0 + half * 16;
  *(s8v*)dst = *(s8v*)&u[0];
  *(s8v*)(dst + 8) = *(s8v*)&u[8];
}

// ---------------- int8 GEMM (global_load_lds + XOR swizzle, 128x128, BK=64) ----------------
__global__ __launch_bounds__(256) void gemm_i8_kernel(const int8_t* __restrict__ A,
                                                      const float* __restrict__ sA,
                                                      const int8_t* __restrict__ B,
                                                      const float* __restrict__ sB,
                                                      const float* __restrict__ res,
                                                      float* __restrict__ C, int N, int K) {
  __shared__ __align__(16) int8_t lA[8192];
  __shared__ __align__(16) int8_t lB[8192];
  int tid = threadIdx.x;
  int row0 = blockIdx.y * 128;
  int col0 = blockIdx.x * 128;
  int lane = tid & 63, wid = tid >> 6;
  int wm = (wid >> 1) * 64, wn = (wid & 1) * 64;
  int fr = lane & 15, lq = lane >> 4;

  int rS = wid * 32 + (lane >> 2);
  int cS = ((lane & 3) ^ (rS & 3)) << 4;
  const int8_t* gA0 = A + (size_t)(row0 + rS) * K + cS;
  const int8_t* gA1 = A + (size_t)(row0 + rS + 16) * K + cS;
  const int8_t* gB0 = B + (size_t)(col0 + rS) * K + cS;
  const int8_t* gB1 = B + (size_t)(col0 + rS + 16) * K + cS;
  int8_t* lA0 = &lA[wid * 2048];
  int8_t* lA1 = &lA[wid * 2048 + 1024];
  int8_t* lB0 = &lB[wid * 2048];
  int8_t* lB1 = &lB[wid * 2048 + 1024];

  int aoff[4], boff[4];
#pragma unroll
  for (int m = 0; m < 4; m++) {
    int r = wm + m * 16 + fr;
    aoff[m] = r * 64 + ((lq ^ (r & 3)) << 4);
    r = wn + m * 16 + fr;
    boff[m] = r * 64 + ((lq ^ (r & 3)) << 4);
  }

  v4i acc[4][4];
#pragma unroll
  for (int m = 0; m < 4; m++)
#pragma unroll
    for (int n = 0; n < 4; n++) acc[m][n] = (v4i){0, 0, 0, 0};

  for (int k0 = 0; k0 < K; k0 += 64) {
    GL16(gA0 + k0, lA0);
    GL16(gA1 + k0, lA1);
    GL16(gB0 + k0, lB0);
    GL16(gB1 + k0, lB1);
    __syncthreads();
    v4i a[4], b[4];
#pragma unroll
    for (int m = 0; m < 4; m++) a[m] = *(const v4i*)&lA[aoff[m]];
#pragma unroll
    for (int n = 0; n < 4; n++) b[n] = *(const v4i*)&lB[boff[n]];
#pragma unroll
    for (int m = 0; m < 4; m++)
#pragma unroll
      for (int n = 0; n < 4; n++)
        acc[m][n] = __builtin_amdgcn_mfma_i32_16x16x64_i8(a[m], b[n], acc[m][n], 0, 0, 0);
    __syncthreads();
  }
  int rj = lq * 4;
  int cn = fr;
#pragma unroll
  for (int m = 0; m < 4; m++) {
#pragma unroll
    for (int j = 0; j < 4; j++) {
      int rl = row0 + wm + m * 16 + rj + j;
      float sa = sA[rl];
      size_t rowoff = (size_t)rl * N;
#pragma unroll
      for (int n = 0; n < 4; n++) {
        int cg = col0 + wn + n * 16 + cn;
        float v = (float)acc[m][n][j] * sa * sB[cg];
        if (res) v += res[rowoff + cg];
        C[rowoff + cg] = v;
      }
    }
  }
}

// ---------------- flash attention: bf16 MFMA, DMA-staged LDS, double-buffered ----------------
// 4 waves/block, 64 q rows/block (16/wave), 32-wide KV tiles.
// LDS K tiles: [32][256B] rows, XOR swizzle byte^=((row&7)<<4).
// LDS V tiles: [128 d][64B] rows in 128B super-rows, XOR swizzle byte^=(((d>>1)&7)<<4).
__global__ __launch_bounds__(256, 3) void attn_mfma_kernel(
    const unsigned short* __restrict__ Qhi, const unsigned short* __restrict__ Qlo,
    const unsigned short* __restrict__ Khi, const unsigned short* __restrict__ Klo,
    const unsigned short* __restrict__ Vt, float* __restrict__ out) {
  __shared__ __align__(16) int8_t lkh[2][8192], lkl[2][8192], lvt[2][8192];
  __shared__ unsigned short ps[4][16][40];
  int qt = (int)gridDim.x - 1 - (int)blockIdx.x;  // big tiles first
  int bh = blockIdx.y;
  int b = bh >> 4, h = bh & 15, g = h >> 1;
  int bg = b * NKV + g;
  int tid = threadIdx.x;
  int lane = tid & 63, w = tid >> 6;
  int lr = lane & 15, lq = lane >> 4;
  int qbase = qt * 64 + w * 16;

  const int8_t* kbh = (const int8_t*)(Khi + (size_t)bg * SEQ * HD);
  const int8_t* kbl = (const int8_t*)(Klo + (size_t)bg * SEQ * HD);
  const int8_t* vb = (const int8_t*)(Vt + (size_t)bg * HD * SEQ);

  // per-lane staging geometry (tile 0); advance by +8192B (K) / +64B (V) per tile
  int c0 = w, c1 = w + 4;
  int dstK0 = c0 * 1024 + lane * 16;
  int dstK1 = c1 * 1024 + lane * 16;
  int srcK0 = dstK0 ^ (((((c0 & 1) * 4) | (lane >> 4)) & 7) << 4);
  int srcK1 = dstK1 ^ (((((c1 & 1) * 4) | (lane >> 4)) & 7) << 4);
  int srcV0l = dstK0 ^ (((lane >> 3) & 7) << 4);
  int srcV1l = dstK1 ^ (((lane >> 3) & 7) << 4);
  // V: map linear vt-space -> global [d][SEQ] bytes
  size_t srcV0 = (size_t)(srcV0l >> 6) * (SEQ * 2) + (srcV0l & 63);
  size_t srcV1 = (size_t)(srcV1l >> 6) * (SEQ * 2) + (srcV1l & 63);

  // Q fragments (hi/lo) in registers
  s8v qh[4], ql[4];
  {
    size_t qo = (size_t)(b * SEQ + qbase + lr) * QDIM + h * HD + lq * 8;
#pragma unroll
    for (int c = 0; c < 4; ++c) {
      qh[c] = *(const s8v*)(Qhi + qo + c * 32);
      ql[c] = *(const s8v*)(Qlo + qo + c * 32);
    }
  }

  v4f oacc[8];
#pragma unroll
  for (int i = 0; i < 8; ++i) oacc[i] = (v4f){0.f, 0.f, 0.f, 0.f};
  float mrun[4] = {-1e30f, -1e30f, -1e30f, -1e30f};
  float lsum[4] = {0.f, 0.f, 0.f, 0.f};
  const float kin = 0.0017677669529663687f;  // 1/(sqrt(128)*50)

  int kswz = (lr & 7) << 4;
  int vswz = ((lr >> 1) & 7) << 4;
  int vwithin = ((lr & 1) * 64 + lq * 16) ^ vswz;
  int kcol = lq * 16;

  int ktiles = 2 * qt + 2;

#define STAGE(kt, buf)                                                    \
  do {                                                                    \
    size_t kb = (size_t)(kt) * 8192;                                      \
    size_t vbo = (size_t)(kt) * 64;                                       \
    GL16(kbh + kb + srcK0, &lkh[buf][c0 * 1024]);                         \
    GL16(kbl + kb + srcK0, &lkl[buf][c0 * 1024]);                         \
    GL16(kbh + kb + srcK1, &lkh[buf][c1 * 1024]);                         \
    GL16(kbl + kb + srcK1, &lkl[buf][c1 * 1024]);                         \
    GL16(vb + vbo + srcV0, &lvt[buf][c0 * 1024]);                         \
    GL16(vb + vbo + srcV1, &lvt[buf][c1 * 1024]);                         \
  } while (0)

  STAGE(0, 0);
  for (int kt = 0; kt < ktiles; ++kt) {
    int cur = kt & 1;
    if (kt + 1 < ktiles) {
      STAGE(kt + 1, cur ^ 1);
      asm volatile("s_waitcnt vmcnt(6)" ::: "memory");
    } else {
      asm volatile("s_waitcnt vmcnt(0)" ::: "memory");
    }
    __builtin_amdgcn_s_barrier();
    __builtin_amdgcn_sched_barrier(0);
    int kbase = kt * 32;
    if (kbase <= qbase + 15) {
      // QK^T: two 16x16 tiles, 3-term hi/lo
      v4f sacc[2];
#pragma unroll
      for (int t2 = 0; t2 < 2; ++t2) {
        v4f s = (v4f){0.f, 0.f, 0.f, 0.f};
        int rowb = (t2 * 16 + lr) * 256;
#pragma unroll
        for (int c = 0; c < 4; ++c) {
          int off = rowb + ((c * 64 + kcol) ^ kswz);
          s8v kh = *(const s8v*)&lkh[cur][off];
          s8v kl = *(const s8v*)&lkl[cur][off];
          s = __builtin_amdgcn_mfma_f32_16x16x32_bf16(qh[c], kh, s, 0, 0, 0);
          s = __builtin_amdgcn_mfma_f32_16x16x32_bf16(qh[c], kl, s, 0, 0, 0);
          s = __builtin_amdgcn_mfma_f32_16x16x32_bf16(ql[c], kh, s, 0, 0, 0);
        }
        sacc[t2] = s;
      }

      // softcap + causal mask + online softmax
      float cc0[4], cc1[4], mt[4];
#pragma unroll
      for (int j = 0; j < 4; ++j) {
        int qg = qbase + lq * 4 + j;
        int k0g = kbase + lr, k1g = kbase + 16 + lr;
        float z0 = __expf(2.f * (sacc[0][j] * kin));
        float z1 = __expf(2.f * (sacc[1][j] * kin));
        float t0 = 50.f - 100.f * __builtin_amdgcn_rcpf(z0 + 1.f);
        float t1 = 50.f - 100.f * __builtin_amdgcn_rcpf(z1 + 1.f);
        cc0[j] = (k0g <= qg) ? t0 : -1e30f;
        cc1[j] = (k1g <= qg) ? t1 : -1e30f;
        mt[j] = fmaxf(cc0[j], cc1[j]);
      }
#pragma unroll
      for (int st = 1; st <= 8; st <<= 1)
#pragma unroll
        for (int j = 0; j < 4; ++j) mt[j] = fmaxf(mt[j], __shfl_xor(mt[j], st));

      float al[4], rs[4];
#pragma unroll
      for (int j = 0; j < 4; ++j) {
        float mnew = fmaxf(mrun[j], mt[j]);
        al[j] = __expf(mrun[j] - mnew);
        mrun[j] = mnew;
        float e0 = __expf(cc0[j] - mnew);
        float e1 = __expf(cc1[j] - mnew);
        rs[j] = e0 + e1;
        int q = lq * 4 + j;
        ps[w][q][lr] = f2bf_rne(e0);
        ps[w][q][16 + lr] = f2bf_rne(e1);
      }
#pragma unroll
      for (int st = 1; st <= 8; st <<= 1)
#pragma unroll
        for (int j = 0; j < 4; ++j) rs[j] += __shfl_xor(rs[j], st);
#pragma unroll
      for (int j = 0; j < 4; ++j) lsum[j] = lsum[j] * al[j] + rs[j];
#pragma unroll
      for (int dt = 0; dt < 8; ++dt)
#pragma unroll
        for (int j = 0; j < 4; ++j) oacc[dt][j] *= al[j];

      s8v pa = *(const s8v*)&ps[w][lr][lq * 8];
#pragma unroll
      for (int dt = 0; dt < 8; ++dt) {
        int off = (dt * 8 + (lr >> 1)) * 128 + vwithin;
        s8v vh = *(const s8v*)&lvt[cur][off];
        oacc[dt] = __builtin_amdgcn_mfma_f32_16x16x32_bf16(pa, vh, oacc[dt], 0, 0, 0);
      }
    }
    __builtin_amdgcn_s_barrier();
  }
#undef STAGE

  float inv[4];
#pragma unroll
  for (int j = 0; j < 4; ++j) inv[j] = 1.f / lsum[j];
  float* ob = out + (size_t)(b * SEQ + qbase) * QDIM + h * HD;
#pragma unroll
  for (int dt = 0; dt < 8; ++dt)
#pragma unroll
    for (int j = 0; j < 4; ++j)
      ob[(size_t)(lq * 4 + j) * QDIM + dt * 16 + lr] = oacc[dt][j] * inv[j];
}

extern "C" void kernel_launch(void* const* d_in, const int* in_sizes, int n_in, void* d_out,
                              int out_size, void* d_ws, size_t ws_size, hipStream_t stream) {
  (void)in_sizes; (void)n_in; (void)out_size; (void)ws_size;
  const float* hidden = (const float*)d_in[0];
  const float* w_in_norm = (const float*)d_in[1];
  const float* w_post_norm = (const float*)d_in[2];
  const float* wqkv = (const float*)d_in[3];
  const float* wo = (const float*)d_in[4];
  const float* w_gate_up = (const float*)d_in[5];
  const float* w_down = (const float*)d_in[6];
  float* out = (float*)d_out;

  char* p = (char*)d_ws;
  size_t off = 0;
  auto take = [&](size_t bytes) -> char* {
    char* r = p + off;
    off += (bytes + 255) & ~(size_t)255;
    return r;
  };
  const size_t MB = 1u << 20;
  int8_t* qx = (int8_t*)take((size_t)T_TOKENS * DM);
  float* sx = (float*)take((size_t)T_TOKENS * 4);
  int8_t* qw_qkv = (int8_t*)take((size_t)QKVN * DM);
  float* sw_qkv = (float*)take((size_t)QKVN * 4);
  int8_t* qw_wo = (int8_t*)take((size_t)DM * QDIM);
  float* sw_wo = (float*)take((size_t)DM * 4);
  int8_t* qw_gu = (int8_t*)take((size_t)GUN * DM);
  float* sw_gu = (float*)take((size_t)GUN * 4);
  int8_t* qw_dn = (int8_t*)take((size_t)DM * INTER);
  float* sw_dn = (float*)take((size_t)DM * 4);
  float* cosT = (float*)take((size_t)SEQ * 64 * 4);
  float* sinT = (float*)take((size_t)SEQ * 64 * 4);
  float* x1 = (float*)take((size_t)T_TOKENS * DM * 4);
  float* s_act = (float*)take((size_t)T_TOKENS * 4);
  char* regB = take(96 * MB);
  float* qf32 = (float*)regB;
  float* kvf32 = (float*)regB;
  float* attn_out = (float*)regB;
  unsigned short* Qhi = (unsigned short*)(regB + 32 * MB);
  unsigned short* Qlo = (unsigned short*)(regB + 48 * MB);
  unsigned short* Khi = (unsigned short*)(regB + 64 * MB);
  unsigned short* Klo = (unsigned short*)(regB + 72 * MB);
  unsigned short* Vt = (unsigned short*)(regB + 80 * MB);
  float* gu = (float*)regB;
  int8_t* act_q8 = (int8_t*)(regB + 64 * MB);

  rope_table_kernel<<<SEQ, 64, 0, stream>>>(cosT, sinT);
  quant_w_kernel<<<QKVN, 256, 0, stream>>>(wqkv, qw_qkv, sw_qkv, DM);
  quant_w_kernel<<<DM, 256, 0, stream>>>(wo, qw_wo, sw_wo, QDIM);
  quant_w_kernel<<<GUN, 256, 0, stream>>>(w_gate_up, qw_gu, sw_gu, DM);
  quant_w_kernel<<<DM, 256, 0, stream>>>(w_down, qw_dn, sw_dn, INTER);

  // attention block
  rmsnorm_quant_kernel<<<T_TOKENS, 256, 0, stream>>>(hidden, w_in_norm, qx, sx);
  gemm_i8_kernel<<<dim3(QDIM / 128, T_TOKENS / 128), 256, 0, stream>>>(qx, sx, qw_qkv, sw_qkv,
                                                                       nullptr, qf32, QDIM, DM);
  cvt_q_kernel<<<T_TOKENS, 256, 0, stream>>>(qf32, cosT, sinT, Qhi, Qlo);
  gemm_i8_kernel<<<dim3(DM / 128, T_TOKENS / 128), 256, 0, stream>>>(
      qx, sx, qw_qkv + (size_t)QDIM * DM, sw_qkv + QDIM, nullptr, kvf32, DM, DM);
  cvt_k_kernel<<<T_TOKENS, 256, 0, stream>>>(kvf32, cosT, sinT, Khi, Klo);
  cvt_v_kernel<<<dim3(SEQ / 32, 16), 256, 0, stream>>>(kvf32, Vt);
  attn_mfma_kernel<<<dim3(SEQ / 64, 32), 256, 0, stream>>>(Qhi, Qlo, Khi, Klo, Vt, attn_out);
  quant_rows_2048_kernel<<<T_TOKENS, 256, 0, stream>>>(attn_out, qx, sx);
  gemm_i8_kernel<<<dim3(DM / 128, T_TOKENS / 128), 256, 0, stream>>>(qx, sx, qw_wo, sw_wo, hidden,
                                                                     x1, DM, QDIM);

  // MLP block
  rmsnorm_quant_kernel<<<T_TOKENS, 256, 0, stream>>>(x1, w_post_norm, qx, sx);
  for (int ch = 0; ch < 4; ++ch) {
    const int8_t* qxc = qx + (size_t)ch * 1024 * DM;
    const float* sxc = sx + (size_t)ch * 1024;
    gemm_i8_kernel<<<dim3(GUN / 128, 1024 / 128), 256, 0, stream>>>(qxc, sxc, qw_gu, sw_gu,
                                                                    nullptr, gu, GUN, DM);
    gelu_mul_quant_kernel<<<1024, 256, 0, stream>>>(gu, act_q8 + (size_t)ch * 1024 * INTER,
                                                    s_act + (size_t)ch * 1024);
  }
  gemm_i8_kernel<<<dim3(DM / 128, T_TOKENS / 128), 256, 0, stream>>>(act_q8, s_act, qw_dn, sw_dn,
                                                                     x1, out, DM, INTER);
}

// Round 5
// 869.214 us; speedup vs baseline: 3.4082x; 1.2606x over previous
//
#include <hip/hip_runtime.h>
#include <cstdint>
#include <math.h>

#define T_TOKENS 4096
#define SEQ 2048
#define DM 2048
#define NH 16
#define NKV 8
#define HD 128
#define QDIM 2048   // NH*HD
#define KVDIM 1024  // NKV*HD
#define QKVN 4096   // QDIM + 2*KVDIM
#define INTER 8192
#define GUN 16384   // 2*INTER

typedef int v4i __attribute__((ext_vector_type(4)));
typedef float v4f __attribute__((ext_vector_type(4)));
typedef short s8v __attribute__((ext_vector_type(8)));
typedef short s4v __attribute__((ext_vector_type(4)));
typedef short s2v __attribute__((ext_vector_type(2)));

#define GL16(g, l)                                                                       \
  __builtin_amdgcn_global_load_lds((__attribute__((address_space(1))) const void*)(g),   \
                                   (__attribute__((address_space(3))) void*)(l), 16, 0, 0)

__device__ inline float wave_sum(float v) {
#pragma unroll
  for (int off = 32; off > 0; off >>= 1) v += __shfl_down(v, off);
  return v;
}
__device__ inline float wave_max(float v) {
#pragma unroll
  for (int off = 32; off > 0; off >>= 1) v = fmaxf(v, __shfl_down(v, off));
  return v;
}
__device__ inline float dot4(float4 a, float4 b) {
  return a.x * b.x + a.y * b.y + a.z * b.z + a.w * b.w;
}
__device__ inline int8_t quant1(float v, float s) {
  float q = rintf(v / s);
  q = fminf(fmaxf(q, -127.f), 127.f);
  return (int8_t)(int)q;
}
__device__ inline unsigned short f2bf_rne(float x) {
  unsigned u = __float_as_uint(x);
  return (unsigned short)((u + 0x7FFFu + ((u >> 16) & 1u)) >> 16);
}
__device__ inline float bf2f(unsigned short h) { return __uint_as_float(((unsigned)h) << 16); }

// ---------------- RoPE tables ----------------
__global__ void rope_table_kernel(float* __restrict__ cosT, float* __restrict__ sinT) {
  int s = blockIdx.x, d = threadIdx.x;  // 64 threads
  float inv = 1.0f / powf(10000.0f, (float)d * (1.0f / 64.0f));
  float f = (float)s * inv;
  cosT[s * 64 + d] = cosf(f);
  sinT[s * 64 + d] = sinf(f);
}

// ---------------- per-row weight quant (single-read, register cached) ----------------
__global__ __launch_bounds__(256) void quant_w_kernel(const float* __restrict__ w,
                                                      int8_t* __restrict__ qw,
                                                      float* __restrict__ sw, int K) {
  __shared__ float red[4];
  int row = blockIdx.x, tid = threadIdx.x;
  const float* wr = w + (size_t)row * K;
  int nv = K >> 10;
  float4 v[8];
  float mx = 0.f;
#pragma unroll
  for (int i = 0; i < 8; i++) {
    if (i < nv) {
      v[i] = *(const float4*)(wr + (size_t)(tid + i * 256) * 4);
      mx = fmaxf(mx, fmaxf(fmaxf(fabsf(v[i].x), fabsf(v[i].y)),
                           fmaxf(fabsf(v[i].z), fabsf(v[i].w))));
    }
  }
  mx = wave_max(mx);
  if ((tid & 63) == 0) red[tid >> 6] = mx;
  __syncthreads();
  float m = fmaxf(fmaxf(red[0], red[1]), fmaxf(red[2], red[3]));
  float s = m * (1.0f / 127.0f);
  if (tid == 0) sw[row] = s;
  float sd = (s > 0.f) ? s : 1.f;
  int8_t* qr = qw + (size_t)row * K;
#pragma unroll
  for (int i = 0; i < 8; i++) {
    if (i < nv) {
      char4 o;
      o.x = quant1(v[i].x, sd);
      o.y = quant1(v[i].y, sd);
      o.z = quant1(v[i].z, sd);
      o.w = quant1(v[i].w, sd);
      *(char4*)(qr + (size_t)(tid + i * 256) * 4) = o;
    }
  }
}

// ---------------- gate_up weight quant with 16-col interleaved permutation ----------------
// source row r -> permuted row pr so each 128-col tile = [g0-15,u0-15,g16-31,u16-31,...]
__global__ __launch_bounds__(256) void quant_w_gu_kernel(const float* __restrict__ w,
                                                         int8_t* __restrict__ qw,
                                                         float* __restrict__ sw) {
  __shared__ float red[4];
  int row = blockIdx.x, tid = threadIdx.x;
  const int K = DM;
  int j = (row < INTER) ? row : row - INTER;
  int pr = (j >> 6) * 128 + ((j >> 4) & 3) * 32 + ((row < INTER) ? 0 : 16) + (j & 15);
  const float* wr = w + (size_t)row * K;
  float4 v[2];
  float mx = 0.f;
#pragma unroll
  for (int i = 0; i < 2; i++) {
    v[i] = *(const float4*)(wr + (size_t)(tid + i * 256) * 4);
    mx = fmaxf(mx, fmaxf(fmaxf(fabsf(v[i].x), fabsf(v[i].y)),
                         fmaxf(fabsf(v[i].z), fabsf(v[i].w))));
  }
  mx = wave_max(mx);
  if ((tid & 63) == 0) red[tid >> 6] = mx;
  __syncthreads();
  float m = fmaxf(fmaxf(red[0], red[1]), fmaxf(red[2], red[3]));
  float s = m * (1.0f / 127.0f);
  if (tid == 0) sw[pr] = s;
  float sd = (s > 0.f) ? s : 1.f;
  int8_t* qr = qw + (size_t)pr * K;
#pragma unroll
  for (int i = 0; i < 2; i++) {
    char4 o;
    o.x = quant1(v[i].x, sd);
    o.y = quant1(v[i].y, sd);
    o.z = quant1(v[i].z, sd);
    o.w = quant1(v[i].w, sd);
    *(char4*)(qr + (size_t)(tid + i * 256) * 4) = o;
  }
}

// ---------------- RMSNorm + per-token quant ----------------
__global__ __launch_bounds__(256) void rmsnorm_quant_kernel(const float* __restrict__ x,
                                                            const float* __restrict__ w,
                                                            int8_t* __restrict__ q,
                                                            float* __restrict__ s) {
  __shared__ float red[8];
  int t = blockIdx.x, tid = threadIdx.x;
  const float* xr = x + (size_t)t * DM;
  float4 a = *(const float4*)(xr + tid * 8);
  float4 b = *(const float4*)(xr + tid * 8 + 4);
  float ss = dot4(a, a) + dot4(b, b);
  ss = wave_sum(ss);
  if ((tid & 63) == 0) red[tid >> 6] = ss;
  __syncthreads();
  float tot = red[0] + red[1] + red[2] + red[3];
  float rms = rsqrtf(tot * (1.0f / DM) + 1e-6f);
  float4 wa = *(const float4*)(w + tid * 8);
  float4 wb = *(const float4*)(w + tid * 8 + 4);
  float y[8] = {a.x * rms * wa.x, a.y * rms * wa.y, a.z * rms * wa.z, a.w * rms * wa.w,
                b.x * rms * wb.x, b.y * rms * wb.y, b.z * rms * wb.z, b.w * rms * wb.w};
  float mx = 0.f;
#pragma unroll
  for (int i = 0; i < 8; i++) mx = fmaxf(mx, fabsf(y[i]));
  mx = wave_max(mx);
  if ((tid & 63) == 0) red[4 + (tid >> 6)] = mx;
  __syncthreads();
  float m = fmaxf(fmaxf(red[4], red[5]), fmaxf(red[6], red[7]));
  float sc = fmaxf(m * (1.0f / 127.0f), 1e-8f);
  if (tid == 0) s[t] = sc;
  int8_t* qr = q + (size_t)t * DM + tid * 8;
  char4 o0, o1;
  o0.x = quant1(y[0], sc); o0.y = quant1(y[1], sc); o0.z = quant1(y[2], sc); o0.w = quant1(y[3], sc);
  o1.x = quant1(y[4], sc); o1.y = quant1(y[5], sc); o1.z = quant1(y[6], sc); o1.w = quant1(y[7], sc);
  *(char4*)(qr) = o0;
  *(char4*)(qr + 4) = o1;
}

// ---------------- plain per-token quant of a [*,2048] f32 matrix ----------------
__global__ __launch_bounds__(256) void quant_rows_2048_kernel(const float* __restrict__ x,
                                                              int8_t* __restrict__ q,
                                                              float* __restrict__ s) {
  __shared__ float red[4];
  int t = blockIdx.x, tid = threadIdx.x;
  const float* xr = x + (size_t)t * DM;
  float4 a = *(const float4*)(xr + tid * 8);
  float4 b = *(const float4*)(xr + tid * 8 + 4);
  float y[8] = {a.x, a.y, a.z, a.w, b.x, b.y, b.z, b.w};
  float mx = 0.f;
#pragma unroll
  for (int i = 0; i < 8; i++) mx = fmaxf(mx, fabsf(y[i]));
  mx = wave_max(mx);
  if ((tid & 63) == 0) red[tid >> 6] = mx;
  __syncthreads();
  float m = fmaxf(fmaxf(red[0], red[1]), fmaxf(red[2], red[3]));
  float sc = fmaxf(m * (1.0f / 127.0f), 1e-8f);
  if (tid == 0) s[t] = sc;
  int8_t* qr = q + (size_t)t * DM + tid * 8;
  char4 o0, o1;
  o0.x = quant1(y[0], sc); o0.y = quant1(y[1], sc); o0.z = quant1(y[2], sc); o0.w = quant1(y[3], sc);
  o1.x = quant1(y[4], sc); o1.y = quant1(y[5], sc); o1.z = quant1(y[6], sc); o1.w = quant1(y[7], sc);
  *(char4*)(qr) = o0;
  *(char4*)(qr + 4) = o1;
}

// ---------------- per-token quant of a [*,8192] f32 matrix ----------------
__global__ __launch_bounds__(256) void quant_rows_8192_kernel(const float* __restrict__ x,
                                                              int8_t* __restrict__ q,
                                                              float* __restrict__ s) {
  __shared__ float red[4];
  int t = blockIdx.x, tid = threadIdx.x;
  const float* xr = x + (size_t)t * INTER + tid * 32;
  float y[32];
  float mx = 0.f;
#pragma unroll
  for (int i4 = 0; i4 < 32; i4 += 4) {
    float4 v = *(const float4*)(xr + i4);
    y[i4] = v.x; y[i4 + 1] = v.y; y[i4 + 2] = v.z; y[i4 + 3] = v.w;
    mx = fmaxf(mx, fmaxf(fmaxf(fabsf(v.x), fabsf(v.y)), fmaxf(fabsf(v.z), fabsf(v.w))));
  }
  mx = wave_max(mx);
  if ((tid & 63) == 0) red[tid >> 6] = mx;
  __syncthreads();
  float m = fmaxf(fmaxf(red[0], red[1]), fmaxf(red[2], red[3]));
  float sc = fmaxf(m * (1.0f / 127.0f), 1e-8f);
  if (tid == 0) s[t] = sc;
  int8_t* qr = q + (size_t)t * INTER + tid * 32;
#pragma unroll
  for (int i4 = 0; i4 < 32; i4 += 4) {
    char4 o;
    o.x = quant1(y[i4], sc);
    o.y = quant1(y[i4 + 1], sc);
    o.z = quant1(y[i4 + 2], sc);
    o.w = quant1(y[i4 + 3], sc);
    *(char4*)(qr + i4) = o;
  }
}

// ---------------- RoPE + f32->bf16 hi/lo conversion: Q ----------------
__global__ __launch_bounds__(256) void cvt_q_kernel(const float* __restrict__ qf,
                                                    const float* __restrict__ cosT,
                                                    const float* __restrict__ sinT,
                                                    unsigned short* __restrict__ Qhi,
                                                    unsigned short* __restrict__ Qlo) {
  int t = blockIdx.x, tid = threadIdx.x;
  int sp = t & (SEQ - 1);
  int h = tid >> 4, pb = (tid & 15) * 4;
  const float* row = qf + (size_t)t * QDIM + h * HD;
  float4 x0 = *(const float4*)(row + pb);
  float4 x1 = *(const float4*)(row + pb + 64);
  float4 c = *(const float4*)(cosT + sp * 64 + pb);
  float4 s = *(const float4*)(sinT + sp * 64 + pb);
  float y0[4] = {x0.x * c.x - x1.x * s.x, x0.y * c.y - x1.y * s.y, x0.z * c.z - x1.z * s.z,
                 x0.w * c.w - x1.w * s.w};
  float y1[4] = {x1.x * c.x + x0.x * s.x, x1.y * c.y + x0.y * s.y, x1.z * c.z + x0.z * s.z,
                 x1.w * c.w + x0.w * s.w};
  s4v h0, l0, h1, l1;
#pragma unroll
  for (int e = 0; e < 4; e++) {
    unsigned short hb = f2bf_rne(y0[e]);
    h0[e] = (short)hb;
    l0[e] = (short)f2bf_rne(y0[e] - bf2f(hb));
    hb = f2bf_rne(y1[e]);
    h1[e] = (short)hb;
    l1[e] = (short)f2bf_rne(y1[e] - bf2f(hb));
  }
  size_t o = (size_t)t * QDIM + h * HD + pb;
  *(s4v*)&Qhi[o] = h0;
  *(s4v*)&Qlo[o] = l0;
  *(s4v*)&Qhi[o + 64] = h1;
  *(s4v*)&Qlo[o + 64] = l1;
}

// ---------------- RoPE + conversion: K (layout [(b,g)][s][d]) ----------------
__global__ __launch_bounds__(256) void cvt_k_kernel(const float* __restrict__ kvf,
                                                    const float* __restrict__ cosT,
                                                    const float* __restrict__ sinT,
                                                    unsigned short* __restrict__ Khi,
                                                    unsigned short* __restrict__ Klo) {
  int t = blockIdx.x, tid = threadIdx.x;
  int sp = t & (SEQ - 1);
  int b = t >> 11;
  int g = tid >> 5, pb = (tid & 31) * 2;
  const float* row = kvf + (size_t)t * DM + g * HD;
  float2 x0 = *(const float2*)(row + pb);
  float2 x1 = *(const float2*)(row + pb + 64);
  float2 c = *(const float2*)(cosT + sp * 64 + pb);
  float2 s = *(const float2*)(sinT + sp * 64 + pb);
  float y0[2] = {x0.x * c.x - x1.x * s.x, x0.y * c.y - x1.y * s.y};
  float y1[2] = {x1.x * c.x + x0.x * s.x, x1.y * c.y + x0.y * s.y};
  s2v h0, l0, h1, l1;
#pragma unroll
  for (int e = 0; e < 2; e++) {
    unsigned short hb = f2bf_rne(y0[e]);
    h0[e] = (short)hb;
    l0[e] = (short)f2bf_rne(y0[e] - bf2f(hb));
    hb = f2bf_rne(y1[e]);
    h1[e] = (short)hb;
    l1[e] = (short)f2bf_rne(y1[e] - bf2f(hb));
  }
  size_t o = ((size_t)(b * NKV + g) * SEQ + sp) * HD + pb;
  *(s2v*)&Khi[o] = h0;
  *(s2v*)&Klo[o] = l0;
  *(s2v*)&Khi[o + 64] = h1;
  *(s2v*)&Klo[o + 64] = l1;
}

// ---------------- V transpose + conversion: Vt layout [(b,g)][d][s] bf16 ----------------
__global__ __launch_bounds__(256) void cvt_v_kernel(const float* __restrict__ kvf,
                                                    unsigned short* __restrict__ Vt) {
  __shared__ float vt[32][132];
  int bg = blockIdx.y;
  int b = bg >> 3, g = bg & 7;
  int s0 = blockIdx.x * 32;
  int tid = threadIdx.x;
#pragma unroll
  for (int i = 0; i < 4; i++) {
    int pos = tid + i * 256;
    int r = pos >> 5, d4 = (pos & 31) * 4;
    *(float4*)&vt[r][d4] =
        *(const float4*)(kvf + (size_t)(b * SEQ + s0 + r) * DM + KVDIM + g * HD + d4);
  }
  __syncthreads();
  int d = tid & 127, half = tid >> 7;
  unsigned short u[16];
#pragma unroll
  for (int i = 0; i < 16; i++) u[i] = f2bf_rne(vt[half * 16 + i][d]);
  unsigned short* dst = Vt + ((size_t)bg * HD + d) * SEQ + s0 + half * 16;
  *(s8v*)dst = *(s8v*)&u[0];
  *(s8v*)(dst + 8) = *(s8v*)&u[8];
}

// ---------------- int8 GEMM (global_load_lds + XOR swizzle, 128x128, BK=64) ----------------
__global__ __launch_bounds__(256) void gemm_i8_kernel(const int8_t* __restrict__ A,
                                                      const float* __restrict__ sA,
                                                      const int8_t* __restrict__ B,
                                                      const float* __restrict__ sB,
                                                      const float* __restrict__ res,
                                                      float* __restrict__ C, int N, int K) {
  __shared__ __align__(16) int8_t lA[8192];
  __shared__ __align__(16) int8_t lB[8192];
  int tid = threadIdx.x;
  int row0 = blockIdx.y * 128;
  int col0 = blockIdx.x * 128;
  int lane = tid & 63, wid = tid >> 6;
  int wm = (wid >> 1) * 64, wn = (wid & 1) * 64;
  int fr = lane & 15, lq = lane >> 4;

  int rS = wid * 32 + (lane >> 2);
  int cS = ((lane & 3) ^ (rS & 3)) << 4;
  const int8_t* gA0 = A + (size_t)(row0 + rS) * K + cS;
  const int8_t* gA1 = A + (size_t)(row0 + rS + 16) * K + cS;
  const int8_t* gB0 = B + (size_t)(col0 + rS) * K + cS;
  const int8_t* gB1 = B + (size_t)(col0 + rS + 16) * K + cS;
  int8_t* lA0 = &lA[wid * 2048];
  int8_t* lA1 = &lA[wid * 2048 + 1024];
  int8_t* lB0 = &lB[wid * 2048];
  int8_t* lB1 = &lB[wid * 2048 + 1024];

  int aoff[4], boff[4];
#pragma unroll
  for (int m = 0; m < 4; m++) {
    int r = wm + m * 16 + fr;
    aoff[m] = r * 64 + ((lq ^ (r & 3)) << 4);
    r = wn + m * 16 + fr;
    boff[m] = r * 64 + ((lq ^ (r & 3)) << 4);
  }

  v4i acc[4][4];
#pragma unroll
  for (int m = 0; m < 4; m++)
#pragma unroll
    for (int n = 0; n < 4; n++) acc[m][n] = (v4i){0, 0, 0, 0};

  for (int k0 = 0; k0 < K; k0 += 64) {
    GL16(gA0 + k0, lA0);
    GL16(gA1 + k0, lA1);
    GL16(gB0 + k0, lB0);
    GL16(gB1 + k0, lB1);
    __syncthreads();
    v4i a[4], b[4];
#pragma unroll
    for (int m = 0; m < 4; m++) a[m] = *(const v4i*)&lA[aoff[m]];
#pragma unroll
    for (int n = 0; n < 4; n++) b[n] = *(const v4i*)&lB[boff[n]];
#pragma unroll
    for (int m = 0; m < 4; m++)
#pragma unroll
      for (int n = 0; n < 4; n++)
        acc[m][n] = __builtin_amdgcn_mfma_i32_16x16x64_i8(a[m], b[n], acc[m][n], 0, 0, 0);
    __syncthreads();
  }
  int rj = lq * 4;
  int cn = fr;
#pragma unroll
  for (int m = 0; m < 4; m++) {
#pragma unroll
    for (int j = 0; j < 4; j++) {
      int rl = row0 + wm + m * 16 + rj + j;
      float sa = sA[rl];
      size_t rowoff = (size_t)rl * N;
#pragma unroll
      for (int n = 0; n < 4; n++) {
        int cg = col0 + wn + n * 16 + cn;
        float v = (float)acc[m][n][j] * sa * sB[cg];
        if (res) v += res[rowoff + cg];
        C[rowoff + cg] = v;
      }
    }
  }
}

// ---------------- int8 GEMM + fused gelu(gate)*up epilogue (permuted gu weights) ----------
__global__ __launch_bounds__(256) void gemm_gu_fused_kernel(const int8_t* __restrict__ A,
                                                            const float* __restrict__ sA,
                                                            const int8_t* __restrict__ B,
                                                            const float* __restrict__ sB,
                                                            float* __restrict__ act) {
  __shared__ __align__(16) int8_t lA[8192];
  __shared__ __align__(16) int8_t lB[8192];
  const int K = DM;
  int tid = threadIdx.x;
  int row0 = blockIdx.y * 128;
  int col0 = blockIdx.x * 128;
  int lane = tid & 63, wid = tid >> 6;
  int wm = (wid >> 1) * 64, wn = (wid & 1) * 64;
  int fr = lane & 15, lq = lane >> 4;

  int rS = wid * 32 + (lane >> 2);
  int cS = ((lane & 3) ^ (rS & 3)) << 4;
  const int8_t* gA0 = A + (size_t)(row0 + rS) * K + cS;
  const int8_t* gA1 = A + (size_t)(row0 + rS + 16) * K + cS;
  const int8_t* gB0 = B + (size_t)(col0 + rS) * K + cS;
  const int8_t* gB1 = B + (size_t)(col0 + rS + 16) * K + cS;
  int8_t* lA0 = &lA[wid * 2048];
  int8_t* lA1 = &lA[wid * 2048 + 1024];
  int8_t* lB0 = &lB[wid * 2048];
  int8_t* lB1 = &lB[wid * 2048 + 1024];

  int aoff[4], boff[4];
#pragma unroll
  for (int m = 0; m < 4; m++) {
    int r = wm + m * 16 + fr;
    aoff[m] = r * 64 + ((lq ^ (r & 3)) << 4);
    r = wn + m * 16 + fr;
    boff[m] = r * 64 + ((lq ^ (r & 3)) << 4);
  }

  v4i acc[4][4];
#pragma unroll
  for (int m = 0; m < 4; m++)
#pragma unroll
    for (int n = 0; n < 4; n++) acc[m][n] = (v4i){0, 0, 0, 0};

  for (int k0 = 0; k0 < K; k0 += 64) {
    GL16(gA0 + k0, lA0);
    GL16(gA1 + k0, lA1);
    GL16(gB0 + k0, lB0);
    GL16(gB1 + k0, lB1);
    __syncthreads();
    v4i a[4], b[4];
#pragma unroll
    for (int m = 0; m < 4; m++) a[m] = *(const v4i*)&lA[aoff[m]];
#pragma unroll
    for (int n = 0; n < 4; n++) b[n] = *(const v4i*)&lB[boff[n]];
#pragma unroll
    for (int m = 0; m < 4; m++)
#pragma unroll
      for (int n = 0; n < 4; n++)
        acc[m][n] = __builtin_amdgcn_mfma_i32_16x16x64_i8(a[m], b[n], acc[m][n], 0, 0, 0);
    __syncthreads();
  }
  int rj = lq * 4;
  int cn = fr;
#pragma unroll
  for (int m = 0; m < 4; m++) {
#pragma unroll
    for (int j = 0; j < 4; j++) {
      int rl = row0 + wm + m * 16 + rj + j;
      float sa = sA[rl];
      size_t rowoff = (size_t)rl * INTER;
#pragma unroll
      for (int np = 0; np < 2; np++) {
        float gv = (float)acc[m][np * 2][j] * sa * sB[col0 + wn + (np * 2) * 16 + cn];
        float uv = (float)acc[m][np * 2 + 1][j] * sa * sB[col0 + wn + (np * 2 + 1) * 16 + cn];
        float inner = 0.7978845608028654f * (gv + 0.044715f * gv * gv * gv);
        float gl = 0.5f * gv * (1.0f + tanhf(inner));
        int jg = (col0 >> 1) + (wn >> 1) + np * 16 + cn;
        act[rowoff + jg] = gl * uv;
      }
    }
  }
}

// ---------------- flash attention: 512 thr, 2 heads (1 KV group) per block ----------------
// 8 waves: w>>2 selects head, w&3 selects 16-row q slice; 32-wide KV tiles.
// LDS K tiles: [32][256B] rows, XOR swizzle byte^=((row&7)<<4).
// LDS V tiles: 64 super-rows x 128B (2 d-values), XOR swizzle byte^=(((sr)&7)<<4).
__global__ __launch_bounds__(512, 4) void attn_mfma_kernel(
    const unsigned short* __restrict__ Qhi, const unsigned short* __restrict__ Qlo,
    const unsigned short* __restrict__ Khi, const unsigned short* __restrict__ Klo,
    const unsigned short* __restrict__ Vt, float* __restrict__ out) {
  __shared__ __align__(16) int8_t lkh[2][8192], lkl[2][8192], lvt[2][8192];
  __shared__ unsigned short ps[8][16][40];
  int qt = (int)gridDim.x - 1 - (int)blockIdx.x;  // big tiles first
  int bg = blockIdx.y;
  int b = bg >> 3, g = bg & 7;
  int tid = threadIdx.x;
  int lane = tid & 63, w = tid >> 6;
  int lr = lane & 15, lq = lane >> 4;
  int h = g * 2 + (w >> 2);
  int qbase = qt * 64 + (w & 3) * 16;

  const int8_t* kbh = (const int8_t*)(Khi + (size_t)bg * SEQ * HD);
  const int8_t* kbl = (const int8_t*)(Klo + (size_t)bg * SEQ * HD);
  const int8_t* vb = (const int8_t*)(Vt + (size_t)bg * HD * SEQ);

  // staging: one GL16 per lane per buffer (512 lanes x 16B = 8192B)
  int xK = tid * 16;
  int sK = xK ^ (((xK >> 8) & 7) << 4);
  int sVl = xK ^ (((xK >> 7) & 7) << 4);
  size_t gsrcV = (size_t)(sVl >> 6) * (SEQ * 2) + (sVl & 63);

  // Q fragments (hi/lo) in registers
  s8v qh[4], ql[4];
  {
    size_t qo = (size_t)(b * SEQ + qbase + lr) * QDIM + h * HD + lq * 8;
#pragma unroll
    for (int c = 0; c < 4; ++c) {
      qh[c] = *(const s8v*)(Qhi + qo + c * 32);
      ql[c] = *(const s8v*)(Qlo + qo + c * 32);
    }
  }

  v4f oacc[8];
#pragma unroll
  for (int i = 0; i < 8; ++i) oacc[i] = (v4f){0.f, 0.f, 0.f, 0.f};
  float mrun[4] = {-1e30f, -1e30f, -1e30f, -1e30f};
  float lsum[4] = {0.f, 0.f, 0.f, 0.f};
  const float kin = 0.0017677669529663687f;  // 1/(sqrt(128)*50)

  int kswz = (lr & 7) << 4;
  int vswz = ((lr >> 1) & 7) << 4;
  int vwithin = ((lr & 1) * 64 + lq * 16) ^ vswz;
  int kcol = lq * 16;

  int ktiles = 2 * qt + 2;

#define STAGE(kt, buf)                                  \
  do {                                                  \
    size_t kb = (size_t)(kt) * 8192;                    \
    GL16(kbh + kb + sK, &lkh[buf][xK]);                 \
    GL16(kbl + kb + sK, &lkl[buf][xK]);                 \
    GL16(vb + (size_t)(kt) * 64 + gsrcV, &lvt[buf][xK]); \
  } while (0)

  STAGE(0, 0);
  for (int kt = 0; kt < ktiles; ++kt) {
    int cur = kt & 1;
    if (kt + 1 < ktiles) {
      STAGE(kt + 1, cur ^ 1);
      asm volatile("s_waitcnt vmcnt(3)" ::: "memory");
    } else {
      asm volatile("s_waitcnt vmcnt(0)" ::: "memory");
    }
    __builtin_amdgcn_s_barrier();
    __builtin_amdgcn_sched_barrier(0);
    int kbase = kt * 32;
    if (kbase <= qbase + 15) {
      // QK^T: two 16x16 tiles, 3-term hi/lo
      v4f sacc[2];
#pragma unroll
      for (int t2 = 0; t2 < 2; ++t2) {
        v4f s = (v4f){0.f, 0.f, 0.f, 0.f};
        int rowb = (t2 * 16 + lr) * 256;
#pragma unroll
        for (int c = 0; c < 4; ++c) {
          int off = rowb + ((c * 64 + kcol) ^ kswz);
          s8v kh = *(const s8v*)&lkh[cur][off];
          s8v kl = *(const s8v*)&lkl[cur][off];
          s = __builtin_amdgcn_mfma_f32_16x16x32_bf16(qh[c], kh, s, 0, 0, 0);
          s = __builtin_amdgcn_mfma_f32_16x16x32_bf16(qh[c], kl, s, 0, 0, 0);
          s = __builtin_amdgcn_mfma_f32_16x16x32_bf16(ql[c], kh, s, 0, 0, 0);
        }
        sacc[t2] = s;
      }

      // softcap + causal mask + online softmax
      float cc0[4], cc1[4], mt[4];
#pragma unroll
      for (int j = 0; j < 4; ++j) {
        int qg = qbase + lq * 4 + j;
        int k0g = kbase + lr, k1g = kbase + 16 + lr;
        float z0 = __expf(2.f * (sacc[0][j] * kin));
        float z1 = __expf(2.f * (sacc[1][j] * kin));
        float t0 = 50.f - 100.f * __builtin_amdgcn_rcpf(z0 + 1.f);
        float t1 = 50.f - 100.f * __builtin_amdgcn_rcpf(z1 + 1.f);
        cc0[j] = (k0g <= qg) ? t0 : -1e30f;
        cc1[j] = (k1g <= qg) ? t1 : -1e30f;
        mt[j] = fmaxf(cc0[j], cc1[j]);
      }
#pragma unroll
      for (int st = 1; st <= 8; st <<= 1)
#pragma unroll
        for (int j = 0; j < 4; ++j) mt[j] = fmaxf(mt[j], __shfl_xor(mt[j], st));

      float al[4], rs[4];
#pragma unroll
      for (int j = 0; j < 4; ++j) {
        float mnew = fmaxf(mrun[j], mt[j]);
        al[j] = __expf(mrun[j] - mnew);
        mrun[j] = mnew;
        float e0 = __expf(cc0[j] - mnew);
        float e1 = __expf(cc1[j] - mnew);
        rs[j] = e0 + e1;
        int q = lq * 4 + j;
        ps[w][q][lr] = f2bf_rne(e0);
        ps[w][q][16 + lr] = f2bf_rne(e1);
      }
#pragma unroll
      for (int st = 1; st <= 8; st <<= 1)
#pragma unroll
        for (int j = 0; j < 4; ++j) rs[j] += __shfl_xor(rs[j], st);
#pragma unroll
      for (int j = 0; j < 4; ++j) lsum[j] = lsum[j] * al[j] + rs[j];
#pragma unroll
      for (int dt = 0; dt < 8; ++dt)
#pragma unroll
        for (int j = 0; j < 4; ++j) oacc[dt][j] *= al[j];

      s8v pa = *(const s8v*)&ps[w][lr][lq * 8];
#pragma unroll
      for (int dt = 0; dt < 8; ++dt) {
        int off = (dt * 8 + (lr >> 1)) * 128 + vwithin;
        s8v vh = *(const s8v*)&lvt[cur][off];
        oacc[dt] = __builtin_amdgcn_mfma_f32_16x16x32_bf16(pa, vh, oacc[dt], 0, 0, 0);
      }
    }
    __builtin_amdgcn_s_barrier();
  }
#undef STAGE

  float inv[4];
#pragma unroll
  for (int j = 0; j < 4; ++j) inv[j] = 1.f / lsum[j];
  float* ob = out + (size_t)(b * SEQ + qbase) * QDIM + h * HD;
#pragma unroll
  for (int dt = 0; dt < 8; ++dt)
#pragma unroll
    for (int j = 0; j < 4; ++j)
      ob[(size_t)(lq * 4 + j) * QDIM + dt * 16 + lr] = oacc[dt][j] * inv[j];
}

extern "C" void kernel_launch(void* const* d_in, const int* in_sizes, int n_in, void* d_out,
                              int out_size, void* d_ws, size_t ws_size, hipStream_t stream) {
  (void)in_sizes; (void)n_in; (void)out_size; (void)ws_size;
  const float* hidden = (const float*)d_in[0];
  const float* w_in_norm = (const float*)d_in[1];
  const float* w_post_norm = (const float*)d_in[2];
  const float* wqkv = (const float*)d_in[3];
  const float* wo = (const float*)d_in[4];
  const float* w_gate_up = (const float*)d_in[5];
  const float* w_down = (const float*)d_in[6];
  float* out = (float*)d_out;

  char* p = (char*)d_ws;
  size_t off = 0;
  auto take = [&](size_t bytes) -> char* {
    char* r = p + off;
    off += (bytes + 255) & ~(size_t)255;
    return r;
  };
  const size_t MB = 1u << 20;
  int8_t* qx = (int8_t*)take((size_t)T_TOKENS * DM);
  float* sx = (float*)take((size_t)T_TOKENS * 4);
  int8_t* qw_qkv = (int8_t*)take((size_t)QKVN * DM);
  float* sw_qkv = (float*)take((size_t)QKVN * 4);
  int8_t* qw_wo = (int8_t*)take((size_t)DM * QDIM);
  float* sw_wo = (float*)take((size_t)DM * 4);
  int8_t* qw_gu = (int8_t*)take((size_t)GUN * DM);
  float* sw_gu = (float*)take((size_t)GUN * 4);
  int8_t* qw_dn = (int8_t*)take((size_t)DM * INTER);
  float* sw_dn = (float*)take((size_t)DM * 4);
  float* cosT = (float*)take((size_t)SEQ * 64 * 4);
  float* sinT = (float*)take((size_t)SEQ * 64 * 4);
  float* x1 = (float*)take((size_t)T_TOKENS * DM * 4);
  float* s_act = (float*)take((size_t)T_TOKENS * 4);
  char* regB = take(96 * MB);
  float* qf32 = (float*)regB;
  float* kvf32 = (float*)regB;
  float* attn_out = (float*)regB;
  unsigned short* Qhi = (unsigned short*)(regB + 32 * MB);
  unsigned short* Qlo = (unsigned short*)(regB + 48 * MB);
  unsigned short* Khi = (unsigned short*)(regB + 64 * MB);
  unsigned short* Klo = (unsigned short*)(regB + 72 * MB);
  unsigned short* Vt = (unsigned short*)(regB + 80 * MB);
  float* act_f32 = (float*)regB;                       // phase-2: [0,32MB)
  int8_t* act_q8 = (int8_t*)(regB + 64 * MB);          // phase-2: [64,96MB)

  rope_table_kernel<<<SEQ, 64, 0, stream>>>(cosT, sinT);
  quant_w_kernel<<<QKVN, 256, 0, stream>>>(wqkv, qw_qkv, sw_qkv, DM);
  quant_w_kernel<<<DM, 256, 0, stream>>>(wo, qw_wo, sw_wo, QDIM);
  quant_w_gu_kernel<<<GUN, 256, 0, stream>>>(w_gate_up, qw_gu, sw_gu);
  quant_w_kernel<<<DM, 256, 0, stream>>>(w_down, qw_dn, sw_dn, INTER);

  // attention block
  rmsnorm_quant_kernel<<<T_TOKENS, 256, 0, stream>>>(hidden, w_in_norm, qx, sx);
  gemm_i8_kernel<<<dim3(QDIM / 128, T_TOKENS / 128), 256, 0, stream>>>(qx, sx, qw_qkv, sw_qkv,
                                                                       nullptr, qf32, QDIM, DM);
  cvt_q_kernel<<<T_TOKENS, 256, 0, stream>>>(qf32, cosT, sinT, Qhi, Qlo);
  gemm_i8_kernel<<<dim3(DM / 128, T_TOKENS / 128), 256, 0, stream>>>(
      qx, sx, qw_qkv + (size_t)QDIM * DM, sw_qkv + QDIM, nullptr, kvf32, DM, DM);
  cvt_k_kernel<<<T_TOKENS, 256, 0, stream>>>(kvf32, cosT, sinT, Khi, Klo);
  cvt_v_kernel<<<dim3(SEQ / 32, 16), 256, 0, stream>>>(kvf32, Vt);
  attn_mfma_kernel<<<dim3(SEQ / 64, 16), 512, 0, stream>>>(Qhi, Qlo, Khi, Klo, Vt, attn_out);
  quant_rows_2048_kernel<<<T_TOKENS, 256, 0, stream>>>(attn_out, qx, sx);
  gemm_i8_kernel<<<dim3(DM / 128, T_TOKENS / 128), 256, 0, stream>>>(qx, sx, qw_wo, sw_wo, hidden,
                                                                     x1, DM, QDIM);

  // MLP block: fused gelu epilogue writes act f32; quant; single down GEMM
  rmsnorm_quant_kernel<<<T_TOKENS, 256, 0, stream>>>(x1, w_post_norm, qx, sx);
  for (int ch = 0; ch < 4; ++ch) {
    const int8_t* qxc = qx + (size_t)ch * 1024 * DM;
    const float* sxc = sx + (size_t)ch * 1024;
    gemm_gu_fused_kernel<<<dim3(GUN / 128, 1024 / 128), 256, 0, stream>>>(qxc, sxc, qw_gu, sw_gu,
                                                                          act_f32);
    quant_rows_8192_kernel<<<1024, 256, 0, stream>>>(act_f32, act_q8 + (size_t)ch * 1024 * INTER,
                                                     s_act + (size_t)ch * 1024);
  }
  gemm_i8_kernel<<<dim3(DM / 128, T_TOKENS / 128), 256, 0, stream>>>(act_q8, s_act, qw_dn, sw_dn,
                                                                     x1, out, DM, INTER);
}

// Round 6
// 825.638 us; speedup vs baseline: 3.5880x; 1.0528x over previous
//
#include <hip/hip_runtime.h>
#include <cstdint>
#include <math.h>

#define T_TOKENS 4096
#define SEQ 2048
#define DM 2048
#define NH 16
#define NKV 8
#define HD 128
#define QDIM 2048   // NH*HD
#define KVDIM 1024  // NKV*HD
#define QKVN 4096   // QDIM + 2*KVDIM
#define INTER 8192
#define GUN 16384   // 2*INTER

typedef int v4i __attribute__((ext_vector_type(4)));
typedef float v4f __attribute__((ext_vector_type(4)));
typedef short s8v __attribute__((ext_vector_type(8)));
typedef short s4v __attribute__((ext_vector_type(4)));
typedef short s2v __attribute__((ext_vector_type(2)));

#define GL16(g, l)                                                                       \
  __builtin_amdgcn_global_load_lds((__attribute__((address_space(1))) const void*)(g),   \
                                   (__attribute__((address_space(3))) void*)(l), 16, 0, 0)

__device__ inline float wave_sum(float v) {
#pragma unroll
  for (int off = 32; off > 0; off >>= 1) v += __shfl_down(v, off);
  return v;
}
__device__ inline float wave_max(float v) {
#pragma unroll
  for (int off = 32; off > 0; off >>= 1) v = fmaxf(v, __shfl_down(v, off));
  return v;
}
__device__ inline float dot4(float4 a, float4 b) {
  return a.x * b.x + a.y * b.y + a.z * b.z + a.w * b.w;
}
__device__ inline int8_t quant1(float v, float s) {
  float q = rintf(v / s);
  q = fminf(fmaxf(q, -127.f), 127.f);
  return (int8_t)(int)q;
}
__device__ inline unsigned short f2bf_rne(float x) {
  unsigned u = __float_as_uint(x);
  return (unsigned short)((u + 0x7FFFu + ((u >> 16) & 1u)) >> 16);
}
__device__ inline float bf2f(unsigned short h) { return __uint_as_float(((unsigned)h) << 16); }

// ---------------- RoPE tables ----------------
__global__ void rope_table_kernel(float* __restrict__ cosT, float* __restrict__ sinT) {
  int s = blockIdx.x, d = threadIdx.x;  // 64 threads
  float inv = 1.0f / powf(10000.0f, (float)d * (1.0f / 64.0f));
  float f = (float)s * inv;
  cosT[s * 64 + d] = cosf(f);
  sinT[s * 64 + d] = sinf(f);
}

// ---------------- per-row weight quant (single-read, register cached) ----------------
__global__ __launch_bounds__(256) void quant_w_kernel(const float* __restrict__ w,
                                                      int8_t* __restrict__ qw,
                                                      float* __restrict__ sw, int K) {
  __shared__ float red[4];
  int row = blockIdx.x, tid = threadIdx.x;
  const float* wr = w + (size_t)row * K;
  int nv = K >> 10;
  float4 v[8];
  float mx = 0.f;
#pragma unroll
  for (int i = 0; i < 8; i++) {
    if (i < nv) {
      v[i] = *(const float4*)(wr + (size_t)(tid + i * 256) * 4);
      mx = fmaxf(mx, fmaxf(fmaxf(fabsf(v[i].x), fabsf(v[i].y)),
                           fmaxf(fabsf(v[i].z), fabsf(v[i].w))));
    }
  }
  mx = wave_max(mx);
  if ((tid & 63) == 0) red[tid >> 6] = mx;
  __syncthreads();
  float m = fmaxf(fmaxf(red[0], red[1]), fmaxf(red[2], red[3]));
  float s = m * (1.0f / 127.0f);
  if (tid == 0) sw[row] = s;
  float sd = (s > 0.f) ? s : 1.f;
  int8_t* qr = qw + (size_t)row * K;
#pragma unroll
  for (int i = 0; i < 8; i++) {
    if (i < nv) {
      char4 o;
      o.x = quant1(v[i].x, sd);
      o.y = quant1(v[i].y, sd);
      o.z = quant1(v[i].z, sd);
      o.w = quant1(v[i].w, sd);
      *(char4*)(qr + (size_t)(tid + i * 256) * 4) = o;
    }
  }
}

// ---------------- gate_up weight quant with 16-col interleaved permutation ----------------
__global__ __launch_bounds__(256) void quant_w_gu_kernel(const float* __restrict__ w,
                                                         int8_t* __restrict__ qw,
                                                         float* __restrict__ sw) {
  __shared__ float red[4];
  int row = blockIdx.x, tid = threadIdx.x;
  const int K = DM;
  int j = (row < INTER) ? row : row - INTER;
  int pr = (j >> 6) * 128 + ((j >> 4) & 3) * 32 + ((row < INTER) ? 0 : 16) + (j & 15);
  const float* wr = w + (size_t)row * K;
  float4 v[2];
  float mx = 0.f;
#pragma unroll
  for (int i = 0; i < 2; i++) {
    v[i] = *(const float4*)(wr + (size_t)(tid + i * 256) * 4);
    mx = fmaxf(mx, fmaxf(fmaxf(fabsf(v[i].x), fabsf(v[i].y)),
                         fmaxf(fabsf(v[i].z), fabsf(v[i].w))));
  }
  mx = wave_max(mx);
  if ((tid & 63) == 0) red[tid >> 6] = mx;
  __syncthreads();
  float m = fmaxf(fmaxf(red[0], red[1]), fmaxf(red[2], red[3]));
  float s = m * (1.0f / 127.0f);
  if (tid == 0) sw[pr] = s;
  float sd = (s > 0.f) ? s : 1.f;
  int8_t* qr = qw + (size_t)pr * K;
#pragma unroll
  for (int i = 0; i < 2; i++) {
    char4 o;
    o.x = quant1(v[i].x, sd);
    o.y = quant1(v[i].y, sd);
    o.z = quant1(v[i].z, sd);
    o.w = quant1(v[i].w, sd);
    *(char4*)(qr + (size_t)(tid + i * 256) * 4) = o;
  }
}

// ---------------- RMSNorm + per-token quant ----------------
__global__ __launch_bounds__(256) void rmsnorm_quant_kernel(const float* __restrict__ x,
                                                            const float* __restrict__ w,
                                                            int8_t* __restrict__ q,
                                                            float* __restrict__ s) {
  __shared__ float red[8];
  int t = blockIdx.x, tid = threadIdx.x;
  const float* xr = x + (size_t)t * DM;
  float4 a = *(const float4*)(xr + tid * 8);
  float4 b = *(const float4*)(xr + tid * 8 + 4);
  float ss = dot4(a, a) + dot4(b, b);
  ss = wave_sum(ss);
  if ((tid & 63) == 0) red[tid >> 6] = ss;
  __syncthreads();
  float tot = red[0] + red[1] + red[2] + red[3];
  float rms = rsqrtf(tot * (1.0f / DM) + 1e-6f);
  float4 wa = *(const float4*)(w + tid * 8);
  float4 wb = *(const float4*)(w + tid * 8 + 4);
  float y[8] = {a.x * rms * wa.x, a.y * rms * wa.y, a.z * rms * wa.z, a.w * rms * wa.w,
                b.x * rms * wb.x, b.y * rms * wb.y, b.z * rms * wb.z, b.w * rms * wb.w};
  float mx = 0.f;
#pragma unroll
  for (int i = 0; i < 8; i++) mx = fmaxf(mx, fabsf(y[i]));
  mx = wave_max(mx);
  if ((tid & 63) == 0) red[4 + (tid >> 6)] = mx;
  __syncthreads();
  float m = fmaxf(fmaxf(red[4], red[5]), fmaxf(red[6], red[7]));
  float sc = fmaxf(m * (1.0f / 127.0f), 1e-8f);
  if (tid == 0) s[t] = sc;
  int8_t* qr = q + (size_t)t * DM + tid * 8;
  char4 o0, o1;
  o0.x = quant1(y[0], sc); o0.y = quant1(y[1], sc); o0.z = quant1(y[2], sc); o0.w = quant1(y[3], sc);
  o1.x = quant1(y[4], sc); o1.y = quant1(y[5], sc); o1.z = quant1(y[6], sc); o1.w = quant1(y[7], sc);
  *(char4*)(qr) = o0;
  *(char4*)(qr + 4) = o1;
}

// ---------------- plain per-token quant of a [*,2048] f32 matrix ----------------
__global__ __launch_bounds__(256) void quant_rows_2048_kernel(const float* __restrict__ x,
                                                              int8_t* __restrict__ q,
                                                              float* __restrict__ s) {
  __shared__ float red[4];
  int t = blockIdx.x, tid = threadIdx.x;
  const float* xr = x + (size_t)t * DM;
  float4 a = *(const float4*)(xr + tid * 8);
  float4 b = *(const float4*)(xr + tid * 8 + 4);
  float y[8] = {a.x, a.y, a.z, a.w, b.x, b.y, b.z, b.w};
  float mx = 0.f;
#pragma unroll
  for (int i = 0; i < 8; i++) mx = fmaxf(mx, fabsf(y[i]));
  mx = wave_max(mx);
  if ((tid & 63) == 0) red[tid >> 6] = mx;
  __syncthreads();
  float m = fmaxf(fmaxf(red[0], red[1]), fmaxf(red[2], red[3]));
  float sc = fmaxf(m * (1.0f / 127.0f), 1e-8f);
  if (tid == 0) s[t] = sc;
  int8_t* qr = q + (size_t)t * DM + tid * 8;
  char4 o0, o1;
  o0.x = quant1(y[0], sc); o0.y = quant1(y[1], sc); o0.z = quant1(y[2], sc); o0.w = quant1(y[3], sc);
  o1.x = quant1(y[4], sc); o1.y = quant1(y[5], sc); o1.z = quant1(y[6], sc); o1.w = quant1(y[7], sc);
  *(char4*)(qr) = o0;
  *(char4*)(qr + 4) = o1;
}

// ---------------- per-token quant of a [*,8192] f32 matrix ----------------
__global__ __launch_bounds__(256) void quant_rows_8192_kernel(const float* __restrict__ x,
                                                              int8_t* __restrict__ q,
                                                              float* __restrict__ s) {
  __shared__ float red[4];
  int t = blockIdx.x, tid = threadIdx.x;
  const float* xr = x + (size_t)t * INTER + tid * 32;
  float y[32];
  float mx = 0.f;
#pragma unroll
  for (int i4 = 0; i4 < 32; i4 += 4) {
    float4 v = *(const float4*)(xr + i4);
    y[i4] = v.x; y[i4 + 1] = v.y; y[i4 + 2] = v.z; y[i4 + 3] = v.w;
    mx = fmaxf(mx, fmaxf(fmaxf(fabsf(v.x), fabsf(v.y)), fmaxf(fabsf(v.z), fabsf(v.w))));
  }
  mx = wave_max(mx);
  if ((tid & 63) == 0) red[tid >> 6] = mx;
  __syncthreads();
  float m = fmaxf(fmaxf(red[0], red[1]), fmaxf(red[2], red[3]));
  float sc = fmaxf(m * (1.0f / 127.0f), 1e-8f);
  if (tid == 0) s[t] = sc;
  int8_t* qr = q + (size_t)t * INTER + tid * 32;
#pragma unroll
  for (int i4 = 0; i4 < 32; i4 += 4) {
    char4 o;
    o.x = quant1(y[i4], sc);
    o.y = quant1(y[i4 + 1], sc);
    o.z = quant1(y[i4 + 2], sc);
    o.w = quant1(y[i4 + 3], sc);
    *(char4*)(qr + i4) = o;
  }
}

// ---------------- RoPE + f32->bf16 hi/lo conversion: Q ----------------
__global__ __launch_bounds__(256) void cvt_q_kernel(const float* __restrict__ qf,
                                                    const float* __restrict__ cosT,
                                                    const float* __restrict__ sinT,
                                                    unsigned short* __restrict__ Qhi,
                                                    unsigned short* __restrict__ Qlo) {
  int t = blockIdx.x, tid = threadIdx.x;
  int sp = t & (SEQ - 1);
  int h = tid >> 4, pb = (tid & 15) * 4;
  const float* row = qf + (size_t)t * QDIM + h * HD;
  float4 x0 = *(const float4*)(row + pb);
  float4 x1 = *(const float4*)(row + pb + 64);
  float4 c = *(const float4*)(cosT + sp * 64 + pb);
  float4 s = *(const float4*)(sinT + sp * 64 + pb);
  float y0[4] = {x0.x * c.x - x1.x * s.x, x0.y * c.y - x1.y * s.y, x0.z * c.z - x1.z * s.z,
                 x0.w * c.w - x1.w * s.w};
  float y1[4] = {x1.x * c.x + x0.x * s.x, x1.y * c.y + x0.y * s.y, x1.z * c.z + x0.z * s.z,
                 x1.w * c.w + x0.w * s.w};
  s4v h0, l0, h1, l1;
#pragma unroll
  for (int e = 0; e < 4; e++) {
    unsigned short hb = f2bf_rne(y0[e]);
    h0[e] = (short)hb;
    l0[e] = (short)f2bf_rne(y0[e] - bf2f(hb));
    hb = f2bf_rne(y1[e]);
    h1[e] = (short)hb;
    l1[e] = (short)f2bf_rne(y1[e] - bf2f(hb));
  }
  size_t o = (size_t)t * QDIM + h * HD + pb;
  *(s4v*)&Qhi[o] = h0;
  *(s4v*)&Qlo[o] = l0;
  *(s4v*)&Qhi[o + 64] = h1;
  *(s4v*)&Qlo[o + 64] = l1;
}

// ---------------- RoPE + conversion: K (layout [(b,g)][s][d]) ----------------
__global__ __launch_bounds__(256) void cvt_k_kernel(const float* __restrict__ kvf,
                                                    const float* __restrict__ cosT,
                                                    const float* __restrict__ sinT,
                                                    unsigned short* __restrict__ Khi,
                                                    unsigned short* __restrict__ Klo) {
  int t = blockIdx.x, tid = threadIdx.x;
  int sp = t & (SEQ - 1);
  int b = t >> 11;
  int g = tid >> 5, pb = (tid & 31) * 2;
  const float* row = kvf + (size_t)t * DM + g * HD;
  float2 x0 = *(const float2*)(row + pb);
  float2 x1 = *(const float2*)(row + pb + 64);
  float2 c = *(const float2*)(cosT + sp * 64 + pb);
  float2 s = *(const float2*)(sinT + sp * 64 + pb);
  float y0[2] = {x0.x * c.x - x1.x * s.x, x0.y * c.y - x1.y * s.y};
  float y1[2] = {x1.x * c.x + x0.x * s.x, x1.y * c.y + x0.y * s.y};
  s2v h0, l0, h1, l1;
#pragma unroll
  for (int e = 0; e < 2; e++) {
    unsigned short hb = f2bf_rne(y0[e]);
    h0[e] = (short)hb;
    l0[e] = (short)f2bf_rne(y0[e] - bf2f(hb));
    hb = f2bf_rne(y1[e]);
    h1[e] = (short)hb;
    l1[e] = (short)f2bf_rne(y1[e] - bf2f(hb));
  }
  size_t o = ((size_t)(b * NKV + g) * SEQ + sp) * HD + pb;
  *(s2v*)&Khi[o] = h0;
  *(s2v*)&Klo[o] = l0;
  *(s2v*)&Khi[o + 64] = h1;
  *(s2v*)&Klo[o + 64] = l1;
}

// ---------------- V transpose + conversion ----------------
// New Vt layout per bg: per 32-k tile (8192B): [kc 0-3][d 0-127][e 0-7] bf16
// short index = (s>>5)*4096 + ((s&31)>>3)*1024 + d*8 + (s&7)
__global__ __launch_bounds__(256) void cvt_v_kernel(const float* __restrict__ kvf,
                                                    unsigned short* __restrict__ Vt) {
  __shared__ float vt[32][132];
  int bg = blockIdx.y;
  int b = bg >> 3, g = bg & 7;
  int s0 = blockIdx.x * 32;
  int tid = threadIdx.x;
#pragma unroll
  for (int i = 0; i < 4; i++) {
    int pos = tid + i * 256;
    int r = pos >> 5, d4 = (pos & 31) * 4;
    *(float4*)&vt[r][d4] =
        *(const float4*)(kvf + (size_t)(b * SEQ + s0 + r) * DM + KVDIM + g * HD + d4);
  }
  __syncthreads();
  int d = tid & 127, half = tid >> 7;
  unsigned short u[16];
#pragma unroll
  for (int i = 0; i < 16; i++) u[i] = f2bf_rne(vt[half * 16 + i][d]);
  unsigned short* dst =
      Vt + (size_t)bg * HD * SEQ + (size_t)(s0 >> 5) * 4096 + (half * 2) * 1024 + d * 8;
  *(s8v*)dst = *(s8v*)&u[0];
  *(s8v*)(dst + 1024) = *(s8v*)&u[8];
}

// ---------------- int8 GEMM (global_load_lds + XOR swizzle, 128x128, BK=128) ----------------
__global__ __launch_bounds__(256) void gemm_i8_kernel(const int8_t* __restrict__ A,
                                                      const float* __restrict__ sA,
                                                      const int8_t* __restrict__ B,
                                                      const float* __restrict__ sB,
                                                      const float* __restrict__ res,
                                                      float* __restrict__ C, int N, int K) {
  __shared__ __align__(16) int8_t lA[16384];
  __shared__ __align__(16) int8_t lB[16384];
  int tid = threadIdx.x;
  int row0 = blockIdx.y * 128;
  int col0 = blockIdx.x * 128;
  int lane = tid & 63, wid = tid >> 6;
  int wm = (wid >> 1) * 64, wn = (wid & 1) * 64;
  int fr = lane & 15, lq = lane >> 4;

  // staging: rows are 128B; thread covers row rT=tid>>3, issues step rows by 32
  int rT = tid >> 3;
  int colS = ((tid & 7) << 4) ^ ((rT & 7) << 4);
  const int8_t* gA = A + (size_t)(row0 + rT) * K + colS;
  const int8_t* gB = B + (size_t)(col0 + rT) * K + colS;
  int8_t* lAd = &lA[tid * 16];
  int8_t* lBd = &lB[tid * 16];

  int swzk = (fr & 7) << 4;
  int aoff[4], boff[4];
#pragma unroll
  for (int m = 0; m < 4; m++) {
    aoff[m] = (wm + m * 16 + fr) * 128;
    boff[m] = (wn + m * 16 + fr) * 128;
  }

  v4i acc[4][4];
#pragma unroll
  for (int m = 0; m < 4; m++)
#pragma unroll
    for (int n = 0; n < 4; n++) acc[m][n] = (v4i){0, 0, 0, 0};

  for (int k0 = 0; k0 < K; k0 += 128) {
#pragma unroll
    for (int i = 0; i < 4; i++) GL16(gA + k0 + (size_t)(32 * i) * K, lAd + i * 4096);
#pragma unroll
    for (int i = 0; i < 4; i++) GL16(gB + k0 + (size_t)(32 * i) * K, lBd + i * 4096);
    __syncthreads();
#pragma unroll
    for (int kk = 0; kk < 2; kk++) {
      int kc = (kk * 64 + lq * 16) ^ swzk;
      v4i a[4], b[4];
#pragma unroll
      for (int m = 0; m < 4; m++) a[m] = *(const v4i*)&lA[aoff[m] + kc];
#pragma unroll
      for (int n = 0; n < 4; n++) b[n] = *(const v4i*)&lB[boff[n] + kc];
#pragma unroll
      for (int m = 0; m < 4; m++)
#pragma unroll
        for (int n = 0; n < 4; n++)
          acc[m][n] = __builtin_amdgcn_mfma_i32_16x16x64_i8(a[m], b[n], acc[m][n], 0, 0, 0);
    }
    __syncthreads();
  }
  int rj = lq * 4;
  int cn = fr;
#pragma unroll
  for (int m = 0; m < 4; m++) {
#pragma unroll
    for (int j = 0; j < 4; j++) {
      int rl = row0 + wm + m * 16 + rj + j;
      float sa = sA[rl];
      size_t rowoff = (size_t)rl * N;
#pragma unroll
      for (int n = 0; n < 4; n++) {
        int cg = col0 + wn + n * 16 + cn;
        float v = (float)acc[m][n][j] * sa * sB[cg];
        if (res) v += res[rowoff + cg];
        C[rowoff + cg] = v;
      }
    }
  }
}

// ---------------- int8 GEMM + fused gelu(gate)*up epilogue (permuted gu weights) ----------
__global__ __launch_bounds__(256) void gemm_gu_fused_kernel(const int8_t* __restrict__ A,
                                                            const float* __restrict__ sA,
                                                            const int8_t* __restrict__ B,
                                                            const float* __restrict__ sB,
                                                            float* __restrict__ act) {
  __shared__ __align__(16) int8_t lA[16384];
  __shared__ __align__(16) int8_t lB[16384];
  const int K = DM;
  int tid = threadIdx.x;
  int row0 = blockIdx.y * 128;
  int col0 = blockIdx.x * 128;
  int lane = tid & 63, wid = tid >> 6;
  int wm = (wid >> 1) * 64, wn = (wid & 1) * 64;
  int fr = lane & 15, lq = lane >> 4;

  int rT = tid >> 3;
  int colS = ((tid & 7) << 4) ^ ((rT & 7) << 4);
  const int8_t* gA = A + (size_t)(row0 + rT) * K + colS;
  const int8_t* gB = B + (size_t)(col0 + rT) * K + colS;
  int8_t* lAd = &lA[tid * 16];
  int8_t* lBd = &lB[tid * 16];

  int swzk = (fr & 7) << 4;
  int aoff[4], boff[4];
#pragma unroll
  for (int m = 0; m < 4; m++) {
    aoff[m] = (wm + m * 16 + fr) * 128;
    boff[m] = (wn + m * 16 + fr) * 128;
  }

  v4i acc[4][4];
#pragma unroll
  for (int m = 0; m < 4; m++)
#pragma unroll
    for (int n = 0; n < 4; n++) acc[m][n] = (v4i){0, 0, 0, 0};

  for (int k0 = 0; k0 < K; k0 += 128) {
#pragma unroll
    for (int i = 0; i < 4; i++) GL16(gA + k0 + (size_t)(32 * i) * K, lAd + i * 4096);
#pragma unroll
    for (int i = 0; i < 4; i++) GL16(gB + k0 + (size_t)(32 * i) * K, lBd + i * 4096);
    __syncthreads();
#pragma unroll
    for (int kk = 0; kk < 2; kk++) {
      int kc = (kk * 64 + lq * 16) ^ swzk;
      v4i a[4], b[4];
#pragma unroll
      for (int m = 0; m < 4; m++) a[m] = *(const v4i*)&lA[aoff[m] + kc];
#pragma unroll
      for (int n = 0; n < 4; n++) b[n] = *(const v4i*)&lB[boff[n] + kc];
#pragma unroll
      for (int m = 0; m < 4; m++)
#pragma unroll
        for (int n = 0; n < 4; n++)
          acc[m][n] = __builtin_amdgcn_mfma_i32_16x16x64_i8(a[m], b[n], acc[m][n], 0, 0, 0);
    }
    __syncthreads();
  }
  int rj = lq * 4;
  int cn = fr;
#pragma unroll
  for (int m = 0; m < 4; m++) {
#pragma unroll
    for (int j = 0; j < 4; j++) {
      int rl = row0 + wm + m * 16 + rj + j;
      float sa = sA[rl];
      size_t rowoff = (size_t)rl * INTER;
#pragma unroll
      for (int np = 0; np < 2; np++) {
        float gv = (float)acc[m][np * 2][j] * sa * sB[col0 + wn + (np * 2) * 16 + cn];
        float uv = (float)acc[m][np * 2 + 1][j] * sa * sB[col0 + wn + (np * 2 + 1) * 16 + cn];
        float inner = 0.7978845608028654f * (gv + 0.044715f * gv * gv * gv);
        float gl = 0.5f * gv * (1.0f + tanhf(inner));
        int jg = (col0 >> 1) + (wn >> 1) + np * 16 + cn;
        act[rowoff + jg] = gl * uv;
      }
    }
  }
}

// ---------------- flash attention: 512 thr, 2 heads (1 KV group) per block ----------------
// LDS K tiles: [32][256B] rows, XOR swizzle byte^=((row&7)<<4).
// LDS V tiles: k-chunk-major [kc 0-3][d 0-127][16B] -- zero-conflict, no swizzle.
__global__ __launch_bounds__(512, 4) void attn_mfma_kernel(
    const unsigned short* __restrict__ Qhi, const unsigned short* __restrict__ Qlo,
    const unsigned short* __restrict__ Khi, const unsigned short* __restrict__ Klo,
    const unsigned short* __restrict__ Vt, float* __restrict__ out) {
  __shared__ __align__(16) int8_t lkh[2][8192], lkl[2][8192], lvt[2][8192];
  __shared__ unsigned short ps[8][16][40];
  int qt = (int)gridDim.x - 1 - (int)blockIdx.x;  // big tiles first
  int bg = blockIdx.y;
  int b = bg >> 3, g = bg & 7;
  int tid = threadIdx.x;
  int lane = tid & 63, w = tid >> 6;
  int lr = lane & 15, lq = lane >> 4;
  int h = g * 2 + (w >> 2);
  int qbase = qt * 64 + (w & 3) * 16;

  const int8_t* kbh = (const int8_t*)(Khi + (size_t)bg * SEQ * HD);
  const int8_t* kbl = (const int8_t*)(Klo + (size_t)bg * SEQ * HD);
  const int8_t* vb = (const int8_t*)(Vt + (size_t)bg * HD * SEQ);

  // staging: one GL16 per lane per plane (512 lanes x 16B = 8192B)
  int xK = tid * 16;
  int sK = xK ^ (((xK >> 8) & 7) << 4);

  // Q fragments (hi/lo) in registers
  s8v qh[4], ql[4];
  {
    size_t qo = (size_t)(b * SEQ + qbase + lr) * QDIM + h * HD + lq * 8;
#pragma unroll
    for (int c = 0; c < 4; ++c) {
      qh[c] = *(const s8v*)(Qhi + qo + c * 32);
      ql[c] = *(const s8v*)(Qlo + qo + c * 32);
    }
  }

  v4f oacc[8];
#pragma unroll
  for (int i = 0; i < 8; ++i) oacc[i] = (v4f){0.f, 0.f, 0.f, 0.f};
  float mrun[4] = {-1e30f, -1e30f, -1e30f, -1e30f};
  float lsum[4] = {0.f, 0.f, 0.f, 0.f};
  const float kin = 0.0017677669529663687f;  // 1/(sqrt(128)*50)

  int kswz = (lr & 7) << 4;
  int kcol = lq * 16;
  int vbase = lq * 2048 + lr * 16;  // + dt*256

  int ktiles = 2 * qt + 2;

#define STAGE(kt, buf)                                  \
  do {                                                  \
    size_t kb = (size_t)(kt) * 8192;                    \
    GL16(kbh + kb + sK, &lkh[buf][xK]);                 \
    GL16(kbl + kb + sK, &lkl[buf][xK]);                 \
    GL16(vb + kb + xK, &lvt[buf][xK]);                  \
  } while (0)

  STAGE(0, 0);
  for (int kt = 0; kt < ktiles; ++kt) {
    int cur = kt & 1;
    if (kt + 1 < ktiles) {
      STAGE(kt + 1, cur ^ 1);
      asm volatile("s_waitcnt vmcnt(3)" ::: "memory");
    } else {
      asm volatile("s_waitcnt vmcnt(0)" ::: "memory");
    }
    __builtin_amdgcn_s_barrier();
    __builtin_amdgcn_sched_barrier(0);
    int kbase = kt * 32;
    if (kbase <= qbase + 15) {
      // QK^T: two 16x16 tiles, 3-term hi/lo
      v4f sacc[2];
#pragma unroll
      for (int t2 = 0; t2 < 2; ++t2) {
        v4f s = (v4f){0.f, 0.f, 0.f, 0.f};
        int rowb = (t2 * 16 + lr) * 256;
#pragma unroll
        for (int c = 0; c < 4; ++c) {
          int off = rowb + ((c * 64 + kcol) ^ kswz);
          s8v kh = *(const s8v*)&lkh[cur][off];
          s8v kl = *(const s8v*)&lkl[cur][off];
          s = __builtin_amdgcn_mfma_f32_16x16x32_bf16(qh[c], kh, s, 0, 0, 0);
          s = __builtin_amdgcn_mfma_f32_16x16x32_bf16(qh[c], kl, s, 0, 0, 0);
          s = __builtin_amdgcn_mfma_f32_16x16x32_bf16(ql[c], kh, s, 0, 0, 0);
        }
        sacc[t2] = s;
      }

      // softcap + causal mask + online softmax
      float cc0[4], cc1[4], mt[4];
#pragma unroll
      for (int j = 0; j < 4; ++j) {
        int qg = qbase + lq * 4 + j;
        int k0g = kbase + lr, k1g = kbase + 16 + lr;
        float z0 = __expf(2.f * (sacc[0][j] * kin));
        float z1 = __expf(2.f * (sacc[1][j] * kin));
        float t0 = 50.f - 100.f * __builtin_amdgcn_rcpf(z0 + 1.f);
        float t1 = 50.f - 100.f * __builtin_amdgcn_rcpf(z1 + 1.f);
        cc0[j] = (k0g <= qg) ? t0 : -1e30f;
        cc1[j] = (k1g <= qg) ? t1 : -1e30f;
        mt[j] = fmaxf(cc0[j], cc1[j]);
      }
#pragma unroll
      for (int st = 1; st <= 8; st <<= 1)
#pragma unroll
        for (int j = 0; j < 4; ++j) mt[j] = fmaxf(mt[j], __shfl_xor(mt[j], st));

      float al[4], rs[4];
#pragma unroll
      for (int j = 0; j < 4; ++j) {
        float mnew = fmaxf(mrun[j], mt[j]);
        al[j] = __expf(mrun[j] - mnew);
        mrun[j] = mnew;
        float e0 = __expf(cc0[j] - mnew);
        float e1 = __expf(cc1[j] - mnew);
        rs[j] = e0 + e1;
        int q = lq * 4 + j;
        ps[w][q][lr] = f2bf_rne(e0);
        ps[w][q][16 + lr] = f2bf_rne(e1);
      }
#pragma unroll
      for (int st = 1; st <= 8; st <<= 1)
#pragma unroll
        for (int j = 0; j < 4; ++j) rs[j] += __shfl_xor(rs[j], st);
#pragma unroll
      for (int j = 0; j < 4; ++j) lsum[j] = lsum[j] * al[j] + rs[j];
#pragma unroll
      for (int dt = 0; dt < 8; ++dt)
#pragma unroll
        for (int j = 0; j < 4; ++j) oacc[dt][j] *= al[j];

      s8v pa = *(const s8v*)&ps[w][lr][lq * 8];
#pragma unroll
      for (int dt = 0; dt < 8; ++dt) {
        s8v vh = *(const s8v*)&lvt[cur][vbase + dt * 256];
        oacc[dt] = __builtin_amdgcn_mfma_f32_16x16x32_bf16(pa, vh, oacc[dt], 0, 0, 0);
      }
    }
    __builtin_amdgcn_s_barrier();
  }
#undef STAGE

  float inv[4];
#pragma unroll
  for (int j = 0; j < 4; ++j) inv[j] = 1.f / lsum[j];
  float* ob = out + (size_t)(b * SEQ + qbase) * QDIM + h * HD;
#pragma unroll
  for (int dt = 0; dt < 8; ++dt)
#pragma unroll
    for (int j = 0; j < 4; ++j)
      ob[(size_t)(lq * 4 + j) * QDIM + dt * 16 + lr] = oacc[dt][j] * inv[j];
}

extern "C" void kernel_launch(void* const* d_in, const int* in_sizes, int n_in, void* d_out,
                              int out_size, void* d_ws, size_t ws_size, hipStream_t stream) {
  (void)in_sizes; (void)n_in; (void)out_size; (void)ws_size;
  const float* hidden = (const float*)d_in[0];
  const float* w_in_norm = (const float*)d_in[1];
  const float* w_post_norm = (const float*)d_in[2];
  const float* wqkv = (const float*)d_in[3];
  const float* wo = (const float*)d_in[4];
  const float* w_gate_up = (const float*)d_in[5];
  const float* w_down = (const float*)d_in[6];
  float* out = (float*)d_out;

  char* p = (char*)d_ws;
  size_t off = 0;
  auto take = [&](size_t bytes) -> char* {
    char* r = p + off;
    off += (bytes + 255) & ~(size_t)255;
    return r;
  };
  const size_t MB = 1u << 20;
  int8_t* qx = (int8_t*)take((size_t)T_TOKENS * DM);
  float* sx = (float*)take((size_t)T_TOKENS * 4);
  int8_t* qw_qkv = (int8_t*)take((size_t)QKVN * DM);
  float* sw_qkv = (float*)take((size_t)QKVN * 4);
  int8_t* qw_wo = (int8_t*)take((size_t)DM * QDIM);
  float* sw_wo = (float*)take((size_t)DM * 4);
  int8_t* qw_gu = (int8_t*)take((size_t)GUN * DM);
  float* sw_gu = (float*)take((size_t)GUN * 4);
  int8_t* qw_dn = (int8_t*)take((size_t)DM * INTER);
  float* sw_dn = (float*)take((size_t)DM * 4);
  float* cosT = (float*)take((size_t)SEQ * 64 * 4);
  float* sinT = (float*)take((size_t)SEQ * 64 * 4);
  float* x1 = (float*)take((size_t)T_TOKENS * DM * 4);
  float* s_act = (float*)take((size_t)T_TOKENS * 4);
  char* regB = take(96 * MB);
  float* qf32 = (float*)regB;
  float* kvf32 = (float*)regB;
  float* attn_out = (float*)regB;
  unsigned short* Qhi = (unsigned short*)(regB + 32 * MB);
  unsigned short* Qlo = (unsigned short*)(regB + 48 * MB);
  unsigned short* Khi = (unsigned short*)(regB + 64 * MB);
  unsigned short* Klo = (unsigned short*)(regB + 72 * MB);
  unsigned short* Vt = (unsigned short*)(regB + 80 * MB);
  float* act_f32 = (float*)regB;                       // phase-2: [0,32MB)
  int8_t* act_q8 = (int8_t*)(regB + 64 * MB);          // phase-2: [64,96MB)

  rope_table_kernel<<<SEQ, 64, 0, stream>>>(cosT, sinT);
  quant_w_kernel<<<QKVN, 256, 0, stream>>>(wqkv, qw_qkv, sw_qkv, DM);
  quant_w_kernel<<<DM, 256, 0, stream>>>(wo, qw_wo, sw_wo, QDIM);
  quant_w_gu_kernel<<<GUN, 256, 0, stream>>>(w_gate_up, qw_gu, sw_gu);
  quant_w_kernel<<<DM, 256, 0, stream>>>(w_down, qw_dn, sw_dn, INTER);

  // attention block
  rmsnorm_quant_kernel<<<T_TOKENS, 256, 0, stream>>>(hidden, w_in_norm, qx, sx);
  gemm_i8_kernel<<<dim3(QDIM / 128, T_TOKENS / 128), 256, 0, stream>>>(qx, sx, qw_qkv, sw_qkv,
                                                                       nullptr, qf32, QDIM, DM);
  cvt_q_kernel<<<T_TOKENS, 256, 0, stream>>>(qf32, cosT, sinT, Qhi, Qlo);
  gemm_i8_kernel<<<dim3(DM / 128, T_TOKENS / 128), 256, 0, stream>>>(
      qx, sx, qw_qkv + (size_t)QDIM * DM, sw_qkv + QDIM, nullptr, kvf32, DM, DM);
  cvt_k_kernel<<<T_TOKENS, 256, 0, stream>>>(kvf32, cosT, sinT, Khi, Klo);
  cvt_v_kernel<<<dim3(SEQ / 32, 16), 256, 0, stream>>>(kvf32, Vt);
  attn_mfma_kernel<<<dim3(SEQ / 64, 16), 512, 0, stream>>>(Qhi, Qlo, Khi, Klo, Vt, attn_out);
  quant_rows_2048_kernel<<<T_TOKENS, 256, 0, stream>>>(attn_out, qx, sx);
  gemm_i8_kernel<<<dim3(DM / 128, T_TOKENS / 128), 256, 0, stream>>>(qx, sx, qw_wo, sw_wo, hidden,
                                                                     x1, DM, QDIM);

  // MLP block: fused gelu epilogue writes act f32; quant; single down GEMM
  rmsnorm_quant_kernel<<<T_TOKENS, 256, 0, stream>>>(x1, w_post_norm, qx, sx);
  for (int ch = 0; ch < 4; ++ch) {
    const int8_t* qxc = qx + (size_t)ch * 1024 * DM;
    const float* sxc = sx + (size_t)ch * 1024;
    gemm_gu_fused_kernel<<<dim3(GUN / 128, 1024 / 128), 256, 0, stream>>>(qxc, sxc, qw_gu, sw_gu,
                                                                          act_f32);
    quant_rows_8192_kernel<<<1024, 256, 0, stream>>>(act_f32, act_q8 + (size_t)ch * 1024 * INTER,
                                                     s_act + (size_t)ch * 1024);
  }
  gemm_i8_kernel<<<dim3(DM / 128, T_TOKENS / 128), 256, 0, stream>>>(act_q8, s_act, qw_dn, sw_dn,
                                                                     x1, out, DM, INTER);
}

// Round 7
// 744.803 us; speedup vs baseline: 3.9775x; 1.1085x over previous
//
#include <hip/hip_runtime.h>
#include <cstdint>
#include <math.h>

#define T_TOKENS 4096
#define SEQ 2048
#define DM 2048
#define NH 16
#define NKV 8
#define HD 128
#define QDIM 2048   // NH*HD
#define KVDIM 1024  // NKV*HD
#define QKVN 4096   // QDIM + 2*KVDIM
#define INTER 8192
#define GUN 16384   // 2*INTER

typedef int v4i __attribute__((ext_vector_type(4)));
typedef float v4f __attribute__((ext_vector_type(4)));
typedef short s8v __attribute__((ext_vector_type(8)));
typedef short s4v __attribute__((ext_vector_type(4)));
typedef short s2v __attribute__((ext_vector_type(2)));

#define GL16(g, l)                                                                       \
  __builtin_amdgcn_global_load_lds((__attribute__((address_space(1))) const void*)(g),   \
                                   (__attribute__((address_space(3))) void*)(l), 16, 0, 0)

__device__ inline float wave_sum(float v) {
#pragma unroll
  for (int off = 32; off > 0; off >>= 1) v += __shfl_down(v, off);
  return v;
}
__device__ inline float wave_max(float v) {
#pragma unroll
  for (int off = 32; off > 0; off >>= 1) v = fmaxf(v, __shfl_down(v, off));
  return v;
}
__device__ inline float dot4(float4 a, float4 b) {
  return a.x * b.x + a.y * b.y + a.z * b.z + a.w * b.w;
}
__device__ inline int8_t quant1(float v, float s) {
  float q = rintf(v / s);
  q = fminf(fmaxf(q, -127.f), 127.f);
  return (int8_t)(int)q;
}
__device__ inline unsigned short f2bf_rne(float x) {
  unsigned u = __float_as_uint(x);
  return (unsigned short)((u + 0x7FFFu + ((u >> 16) & 1u)) >> 16);
}
__device__ inline float bf2f(unsigned short h) { return __uint_as_float(((unsigned)h) << 16); }

// ---------------- RoPE tables ----------------
__global__ void rope_table_kernel(float* __restrict__ cosT, float* __restrict__ sinT) {
  int s = blockIdx.x, d = threadIdx.x;  // 64 threads
  float inv = 1.0f / powf(10000.0f, (float)d * (1.0f / 64.0f));
  float f = (float)s * inv;
  cosT[s * 64 + d] = cosf(f);
  sinT[s * 64 + d] = sinf(f);
}

// ---------------- per-row weight quant (single-read, register cached) ----------------
__global__ __launch_bounds__(256) void quant_w_kernel(const float* __restrict__ w,
                                                      int8_t* __restrict__ qw,
                                                      float* __restrict__ sw, int K) {
  __shared__ float red[4];
  int row = blockIdx.x, tid = threadIdx.x;
  const float* wr = w + (size_t)row * K;
  int nv = K >> 10;
  float4 v[8];
  float mx = 0.f;
#pragma unroll
  for (int i = 0; i < 8; i++) {
    if (i < nv) {
      v[i] = *(const float4*)(wr + (size_t)(tid + i * 256) * 4);
      mx = fmaxf(mx, fmaxf(fmaxf(fabsf(v[i].x), fabsf(v[i].y)),
                           fmaxf(fabsf(v[i].z), fabsf(v[i].w))));
    }
  }
  mx = wave_max(mx);
  if ((tid & 63) == 0) red[tid >> 6] = mx;
  __syncthreads();
  float m = fmaxf(fmaxf(red[0], red[1]), fmaxf(red[2], red[3]));
  float s = m * (1.0f / 127.0f);
  if (tid == 0) sw[row] = s;
  float sd = (s > 0.f) ? s : 1.f;
  int8_t* qr = qw + (size_t)row * K;
#pragma unroll
  for (int i = 0; i < 8; i++) {
    if (i < nv) {
      char4 o;
      o.x = quant1(v[i].x, sd);
      o.y = quant1(v[i].y, sd);
      o.z = quant1(v[i].z, sd);
      o.w = quant1(v[i].w, sd);
      *(char4*)(qr + (size_t)(tid + i * 256) * 4) = o;
    }
  }
}

// ---------------- gate_up weight quant with 16-col interleaved permutation ----------------
__global__ __launch_bounds__(256) void quant_w_gu_kernel(const float* __restrict__ w,
                                                         int8_t* __restrict__ qw,
                                                         float* __restrict__ sw) {
  __shared__ float red[4];
  int row = blockIdx.x, tid = threadIdx.x;
  const int K = DM;
  int j = (row < INTER) ? row : row - INTER;
  int pr = (j >> 6) * 128 + ((j >> 4) & 3) * 32 + ((row < INTER) ? 0 : 16) + (j & 15);
  const float* wr = w + (size_t)row * K;
  float4 v[2];
  float mx = 0.f;
#pragma unroll
  for (int i = 0; i < 2; i++) {
    v[i] = *(const float4*)(wr + (size_t)(tid + i * 256) * 4);
    mx = fmaxf(mx, fmaxf(fmaxf(fabsf(v[i].x), fabsf(v[i].y)),
                         fmaxf(fabsf(v[i].z), fabsf(v[i].w))));
  }
  mx = wave_max(mx);
  if ((tid & 63) == 0) red[tid >> 6] = mx;
  __syncthreads();
  float m = fmaxf(fmaxf(red[0], red[1]), fmaxf(red[2], red[3]));
  float s = m * (1.0f / 127.0f);
  if (tid == 0) sw[pr] = s;
  float sd = (s > 0.f) ? s : 1.f;
  int8_t* qr = qw + (size_t)pr * K;
#pragma unroll
  for (int i = 0; i < 2; i++) {
    char4 o;
    o.x = quant1(v[i].x, sd);
    o.y = quant1(v[i].y, sd);
    o.z = quant1(v[i].z, sd);
    o.w = quant1(v[i].w, sd);
    *(char4*)(qr + (size_t)(tid + i * 256) * 4) = o;
  }
}

// ---------------- RMSNorm + per-token quant ----------------
__global__ __launch_bounds__(256) void rmsnorm_quant_kernel(const float* __restrict__ x,
                                                            const float* __restrict__ w,
                                                            int8_t* __restrict__ q,
                                                            float* __restrict__ s) {
  __shared__ float red[8];
  int t = blockIdx.x, tid = threadIdx.x;
  const float* xr = x + (size_t)t * DM;
  float4 a = *(const float4*)(xr + tid * 8);
  float4 b = *(const float4*)(xr + tid * 8 + 4);
  float ss = dot4(a, a) + dot4(b, b);
  ss = wave_sum(ss);
  if ((tid & 63) == 0) red[tid >> 6] = ss;
  __syncthreads();
  float tot = red[0] + red[1] + red[2] + red[3];
  float rms = rsqrtf(tot * (1.0f / DM) + 1e-6f);
  float4 wa = *(const float4*)(w + tid * 8);
  float4 wb = *(const float4*)(w + tid * 8 + 4);
  float y[8] = {a.x * rms * wa.x, a.y * rms * wa.y, a.z * rms * wa.z, a.w * rms * wa.w,
                b.x * rms * wb.x, b.y * rms * wb.y, b.z * rms * wb.z, b.w * rms * wb.w};
  float mx = 0.f;
#pragma unroll
  for (int i = 0; i < 8; i++) mx = fmaxf(mx, fabsf(y[i]));
  mx = wave_max(mx);
  if ((tid & 63) == 0) red[4 + (tid >> 6)] = mx;
  __syncthreads();
  float m = fmaxf(fmaxf(red[4], red[5]), fmaxf(red[6], red[7]));
  float sc = fmaxf(m * (1.0f / 127.0f), 1e-8f);
  if (tid == 0) s[t] = sc;
  int8_t* qr = q + (size_t)t * DM + tid * 8;
  char4 o0, o1;
  o0.x = quant1(y[0], sc); o0.y = quant1(y[1], sc); o0.z = quant1(y[2], sc); o0.w = quant1(y[3], sc);
  o1.x = quant1(y[4], sc); o1.y = quant1(y[5], sc); o1.z = quant1(y[6], sc); o1.w = quant1(y[7], sc);
  *(char4*)(qr) = o0;
  *(char4*)(qr + 4) = o1;
}

// ---------------- plain per-token quant of a [*,2048] f32 matrix ----------------
__global__ __launch_bounds__(256) void quant_rows_2048_kernel(const float* __restrict__ x,
                                                              int8_t* __restrict__ q,
                                                              float* __restrict__ s) {
  __shared__ float red[4];
  int t = blockIdx.x, tid = threadIdx.x;
  const float* xr = x + (size_t)t * DM;
  float4 a = *(const float4*)(xr + tid * 8);
  float4 b = *(const float4*)(xr + tid * 8 + 4);
  float y[8] = {a.x, a.y, a.z, a.w, b.x, b.y, b.z, b.w};
  float mx = 0.f;
#pragma unroll
  for (int i = 0; i < 8; i++) mx = fmaxf(mx, fabsf(y[i]));
  mx = wave_max(mx);
  if ((tid & 63) == 0) red[tid >> 6] = mx;
  __syncthreads();
  float m = fmaxf(fmaxf(red[0], red[1]), fmaxf(red[2], red[3]));
  float sc = fmaxf(m * (1.0f / 127.0f), 1e-8f);
  if (tid == 0) s[t] = sc;
  int8_t* qr = q + (size_t)t * DM + tid * 8;
  char4 o0, o1;
  o0.x = quant1(y[0], sc); o0.y = quant1(y[1], sc); o0.z = quant1(y[2], sc); o0.w = quant1(y[3], sc);
  o1.x = quant1(y[4], sc); o1.y = quant1(y[5], sc); o1.z = quant1(y[6], sc); o1.w = quant1(y[7], sc);
  *(char4*)(qr) = o0;
  *(char4*)(qr + 4) = o1;
}

// ---------------- per-token quant of a [*,8192] f32 matrix ----------------
__global__ __launch_bounds__(256) void quant_rows_8192_kernel(const float* __restrict__ x,
                                                              int8_t* __restrict__ q,
                                                              float* __restrict__ s) {
  __shared__ float red[4];
  int t = blockIdx.x, tid = threadIdx.x;
  const float* xr = x + (size_t)t * INTER + tid * 32;
  float y[32];
  float mx = 0.f;
#pragma unroll
  for (int i4 = 0; i4 < 32; i4 += 4) {
    float4 v = *(const float4*)(xr + i4);
    y[i4] = v.x; y[i4 + 1] = v.y; y[i4 + 2] = v.z; y[i4 + 3] = v.w;
    mx = fmaxf(mx, fmaxf(fmaxf(fabsf(v.x), fabsf(v.y)), fmaxf(fabsf(v.z), fabsf(v.w))));
  }
  mx = wave_max(mx);
  if ((tid & 63) == 0) red[tid >> 6] = mx;
  __syncthreads();
  float m = fmaxf(fmaxf(red[0], red[1]), fmaxf(red[2], red[3]));
  float sc = fmaxf(m * (1.0f / 127.0f), 1e-8f);
  if (tid == 0) s[t] = sc;
  int8_t* qr = q + (size_t)t * INTER + tid * 32;
#pragma unroll
  for (int i4 = 0; i4 < 32; i4 += 4) {
    char4 o;
    o.x = quant1(y[i4], sc);
    o.y = quant1(y[i4 + 1], sc);
    o.z = quant1(y[i4 + 2], sc);
    o.w = quant1(y[i4 + 3], sc);
    *(char4*)(qr + i4) = o;
  }
}

// ---------------- RoPE + f32->bf16 hi/lo conversion: Q ----------------
__global__ __launch_bounds__(256) void cvt_q_kernel(const float* __restrict__ qf,
                                                    const float* __restrict__ cosT,
                                                    const float* __restrict__ sinT,
                                                    unsigned short* __restrict__ Qhi,
                                                    unsigned short* __restrict__ Qlo) {
  int t = blockIdx.x, tid = threadIdx.x;
  int sp = t & (SEQ - 1);
  int h = tid >> 4, pb = (tid & 15) * 4;
  const float* row = qf + (size_t)t * QDIM + h * HD;
  float4 x0 = *(const float4*)(row + pb);
  float4 x1 = *(const float4*)(row + pb + 64);
  float4 c = *(const float4*)(cosT + sp * 64 + pb);
  float4 s = *(const float4*)(sinT + sp * 64 + pb);
  float y0[4] = {x0.x * c.x - x1.x * s.x, x0.y * c.y - x1.y * s.y, x0.z * c.z - x1.z * s.z,
                 x0.w * c.w - x1.w * s.w};
  float y1[4] = {x1.x * c.x + x0.x * s.x, x1.y * c.y + x0.y * s.y, x1.z * c.z + x0.z * s.z,
                 x1.w * c.w + x0.w * s.w};
  s4v h0, l0, h1, l1;
#pragma unroll
  for (int e = 0; e < 4; e++) {
    unsigned short hb = f2bf_rne(y0[e]);
    h0[e] = (short)hb;
    l0[e] = (short)f2bf_rne(y0[e] - bf2f(hb));
    hb = f2bf_rne(y1[e]);
    h1[e] = (short)hb;
    l1[e] = (short)f2bf_rne(y1[e] - bf2f(hb));
  }
  size_t o = (size_t)t * QDIM + h * HD + pb;
  *(s4v*)&Qhi[o] = h0;
  *(s4v*)&Qlo[o] = l0;
  *(s4v*)&Qhi[o + 64] = h1;
  *(s4v*)&Qlo[o + 64] = l1;
}

// ---------------- RoPE + conversion: K (layout [(b,g)][s][d]) ----------------
__global__ __launch_bounds__(256) void cvt_k_kernel(const float* __restrict__ kvf,
                                                    const float* __restrict__ cosT,
                                                    const float* __restrict__ sinT,
                                                    unsigned short* __restrict__ Khi,
                                                    unsigned short* __restrict__ Klo) {
  int t = blockIdx.x, tid = threadIdx.x;
  int sp = t & (SEQ - 1);
  int b = t >> 11;
  int g = tid >> 5, pb = (tid & 31) * 2;
  const float* row = kvf + (size_t)t * DM + g * HD;
  float2 x0 = *(const float2*)(row + pb);
  float2 x1 = *(const float2*)(row + pb + 64);
  float2 c = *(const float2*)(cosT + sp * 64 + pb);
  float2 s = *(const float2*)(sinT + sp * 64 + pb);
  float y0[2] = {x0.x * c.x - x1.x * s.x, x0.y * c.y - x1.y * s.y};
  float y1[2] = {x1.x * c.x + x0.x * s.x, x1.y * c.y + x0.y * s.y};
  s2v h0, l0, h1, l1;
#pragma unroll
  for (int e = 0; e < 2; e++) {
    unsigned short hb = f2bf_rne(y0[e]);
    h0[e] = (short)hb;
    l0[e] = (short)f2bf_rne(y0[e] - bf2f(hb));
    hb = f2bf_rne(y1[e]);
    h1[e] = (short)hb;
    l1[e] = (short)f2bf_rne(y1[e] - bf2f(hb));
  }
  size_t o = ((size_t)(b * NKV + g) * SEQ + sp) * HD + pb;
  *(s2v*)&Khi[o] = h0;
  *(s2v*)&Klo[o] = l0;
  *(s2v*)&Khi[o + 64] = h1;
  *(s2v*)&Klo[o + 64] = l1;
}

// ---------------- V transpose + conversion ----------------
// Vt layout per bg: per 32-k tile (8192B): [kc 0-3][d 0-127][e 0-7] bf16
__global__ __launch_bounds__(256) void cvt_v_kernel(const float* __restrict__ kvf,
                                                    unsigned short* __restrict__ Vt) {
  __shared__ float vt[32][132];
  int bg = blockIdx.y;
  int b = bg >> 3, g = bg & 7;
  int s0 = blockIdx.x * 32;
  int tid = threadIdx.x;
#pragma unroll
  for (int i = 0; i < 4; i++) {
    int pos = tid + i * 256;
    int r = pos >> 5, d4 = (pos & 31) * 4;
    *(float4*)&vt[r][d4] =
        *(const float4*)(kvf + (size_t)(b * SEQ + s0 + r) * DM + KVDIM + g * HD + d4);
  }
  __syncthreads();
  int d = tid & 127, half = tid >> 7;
  unsigned short u[16];
#pragma unroll
  for (int i = 0; i < 16; i++) u[i] = f2bf_rne(vt[half * 16 + i][d]);
  unsigned short* dst =
      Vt + (size_t)bg * HD * SEQ + (size_t)(s0 >> 5) * 4096 + (half * 2) * 1024 + d * 8;
  *(s8v*)dst = *(s8v*)&u[0];
  *(s8v*)(dst + 1024) = *(s8v*)&u[8];
}

// ---------------- int8 GEMM (global_load_lds + XOR swizzle, 128x128, BK=128, XCD swz) ------
__global__ __launch_bounds__(256) void gemm_i8_kernel(const int8_t* __restrict__ A,
                                                      const float* __restrict__ sA,
                                                      const int8_t* __restrict__ B,
                                                      const float* __restrict__ sB,
                                                      const float* __restrict__ res,
                                                      float* __restrict__ C, int N, int K) {
  __shared__ __align__(16) int8_t lA[16384];
  __shared__ __align__(16) int8_t lB[16384];
  int tid = threadIdx.x;
  unsigned nx = gridDim.x;
  unsigned hw = blockIdx.y * nx + blockIdx.x;
  unsigned nwg = nx * gridDim.y;
  unsigned work = (hw & 7) * (nwg >> 3) + (hw >> 3);
  int row0 = (int)(work / nx) * 128;
  int col0 = (int)(work % nx) * 128;
  int lane = tid & 63, wid = tid >> 6;
  int wm = (wid >> 1) * 64, wn = (wid & 1) * 64;
  int fr = lane & 15, lq = lane >> 4;

  int rT = tid >> 3;
  int colS = ((tid & 7) << 4) ^ ((rT & 7) << 4);
  const int8_t* gA = A + (size_t)(row0 + rT) * K + colS;
  const int8_t* gB = B + (size_t)(col0 + rT) * K + colS;
  int8_t* lAd = &lA[tid * 16];
  int8_t* lBd = &lB[tid * 16];

  int swzk = (fr & 7) << 4;
  int aoff[4], boff[4];
#pragma unroll
  for (int m = 0; m < 4; m++) {
    aoff[m] = (wm + m * 16 + fr) * 128;
    boff[m] = (wn + m * 16 + fr) * 128;
  }

  v4i acc[4][4];
#pragma unroll
  for (int m = 0; m < 4; m++)
#pragma unroll
    for (int n = 0; n < 4; n++) acc[m][n] = (v4i){0, 0, 0, 0};

  for (int k0 = 0; k0 < K; k0 += 128) {
#pragma unroll
    for (int i = 0; i < 4; i++) GL16(gA + k0 + (size_t)(32 * i) * K, lAd + i * 4096);
#pragma unroll
    for (int i = 0; i < 4; i++) GL16(gB + k0 + (size_t)(32 * i) * K, lBd + i * 4096);
    __syncthreads();
#pragma unroll
    for (int kk = 0; kk < 2; kk++) {
      int kc = (kk * 64 + lq * 16) ^ swzk;
      v4i a[4], b[4];
#pragma unroll
      for (int m = 0; m < 4; m++) a[m] = *(const v4i*)&lA[aoff[m] + kc];
#pragma unroll
      for (int n = 0; n < 4; n++) b[n] = *(const v4i*)&lB[boff[n] + kc];
#pragma unroll
      for (int m = 0; m < 4; m++)
#pragma unroll
        for (int n = 0; n < 4; n++)
          acc[m][n] = __builtin_amdgcn_mfma_i32_16x16x64_i8(a[m], b[n], acc[m][n], 0, 0, 0);
    }
    __syncthreads();
  }
  int rj = lq * 4;
  int cn = fr;
#pragma unroll
  for (int m = 0; m < 4; m++) {
#pragma unroll
    for (int j = 0; j < 4; j++) {
      int rl = row0 + wm + m * 16 + rj + j;
      float sa = sA[rl];
      size_t rowoff = (size_t)rl * N;
#pragma unroll
      for (int n = 0; n < 4; n++) {
        int cg = col0 + wn + n * 16 + cn;
        float v = (float)acc[m][n][j] * sa * sB[cg];
        if (res) v += res[rowoff + cg];
        C[rowoff + cg] = v;
      }
    }
  }
}

// ---------------- int8 GEMM + fused gelu(gate)*up epilogue (permuted gu weights) ----------
__global__ __launch_bounds__(256) void gemm_gu_fused_kernel(const int8_t* __restrict__ A,
                                                            const float* __restrict__ sA,
                                                            const int8_t* __restrict__ B,
                                                            const float* __restrict__ sB,
                                                            float* __restrict__ act) {
  __shared__ __align__(16) int8_t lA[16384];
  __shared__ __align__(16) int8_t lB[16384];
  const int K = DM;
  int tid = threadIdx.x;
  unsigned nx = gridDim.x;
  unsigned hw = blockIdx.y * nx + blockIdx.x;
  unsigned nwg = nx * gridDim.y;
  unsigned work = (hw & 7) * (nwg >> 3) + (hw >> 3);
  int row0 = (int)(work / nx) * 128;
  int col0 = (int)(work % nx) * 128;
  int lane = tid & 63, wid = tid >> 6;
  int wm = (wid >> 1) * 64, wn = (wid & 1) * 64;
  int fr = lane & 15, lq = lane >> 4;

  int rT = tid >> 3;
  int colS = ((tid & 7) << 4) ^ ((rT & 7) << 4);
  const int8_t* gA = A + (size_t)(row0 + rT) * K + colS;
  const int8_t* gB = B + (size_t)(col0 + rT) * K + colS;
  int8_t* lAd = &lA[tid * 16];
  int8_t* lBd = &lB[tid * 16];

  int swzk = (fr & 7) << 4;
  int aoff[4], boff[4];
#pragma unroll
  for (int m = 0; m < 4; m++) {
    aoff[m] = (wm + m * 16 + fr) * 128;
    boff[m] = (wn + m * 16 + fr) * 128;
  }

  v4i acc[4][4];
#pragma unroll
  for (int m = 0; m < 4; m++)
#pragma unroll
    for (int n = 0; n < 4; n++) acc[m][n] = (v4i){0, 0, 0, 0};

  for (int k0 = 0; k0 < K; k0 += 128) {
#pragma unroll
    for (int i = 0; i < 4; i++) GL16(gA + k0 + (size_t)(32 * i) * K, lAd + i * 4096);
#pragma unroll
    for (int i = 0; i < 4; i++) GL16(gB + k0 + (size_t)(32 * i) * K, lBd + i * 4096);
    __syncthreads();
#pragma unroll
    for (int kk = 0; kk < 2; kk++) {
      int kc = (kk * 64 + lq * 16) ^ swzk;
      v4i a[4], b[4];
#pragma unroll
      for (int m = 0; m < 4; m++) a[m] = *(const v4i*)&lA[aoff[m] + kc];
#pragma unroll
      for (int n = 0; n < 4; n++) b[n] = *(const v4i*)&lB[boff[n] + kc];
#pragma unroll
      for (int m = 0; m < 4; m++)
#pragma unroll
        for (int n = 0; n < 4; n++)
          acc[m][n] = __builtin_amdgcn_mfma_i32_16x16x64_i8(a[m], b[n], acc[m][n], 0, 0, 0);
    }
    __syncthreads();
  }
  int rj = lq * 4;
  int cn = fr;
#pragma unroll
  for (int m = 0; m < 4; m++) {
#pragma unroll
    for (int j = 0; j < 4; j++) {
      int rl = row0 + wm + m * 16 + rj + j;
      float sa = sA[rl];
      size_t rowoff = (size_t)rl * INTER;
#pragma unroll
      for (int np = 0; np < 2; np++) {
        float gv = (float)acc[m][np * 2][j] * sa * sB[col0 + wn + (np * 2) * 16 + cn];
        float uv = (float)acc[m][np * 2 + 1][j] * sa * sB[col0 + wn + (np * 2 + 1) * 16 + cn];
        float inner = 0.7978845608028654f * (gv + 0.044715f * gv * gv * gv);
        float gl = 0.5f * gv * (1.0f + tanhf(inner));
        int jg = (col0 >> 1) + (wn >> 1) + np * 16 + cn;
        act[rowoff + jg] = gl * uv;
      }
    }
  }
}

// ---------------- flash attention: 512 thr, 2 heads (1 KV group) per block ----------------
// Fixed-max softmax (softcap bounds scores to [-50,50]; shift by 50, no online rescale).
// XCD-clustered: all 32 q-tiles of one KV group land on one XCD (K/V L2-resident).
__global__ __launch_bounds__(512, 4) void attn_mfma_kernel(
    const unsigned short* __restrict__ Qhi, const unsigned short* __restrict__ Qlo,
    const unsigned short* __restrict__ Khi, const unsigned short* __restrict__ Klo,
    const unsigned short* __restrict__ Vt, float* __restrict__ out) {
  __shared__ __align__(16) int8_t lkh[2][8192], lkl[2][8192], lvt[2][8192];
  __shared__ unsigned short ps[8][16][40];
  int hwid = blockIdx.y * gridDim.x + blockIdx.x;         // grid = (32, 16), 512 wgs
  int work = (hwid & 7) * 64 + (hwid >> 3);               // XCD-bijective remap
  int qt = 31 - (work & 31);                              // big tiles first per XCD
  int bg = work >> 5;
  int b = bg >> 3, g = bg & 7;
  int tid = threadIdx.x;
  int lane = tid & 63, w = tid >> 6;
  int lr = lane & 15, lq = lane >> 4;
  int h = g * 2 + (w >> 2);
  int qbase = qt * 64 + (w & 3) * 16;

  const int8_t* kbh = (const int8_t*)(Khi + (size_t)bg * SEQ * HD);
  const int8_t* kbl = (const int8_t*)(Klo + (size_t)bg * SEQ * HD);
  const int8_t* vb = (const int8_t*)(Vt + (size_t)bg * HD * SEQ);

  int xK = tid * 16;
  int sK = xK ^ (((xK >> 8) & 7) << 4);

  // Q fragments (hi/lo) in registers
  s8v qh[4], ql[4];
  {
    size_t qo = (size_t)(b * SEQ + qbase + lr) * QDIM + h * HD + lq * 8;
#pragma unroll
    for (int c = 0; c < 4; ++c) {
      qh[c] = *(const s8v*)(Qhi + qo + c * 32);
      ql[c] = *(const s8v*)(Qlo + qo + c * 32);
    }
  }

  v4f oacc[8];
#pragma unroll
  for (int i = 0; i < 8; ++i) oacc[i] = (v4f){0.f, 0.f, 0.f, 0.f};
  float lsum[4] = {0.f, 0.f, 0.f, 0.f};
  const float kin2 = 0.0035355339059327374f;  // 2/(sqrt(128)*50)

  int kswz = (lr & 7) << 4;
  int kcol = lq * 16;
  int vbase = lq * 2048 + lr * 16;  // + dt*256

  int ktiles = 2 * qt + 2;

#define STAGE(kt, buf)                                  \
  do {                                                  \
    size_t kb = (size_t)(kt) * 8192;                    \
    GL16(kbh + kb + sK, &lkh[buf][xK]);                 \
    GL16(kbl + kb + sK, &lkl[buf][xK]);                 \
    GL16(vb + kb + xK, &lvt[buf][xK]);                  \
  } while (0)

  STAGE(0, 0);
  for (int kt = 0; kt < ktiles; ++kt) {
    int cur = kt & 1;
    if (kt + 1 < ktiles) {
      STAGE(kt + 1, cur ^ 1);
      asm volatile("s_waitcnt vmcnt(3)" ::: "memory");
    } else {
      asm volatile("s_waitcnt vmcnt(0)" ::: "memory");
    }
    __builtin_amdgcn_s_barrier();
    __builtin_amdgcn_sched_barrier(0);
    int kbase = kt * 32;
    if (kbase <= qbase + 15) {
      // QK^T: two 16x16 tiles, 3-term hi/lo
      v4f sacc[2];
#pragma unroll
      for (int t2 = 0; t2 < 2; ++t2) {
        v4f s = (v4f){0.f, 0.f, 0.f, 0.f};
        int rowb = (t2 * 16 + lr) * 256;
#pragma unroll
        for (int c = 0; c < 4; ++c) {
          int off = rowb + ((c * 64 + kcol) ^ kswz);
          s8v kh = *(const s8v*)&lkh[cur][off];
          s8v kl = *(const s8v*)&lkl[cur][off];
          s = __builtin_amdgcn_mfma_f32_16x16x32_bf16(qh[c], kh, s, 0, 0, 0);
          s = __builtin_amdgcn_mfma_f32_16x16x32_bf16(qh[c], kl, s, 0, 0, 0);
          s = __builtin_amdgcn_mfma_f32_16x16x32_bf16(ql[c], kh, s, 0, 0, 0);
        }
        sacc[t2] = s;
      }

      // softcap + causal mask + fixed-shift softmax: P = exp(cap(s) - 50)
#pragma unroll
      for (int j = 0; j < 4; ++j) {
        int qg = qbase + lq * 4 + j;
        int k0g = kbase + lr, k1g = kbase + 16 + lr;
        float z0 = __expf(sacc[0][j] * kin2);
        float z1 = __expf(sacc[1][j] * kin2);
        float e0 = __expf(-100.f * __builtin_amdgcn_rcpf(z0 + 1.f));
        float e1 = __expf(-100.f * __builtin_amdgcn_rcpf(z1 + 1.f));
        e0 = (k0g <= qg) ? e0 : 0.f;
        e1 = (k1g <= qg) ? e1 : 0.f;
        lsum[j] += e0 + e1;
        int q = lq * 4 + j;
        ps[w][q][lr] = f2bf_rne(e0);
        ps[w][q][16 + lr] = f2bf_rne(e1);
      }

      s8v pa = *(const s8v*)&ps[w][lr][lq * 8];
#pragma unroll
      for (int dt = 0; dt < 8; ++dt) {
        s8v vh = *(const s8v*)&lvt[cur][vbase + dt * 256];
        oacc[dt] = __builtin_amdgcn_mfma_f32_16x16x32_bf16(pa, vh, oacc[dt], 0, 0, 0);
      }
    }
    __builtin_amdgcn_s_barrier();
  }
#undef STAGE

  // deferred row-sum reduce across the 16 lanes holding each row's partials
#pragma unroll
  for (int st = 1; st <= 8; st <<= 1)
#pragma unroll
    for (int j = 0; j < 4; ++j) lsum[j] += __shfl_xor(lsum[j], st);

  float inv[4];
#pragma unroll
  for (int j = 0; j < 4; ++j) inv[j] = 1.f / lsum[j];
  float* ob = out + (size_t)(b * SEQ + qbase) * QDIM + h * HD;
#pragma unroll
  for (int dt = 0; dt < 8; ++dt)
#pragma unroll
    for (int j = 0; j < 4; ++j)
      ob[(size_t)(lq * 4 + j) * QDIM + dt * 16 + lr] = oacc[dt][j] * inv[j];
}

extern "C" void kernel_launch(void* const* d_in, const int* in_sizes, int n_in, void* d_out,
                              int out_size, void* d_ws, size_t ws_size, hipStream_t stream) {
  (void)in_sizes; (void)n_in; (void)out_size; (void)ws_size;
  const float* hidden = (const float*)d_in[0];
  const float* w_in_norm = (const float*)d_in[1];
  const float* w_post_norm = (const float*)d_in[2];
  const float* wqkv = (const float*)d_in[3];
  const float* wo = (const float*)d_in[4];
  const float* w_gate_up = (const float*)d_in[5];
  const float* w_down = (const float*)d_in[6];
  float* out = (float*)d_out;

  char* p = (char*)d_ws;
  size_t off = 0;
  auto take = [&](size_t bytes) -> char* {
    char* r = p + off;
    off += (bytes + 255) & ~(size_t)255;
    return r;
  };
  const size_t MB = 1u << 20;
  int8_t* qx = (int8_t*)take((size_t)T_TOKENS * DM);
  float* sx = (float*)take((size_t)T_TOKENS * 4);
  int8_t* qw_qkv = (int8_t*)take((size_t)QKVN * DM);
  float* sw_qkv = (float*)take((size_t)QKVN * 4);
  int8_t* qw_wo = (int8_t*)take((size_t)DM * QDIM);
  float* sw_wo = (float*)take((size_t)DM * 4);
  int8_t* qw_gu = (int8_t*)take((size_t)GUN * DM);
  float* sw_gu = (float*)take((size_t)GUN * 4);
  int8_t* qw_dn = (int8_t*)take((size_t)DM * INTER);
  float* sw_dn = (float*)take((size_t)DM * 4);
  float* cosT = (float*)take((size_t)SEQ * 64 * 4);
  float* sinT = (float*)take((size_t)SEQ * 64 * 4);
  float* x1 = (float*)take((size_t)T_TOKENS * DM * 4);
  float* s_act = (float*)take((size_t)T_TOKENS * 4);
  char* regB = take(96 * MB);
  float* qf32 = (float*)regB;
  float* kvf32 = (float*)regB;
  float* attn_out = (float*)regB;
  unsigned short* Qhi = (unsigned short*)(regB + 32 * MB);
  unsigned short* Qlo = (unsigned short*)(regB + 48 * MB);
  unsigned short* Khi = (unsigned short*)(regB + 64 * MB);
  unsigned short* Klo = (unsigned short*)(regB + 72 * MB);
  unsigned short* Vt = (unsigned short*)(regB + 80 * MB);
  float* act_f32 = (float*)regB;                       // phase-2: [0,32MB)
  int8_t* act_q8 = (int8_t*)(regB + 64 * MB);          // phase-2: [64,96MB)

  rope_table_kernel<<<SEQ, 64, 0, stream>>>(cosT, sinT);
  quant_w_kernel<<<QKVN, 256, 0, stream>>>(wqkv, qw_qkv, sw_qkv, DM);
  quant_w_kernel<<<DM, 256, 0, stream>>>(wo, qw_wo, sw_wo, QDIM);
  quant_w_gu_kernel<<<GUN, 256, 0, stream>>>(w_gate_up, qw_gu, sw_gu);
  quant_w_kernel<<<DM, 256, 0, stream>>>(w_down, qw_dn, sw_dn, INTER);

  // attention block
  rmsnorm_quant_kernel<<<T_TOKENS, 256, 0, stream>>>(hidden, w_in_norm, qx, sx);
  gemm_i8_kernel<<<dim3(QDIM / 128, T_TOKENS / 128), 256, 0, stream>>>(qx, sx, qw_qkv, sw_qkv,
                                                                       nullptr, qf32, QDIM, DM);
  cvt_q_kernel<<<T_TOKENS, 256, 0, stream>>>(qf32, cosT, sinT, Qhi, Qlo);
  gemm_i8_kernel<<<dim3(DM / 128, T_TOKENS / 128), 256, 0, stream>>>(
      qx, sx, qw_qkv + (size_t)QDIM * DM, sw_qkv + QDIM, nullptr, kvf32, DM, DM);
  cvt_k_kernel<<<T_TOKENS, 256, 0, stream>>>(kvf32, cosT, sinT, Khi, Klo);
  cvt_v_kernel<<<dim3(SEQ / 32, 16), 256, 0, stream>>>(kvf32, Vt);
  attn_mfma_kernel<<<dim3(SEQ / 64, 16), 512, 0, stream>>>(Qhi, Qlo, Khi, Klo, Vt, attn_out);
  quant_rows_2048_kernel<<<T_TOKENS, 256, 0, stream>>>(attn_out, qx, sx);
  gemm_i8_kernel<<<dim3(DM / 128, T_TOKENS / 128), 256, 0, stream>>>(qx, sx, qw_wo, sw_wo, hidden,
                                                                     x1, DM, QDIM);

  // MLP block: fused gelu epilogue writes act f32; quant; single down GEMM
  rmsnorm_quant_kernel<<<T_TOKENS, 256, 0, stream>>>(x1, w_post_norm, qx, sx);
  for (int ch = 0; ch < 4; ++ch) {
    const int8_t* qxc = qx + (size_t)ch * 1024 * DM;
    const float* sxc = sx + (size_t)ch * 1024;
    gemm_gu_fused_kernel<<<dim3(GUN / 128, 1024 / 128), 256, 0, stream>>>(qxc, sxc, qw_gu, sw_gu,
                                                                          act_f32);
    quant_rows_8192_kernel<<<1024, 256, 0, stream>>>(act_f32, act_q8 + (size_t)ch * 1024 * INTER,
                                                     s_act + (size_t)ch * 1024);
  }
  gemm_i8_kernel<<<dim3(DM / 128, T_TOKENS / 128), 256, 0, stream>>>(act_q8, s_act, qw_dn, sw_dn,
                                                                     x1, out, DM, INTER);
}